// Round 1
// baseline (2917.105 us; speedup 1.0000x reference)
//
#include <hip/hip_runtime.h>

// RouterKT forward, f32 correctness-first implementation.
// BS=8, S=1024, D_MODEL=256, N_HEADS=8, D_K=32, N_DYN=6, H_SEL=2, D_FF=1024, L=6.
// Workspace requirement: ~84 MB (6 activation bufs of 8 MB + 32 MB FFN hidden + small).

constexpr int DMODEL = 256;
constexpr int SEQ    = 1024;
constexpr int BATCH  = 8;
constexpr int NHEADS = 8;
constexpr int DKDIM  = 32;
constexpr int NDYN_C = 6;
constexpr int NTOK_C = BATCH * SEQ;   // 8192
constexpr int DFF_C  = 1024;

// ---------------- GEMM: C = A @ W + bias (optional relu) ----------------
// BM=64, BN=64, BK=16, 256 threads, 4x4 per-thread micro-tile.
template<bool RELU>
__global__ __launch_bounds__(256)
void gemm_bias_k(const float* __restrict__ A, const float* __restrict__ W,
                 const float* __restrict__ bias, float* __restrict__ C,
                 int M, int N, int K) {
  constexpr int BM = 64, BN = 64, BK = 16;
  __shared__ float sA[BK][BM + 1];
  __shared__ float sB[BK][BN + 4];
  const int tid = threadIdx.x;
  const int tx = tid & 15;   // n
  const int ty = tid >> 4;   // m
  const int m0 = blockIdx.y * BM;
  const int n0 = blockIdx.x * BN;
  float acc[4][4] = {};
  const int ar = tid >> 2;          // 0..63
  const int ac = (tid & 3) << 2;    // 0,4,8,12
  const int br = tid >> 4;          // 0..15
  const int bc = (tid & 15) << 2;   // 0..60
  for (int k0 = 0; k0 < K; k0 += BK) {
    float4 av = *reinterpret_cast<const float4*>(&A[(size_t)(m0 + ar) * K + k0 + ac]);
    sA[ac + 0][ar] = av.x; sA[ac + 1][ar] = av.y;
    sA[ac + 2][ar] = av.z; sA[ac + 3][ar] = av.w;
    float4 bv = *reinterpret_cast<const float4*>(&W[(size_t)(k0 + br) * N + n0 + bc]);
    *reinterpret_cast<float4*>(&sB[br][bc]) = bv;
    __syncthreads();
#pragma unroll
    for (int k = 0; k < BK; ++k) {
      float a[4], b[4];
#pragma unroll
      for (int i = 0; i < 4; ++i) a[i] = sA[k][ty * 4 + i];
#pragma unroll
      for (int j = 0; j < 4; ++j) b[j] = sB[k][tx * 4 + j];
#pragma unroll
      for (int i = 0; i < 4; ++i)
#pragma unroll
        for (int j = 0; j < 4; ++j)
          acc[i][j] = fmaf(a[i], b[j], acc[i][j]);
    }
    __syncthreads();
  }
#pragma unroll
  for (int i = 0; i < 4; ++i) {
    const int m = m0 + ty * 4 + i;
#pragma unroll
    for (int j = 0; j < 4; ++j) {
      const int n = n0 + tx * 4 + j;
      float v = acc[i][j] + bias[n];
      if (RELU) v = fmaxf(v, 0.0f);
      C[(size_t)m * N + n] = v;
    }
  }
}

// ---------------- Attention ----------------
// grid (S/16, NHEADS, BATCH), 256 threads: 16 query rows/block, 16 lanes/row.
// Each lane runs a private online softmax over its key subset; merge via shfl.
// kq_same: keys come from the q buffer. Output scaled by routing[b,h].
__global__ __launch_bounds__(256)
void attn_k(const float* __restrict__ q, const float* __restrict__ v,
            const float* __restrict__ routing8, float* __restrict__ out,
            int mask_val) {
  const int b = blockIdx.z, h = blockIdx.y;
  const int i0 = blockIdx.x * 16;
  const int tid = threadIdx.x;
  const int row = tid >> 4;
  const int lane = tid & 15;
  const int gi = i0 + row;
  __shared__ float sk[64][DKDIM + 1];
  __shared__ float sv[64][DKDIM + 1];

  float qreg[DKDIM];
  {
    const float* qp = &q[((size_t)(b * SEQ + gi)) * DMODEL + h * DKDIM];
#pragma unroll
    for (int t = 0; t < DKDIM / 4; ++t) {
      float4 qq = *reinterpret_cast<const float4*>(qp + t * 4);
      qreg[t * 4 + 0] = qq.x; qreg[t * 4 + 1] = qq.y;
      qreg[t * 4 + 2] = qq.z; qreg[t * 4 + 3] = qq.w;
    }
  }
  float mrun = -INFINITY, srun = 0.0f;
  float oacc[DKDIM];
#pragma unroll
  for (int d = 0; d < DKDIM; ++d) oacc[d] = 0.0f;

  for (int kt = 0; kt < SEQ; kt += 64) {
    __syncthreads();
    for (int t = tid; t < 512; t += 256) {
      const int r = t >> 3;
      const int c = (t & 7) << 2;
      const size_t g = ((size_t)(b * SEQ + kt + r)) * DMODEL + h * DKDIM + c;
      float4 kk = *reinterpret_cast<const float4*>(&q[g]);
      sk[r][c] = kk.x; sk[r][c + 1] = kk.y; sk[r][c + 2] = kk.z; sk[r][c + 3] = kk.w;
      float4 vv = *reinterpret_cast<const float4*>(&v[g]);
      sv[r][c] = vv.x; sv[r][c + 1] = vv.y; sv[r][c + 2] = vv.z; sv[r][c + 3] = vv.w;
    }
    __syncthreads();
    float sc[4];
#pragma unroll
    for (int u = 0; u < 4; ++u) {
      const int j = lane + u * 16;
      float dot = 0.0f;
#pragma unroll
      for (int d = 0; d < DKDIM; ++d) dot = fmaf(qreg[d], sk[j][d], dot);
      const bool allowed = (kt + j) < (gi + mask_val);
      sc[u] = allowed ? dot * 0.17677669529663687f : -1e9f;
    }
    const float tmax = fmaxf(fmaxf(sc[0], sc[1]), fmaxf(sc[2], sc[3]));
    const float mnew = fmaxf(mrun, tmax);
    const float scale = expf(mrun - mnew);  // expf(-inf)=0 on first tile
    float p[4];
    float psum = 0.0f;
#pragma unroll
    for (int u = 0; u < 4; ++u) { p[u] = expf(sc[u] - mnew); psum += p[u]; }
    srun = srun * scale + psum;
#pragma unroll
    for (int d = 0; d < DKDIM; ++d) {
      float o = oacc[d] * scale;
      o = fmaf(p[0], sv[lane][d], o);
      o = fmaf(p[1], sv[lane + 16][d], o);
      o = fmaf(p[2], sv[lane + 32][d], o);
      o = fmaf(p[3], sv[lane + 48][d], o);
      oacc[d] = o;
    }
    mrun = mnew;
  }
  // merge the 16 lanes of this query row (xor masks 1..8 stay inside the group)
  float M = mrun;
#pragma unroll
  for (int o = 8; o >= 1; o >>= 1) M = fmaxf(M, __shfl_xor(M, o, 64));
  const float cf = expf(mrun - M);
  float ssum = srun * cf;
#pragma unroll
  for (int o = 8; o >= 1; o >>= 1) ssum += __shfl_xor(ssum, o, 64);
#pragma unroll
  for (int d = 0; d < DKDIM; ++d) {
    float t = oacc[d] * cf;
#pragma unroll
    for (int o = 8; o >= 1; o >>= 1) t += __shfl_xor(t, o, 64);
    oacc[d] = t;
  }
  const float mult = routing8[b * NHEADS + h] / ssum;
  const int d0 = lane * 2;
  const size_t ob = ((size_t)(b * SEQ + gi)) * DMODEL + h * DKDIM;
  out[ob + d0] = oacc[d0] * mult;
  out[ob + d0 + 1] = oacc[d0 + 1] * mult;
}

// ---------------- Router ----------------
// Scrambled view: qr[r, c] = R[b, s8*8 + (c>>5), h*32 + (c&31)],
// r = b*1024 + h*128 + s8. One thread per row; 64 blocks x 128 threads.
// Emits per-block partials: [0..5] sum dyn_scores, [6..11] sum sel-count, [12..17] sum gates.
__global__ __launch_bounds__(128)
void router_k(const float* __restrict__ R, const float* __restrict__ Wg,
              float* __restrict__ partials) {
  __shared__ float sW[DMODEL * NDYN_C];
  __shared__ float red[18][128];
  const int tid = threadIdx.x;
  for (int t = tid; t < DMODEL * NDYN_C; t += 128) sW[t] = Wg[t];
  __syncthreads();
  const int r = blockIdx.x * 128 + tid;
  const int b = r >> 10;
  const int h = (r >> 7) & 7;
  const int s8 = r & 127;
  float lg[NDYN_C] = {};
  for (int t8 = 0; t8 < 8; ++t8) {
    const float* base = &R[((size_t)(b * SEQ + s8 * 8 + t8)) * DMODEL + h * DKDIM];
#pragma unroll
    for (int d = 0; d < DKDIM; ++d) {
      const float x = base[d];
      const float* w = &sW[(t8 * 32 + d) * NDYN_C];
#pragma unroll
      for (int j = 0; j < NDYN_C; ++j) lg[j] = fmaf(x, w[j], lg[j]);
    }
  }
  float mx = lg[0];
#pragma unroll
  for (int j = 1; j < NDYN_C; ++j) mx = fmaxf(mx, lg[j]);
  float e[NDYN_C], sum = 0.0f;
#pragma unroll
  for (int j = 0; j < NDYN_C; ++j) { e[j] = expf(lg[j] - mx); sum += e[j]; }
  float g[NDYN_C];
#pragma unroll
  for (int j = 0; j < NDYN_C; ++j) g[j] = e[j] / sum;
  // top-2, ties -> lowest index (matches jax.lax.top_k)
  int j1 = 0;
#pragma unroll
  for (int j = 1; j < NDYN_C; ++j) if (g[j] > g[j1]) j1 = j;
  int j2 = -1;
#pragma unroll
  for (int j = 0; j < NDYN_C; ++j) {
    if (j == j1) continue;
    if (j2 < 0 || g[j] > g[j2]) j2 = j;
  }
#pragma unroll
  for (int j = 0; j < NDYN_C; ++j) {
    const bool sel = (j == j1) || (j == j2);
    red[j][tid] = sel ? g[j] : 0.0f;
    red[6 + j][tid] = sel ? 1.0f : 0.0f;
    red[12 + j][tid] = g[j];
  }
  __syncthreads();
  if (tid < 18) {
    float s = 0.0f;
    for (int i = 0; i < 128; ++i) s += red[tid][i];
    partials[blockIdx.x * 18 + tid] = s;
  }
}

// Deterministic finalize: routing8[b*8+h] and bal.
__global__ void router_reduce_k(const float* __restrict__ partials,
                                float* __restrict__ routing8,
                                float* __restrict__ bal_out) {
  const int tid = threadIdx.x;
  if (tid < 48) {
    const int b = tid / 6, j = tid % 6;
    float s = 0.0f;
    for (int t = 0; t < 8; ++t) s += partials[(b * 8 + t) * 18 + j];
    routing8[b * NHEADS + 2 + j] = s * (1.0f / 1024.0f);
  } else if (tid < 56) {
    const int b = tid - 48;
    routing8[b * NHEADS + 0] = 1.0f;
    routing8[b * NHEADS + 1] = 1.0f;
  } else if (tid == 56) {
    float hs[6], hp[6];
    float hssum = 0.0f, hpsum = 0.0f;
    for (int j = 0; j < 6; ++j) {
      float a = 0.0f, c = 0.0f;
      for (int bi = 0; bi < 64; ++bi) {
        a += partials[bi * 18 + 6 + j];
        c += partials[bi * 18 + 12 + j];
      }
      hs[j] = a;
      hp[j] = c * (1.0f / 8192.0f);
      hssum += hs[j];
      hpsum += hp[j];
    }
    float bal = 0.0f;
    for (int j = 0; j < 6; ++j)
      bal += (hs[j] / (hssum + 1e-5f)) * (hp[j] / (hpsum + 1e-5f));
    *bal_out = bal;
  }
}

// ---------------- residual add + layernorm (in place on X) ----------------
__global__ __launch_bounds__(256)
void add_ln_k(float* __restrict__ X, const float* __restrict__ Y,
              const float* __restrict__ g, const float* __restrict__ be) {
  const int r = blockIdx.x;
  const int c = threadIdx.x;
  const size_t idx = (size_t)r * DMODEL + c;
  const float x = X[idx] + Y[idx];
  __shared__ float sh[4];
  float s = x;
#pragma unroll
  for (int o = 32; o >= 1; o >>= 1) s += __shfl_xor(s, o, 64);
  if ((c & 63) == 0) sh[c >> 6] = s;
  __syncthreads();
  const float mean = (sh[0] + sh[1] + sh[2] + sh[3]) * (1.0f / DMODEL);
  const float d = x - mean;
  float vsum = d * d;
  __syncthreads();
#pragma unroll
  for (int o = 32; o >= 1; o >>= 1) vsum += __shfl_xor(vsum, o, 64);
  if ((c & 63) == 0) sh[c >> 6] = vsum;
  __syncthreads();
  const float var = (sh[0] + sh[1] + sh[2] + sh[3]) * (1.0f / DMODEL);
  X[idx] = d * (1.0f / sqrtf(var + 1e-5f)) * g[c] + be[c];
}

// ---------------- driver ----------------
extern "C" void kernel_launch(void* const* d_in, const int* in_sizes, int n_in,
                              void* d_out, int out_size, void* d_ws, size_t ws_size,
                              hipStream_t stream) {
  const float* q_embed  = (const float*)d_in[0];
  const float* qa_embed = (const float*)d_in[1];
  const float* Wq  = (const float*)d_in[2];
  const float* bq  = (const float*)d_in[3];
  const float* Wv  = (const float*)d_in[4];
  const float* bv  = (const float*)d_in[5];
  const float* Wg  = (const float*)d_in[6];
  const float* Wo  = (const float*)d_in[7];
  const float* bo  = (const float*)d_in[8];
  const float* ln1w = (const float*)d_in[9];
  const float* ln1b = (const float*)d_in[10];
  const float* Wf1 = (const float*)d_in[11];
  const float* bf1 = (const float*)d_in[12];
  const float* Wf2 = (const float*)d_in[13];
  const float* bf2 = (const float*)d_in[14];
  const float* ln2w = (const float*)d_in[15];
  const float* ln2b = (const float*)d_in[16];
  float* out = (float*)d_out;

  float* ws = (float*)d_ws;
  const size_t NA = (size_t)NTOK_C * DMODEL;  // 2097152
  float* xbuf = ws;
  float* ybuf = xbuf + NA;
  float* qb   = ybuf + NA;
  float* vb   = qb + NA;
  float* ab   = vb + NA;
  float* ob   = ab + NA;
  float* hb   = ob + NA;                       // NTOK * DFF
  float* routing8   = hb + (size_t)NTOK_C * DFF_C;
  float* partials   = routing8 + 64;
  float* balscratch = partials + 64 * 18;

  hipMemcpyAsync(xbuf, q_embed, NA * sizeof(float), hipMemcpyDeviceToDevice, stream);
  hipMemcpyAsync(ybuf, qa_embed, NA * sizeof(float), hipMemcpyDeviceToDevice, stream);

  auto run_layer = [&](int l, float* Q, const float* V, const float* R,
                       int mask_val, bool ffn, bool last) {
    const float* Wq_l = Wq + (size_t)l * DMODEL * DMODEL;
    const float* bq_l = bq + (size_t)l * DMODEL;
    const float* Wv_l = Wv + (size_t)l * DMODEL * DMODEL;
    const float* bv_l = bv + (size_t)l * DMODEL;
    const float* Wg_l = Wg + (size_t)l * DMODEL * NDYN_C;
    const float* Wo_l = Wo + (size_t)l * DMODEL * DMODEL;
    const float* bo_l = bo + (size_t)l * DMODEL;
    const float* g1_l = ln1w + (size_t)l * DMODEL;
    const float* b1_l = ln1b + (size_t)l * DMODEL;

    router_k<<<64, 128, 0, stream>>>(R, Wg_l, partials);
    router_reduce_k<<<1, 64, 0, stream>>>(partials, routing8,
                                          last ? (out + NA) : balscratch);
    gemm_bias_k<false><<<dim3(DMODEL / 64, NTOK_C / 64), 256, 0, stream>>>(
        Q, Wq_l, bq_l, qb, NTOK_C, DMODEL, DMODEL);
    gemm_bias_k<false><<<dim3(DMODEL / 64, NTOK_C / 64), 256, 0, stream>>>(
        V, Wv_l, bv_l, vb, NTOK_C, DMODEL, DMODEL);
    attn_k<<<dim3(SEQ / 16, NHEADS, BATCH), 256, 0, stream>>>(
        qb, vb, routing8, ab, mask_val);
    gemm_bias_k<false><<<dim3(DMODEL / 64, NTOK_C / 64), 256, 0, stream>>>(
        ab, Wo_l, bo_l, ob, NTOK_C, DMODEL, DMODEL);
    add_ln_k<<<NTOK_C, DMODEL, 0, stream>>>(Q, ob, g1_l, b1_l);
    if (ffn) {
      const float* Wf1_l = Wf1 + (size_t)l * DMODEL * DFF_C;
      const float* bf1_l = bf1 + (size_t)l * DFF_C;
      const float* Wf2_l = Wf2 + (size_t)l * DFF_C * DMODEL;
      const float* bf2_l = bf2 + (size_t)l * DMODEL;
      const float* g2_l = ln2w + (size_t)l * DMODEL;
      const float* b2_l = ln2b + (size_t)l * DMODEL;
      gemm_bias_k<true><<<dim3(DFF_C / 64, NTOK_C / 64), 256, 0, stream>>>(
          Q, Wf1_l, bf1_l, hb, NTOK_C, DFF_C, DMODEL);
      gemm_bias_k<false><<<dim3(DMODEL / 64, NTOK_C / 64), 256, 0, stream>>>(
          hb, Wf2_l, bf2_l, ob, NTOK_C, DMODEL, DFF_C);
      add_ln_k<<<NTOK_C, DMODEL, 0, stream>>>(Q, ob, g2_l, b2_l);
    }
  };

  // blocks_1: y-stream, router input = original x (q_embed)
  run_layer(0, ybuf, ybuf, xbuf, 1, true, false);
  run_layer(1, ybuf, ybuf, xbuf, 1, true, false);
  // blocks_2: (self, no FFN) then (cross to y, strict causal, FFN)
  run_layer(2, xbuf, xbuf, xbuf, 1, false, false);
  run_layer(3, xbuf, ybuf, xbuf, 0, true, false);
  run_layer(4, xbuf, xbuf, xbuf, 1, false, false);
  run_layer(5, xbuf, ybuf, xbuf, 0, true, true);

  hipMemcpyAsync(out, xbuf, NA * sizeof(float), hipMemcpyDeviceToDevice, stream);
}

// Round 2
// 1456.490 us; speedup vs baseline: 2.0028x; 2.0028x over previous
//
#include <hip/hip_runtime.h>

// RouterKT forward. Round 2: bf16-MFMA flash attention with causal tile skip.
// BS=8, S=1024, D_MODEL=256, N_HEADS=8, D_K=32, N_DYN=6, H_SEL=2, D_FF=1024, L=6.

constexpr int DMODEL = 256;
constexpr int SEQ    = 1024;
constexpr int BATCH  = 8;
constexpr int NHEADS = 8;
constexpr int DKDIM  = 32;
constexpr int NDYN_C = 6;
constexpr int NTOK_C = BATCH * SEQ;   // 8192
constexpr int DFF_C  = 1024;

using frag_bf16 = __attribute__((ext_vector_type(8))) short;  // 8 bf16 = 4 VGPR
using f32x4    = __attribute__((ext_vector_type(4))) float;

__device__ __forceinline__ unsigned short f2bf(float f) {
  unsigned u = __float_as_uint(f);
  unsigned r = (u + 0x7fffu + ((u >> 16) & 1u)) >> 16;   // RNE, finite inputs
  return (unsigned short)r;
}

// ---------------- GEMM: C = A @ W + bias ----------------
// OMODE: 0 = f32, 1 = f32+relu, 2 = bf16 [M][N], 3 = bf16 transposed vbT[b][h][d][tok]
template<int OMODE>
__global__ __launch_bounds__(256)
void gemm_bias_k(const float* __restrict__ A, const float* __restrict__ W,
                 const float* __restrict__ bias, void* __restrict__ Cp,
                 int M, int N, int K) {
  constexpr int BM = 64, BN = 64, BK = 16;
  __shared__ float sA[BK][BM + 1];
  __shared__ float sB[BK][BN + 4];
  const int tid = threadIdx.x;
  const int tx = tid & 15;   // n
  const int ty = tid >> 4;   // m
  const int m0 = blockIdx.y * BM;
  const int n0 = blockIdx.x * BN;
  float acc[4][4] = {};
  const int ar = tid >> 2;
  const int ac = (tid & 3) << 2;
  const int br = tid >> 4;
  const int bc = (tid & 15) << 2;
  for (int k0 = 0; k0 < K; k0 += BK) {
    float4 av = *reinterpret_cast<const float4*>(&A[(size_t)(m0 + ar) * K + k0 + ac]);
    sA[ac + 0][ar] = av.x; sA[ac + 1][ar] = av.y;
    sA[ac + 2][ar] = av.z; sA[ac + 3][ar] = av.w;
    float4 bv = *reinterpret_cast<const float4*>(&W[(size_t)(k0 + br) * N + n0 + bc]);
    *reinterpret_cast<float4*>(&sB[br][bc]) = bv;
    __syncthreads();
#pragma unroll
    for (int k = 0; k < BK; ++k) {
      float a[4], b[4];
#pragma unroll
      for (int i = 0; i < 4; ++i) a[i] = sA[k][ty * 4 + i];
#pragma unroll
      for (int j = 0; j < 4; ++j) b[j] = sB[k][tx * 4 + j];
#pragma unroll
      for (int i = 0; i < 4; ++i)
#pragma unroll
        for (int j = 0; j < 4; ++j)
          acc[i][j] = fmaf(a[i], b[j], acc[i][j]);
    }
    __syncthreads();
  }
  if (OMODE <= 1) {
    float* C = (float*)Cp;
#pragma unroll
    for (int i = 0; i < 4; ++i) {
      const int m = m0 + ty * 4 + i;
#pragma unroll
      for (int j = 0; j < 4; ++j) {
        const int n = n0 + tx * 4 + j;
        float v = acc[i][j] + bias[n];
        if (OMODE == 1) v = fmaxf(v, 0.0f);
        C[(size_t)m * N + n] = v;
      }
    }
  } else if (OMODE == 2) {
    unsigned short* C = (unsigned short*)Cp;
#pragma unroll
    for (int i = 0; i < 4; ++i) {
      const int m = m0 + ty * 4 + i;
      const int nb = n0 + tx * 4;
      ushort4 pk;
      pk.x = f2bf(acc[i][0] + bias[nb + 0]);
      pk.y = f2bf(acc[i][1] + bias[nb + 1]);
      pk.z = f2bf(acc[i][2] + bias[nb + 2]);
      pk.w = f2bf(acc[i][3] + bias[nb + 3]);
      *reinterpret_cast<ushort4*>(&C[(size_t)m * N + nb]) = pk;
    }
  } else {  // OMODE 3: vbT[b][h][d][tok] bf16
    unsigned short* C = (unsigned short*)Cp;
    const int bidx = m0 >> 10;
    const int tokb = (m0 & 1023) + ty * 4;
#pragma unroll
    for (int j = 0; j < 4; ++j) {
      const int n = n0 + tx * 4 + j;
      const int hh = n >> 5, dd = n & 31;
      const float bb = bias[n];
      ushort4 pk;
      pk.x = f2bf(acc[0][j] + bb);
      pk.y = f2bf(acc[1][j] + bb);
      pk.z = f2bf(acc[2][j] + bb);
      pk.w = f2bf(acc[3][j] + bb);
      *reinterpret_cast<ushort4*>(
          &C[(((size_t)(bidx * NHEADS + hh)) * DKDIM + dd) * SEQ + tokb]) = pk;
    }
  }
}

// ---------------- MFMA flash attention ----------------
// grid (S/64, NHEADS, BATCH), 256 threads = 4 waves x 16 query rows.
// qb bf16 [8192][256] (k = q), vbT bf16 [b][h][32][1024]. Causal tile skip.
__global__ __launch_bounds__(256)
void attn_mfma_k(const unsigned short* __restrict__ qb,
                 const unsigned short* __restrict__ vbT,
                 const float* __restrict__ routing8, float* __restrict__ out,
                 int mask_val) {
  constexpr int RS = 72;  // LDS row stride (bf16 elems) = 144B: 16B-aligned, ~2-way banks
  __shared__ unsigned short sk[64 * RS];          // K tile, natural [key][d]
  __shared__ unsigned short svt[32 * RS];         // V^T tile [d][key]
  __shared__ unsigned short splds[4 * 16 * RS];   // per-wave P scratch
  const int b = blockIdx.z, h = blockIdx.y;
  const int q0 = blockIdx.x * 64;
  const int tid = threadIdx.x;
  const int wave = tid >> 6, lane = tid & 63;
  const int g = lane >> 4, li = lane & 15;
  const int qw = q0 + wave * 16;  // wave's first query row

  // Q fragment: A[row=li][k=g*8+j]
  const frag_bf16 qf = *reinterpret_cast<const frag_bf16*>(
      &qb[((size_t)(b * SEQ + qw + li)) * DMODEL + h * DKDIM + g * 8]);

  float mrun[4], lrun[4];
  f32x4 o0 = {0.f, 0.f, 0.f, 0.f}, o1 = {0.f, 0.f, 0.f, 0.f};
#pragma unroll
  for (int r = 0; r < 4; ++r) { mrun[r] = -INFINITY; lrun[r] = 0.f; }
  unsigned short* pl = &splds[wave * 16 * RS];

  const int ntiles = blockIdx.x + 1;
  for (int t = 0; t < ntiles; ++t) {
    const int kt = t * 64;
    __syncthreads();
    {
      const int key = tid >> 2, ch = tid & 3;
      *reinterpret_cast<frag_bf16*>(&sk[key * RS + ch * 8]) =
          *reinterpret_cast<const frag_bf16*>(
              &qb[((size_t)(b * SEQ + kt + key)) * DMODEL + h * DKDIM + ch * 8]);
      const int dr = tid >> 3, ck = tid & 7;
      *reinterpret_cast<frag_bf16*>(&svt[dr * RS + ck * 8]) =
          *reinterpret_cast<const frag_bf16*>(
              &vbT[(((size_t)(b * NHEADS + h)) * DKDIM + dr) * SEQ + kt + ck * 8]);
    }
    __syncthreads();

    // S = Q K^T : 4 MFMAs -> lane holds rows 4g+r, col kb*16+li
    f32x4 s[4];
#pragma unroll
    for (int kb = 0; kb < 4; ++kb) {
      frag_bf16 kf = *reinterpret_cast<const frag_bf16*>(&sk[(kb * 16 + li) * RS + g * 8]);
      f32x4 z = {0.f, 0.f, 0.f, 0.f};
      s[kb] = __builtin_amdgcn_mfma_f32_16x16x32_bf16(qf, kf, z, 0, 0, 0);
    }
    const bool need_mask = (kt + 63) >= (qw + mask_val);
#pragma unroll
    for (int kb = 0; kb < 4; ++kb) {
      const int col = kt + kb * 16 + li;
#pragma unroll
      for (int r = 0; r < 4; ++r) {
        float v = s[kb][r] * 0.17677669529663687f;
        if (need_mask && col >= (qw + 4 * g + r + mask_val)) v = -1e9f;
        s[kb][r] = v;
      }
    }
    // online softmax per row (reduce over 16 lanes of this group: xor<16)
    float p[4][4], scl[4];
#pragma unroll
    for (int r = 0; r < 4; ++r) {
      float tm = fmaxf(fmaxf(s[0][r], s[1][r]), fmaxf(s[2][r], s[3][r]));
#pragma unroll
      for (int mm = 8; mm >= 1; mm >>= 1) tm = fmaxf(tm, __shfl_xor(tm, mm, 64));
      const float mnew = fmaxf(mrun[r], tm);
      scl[r] = __expf(mrun[r] - mnew);
      float ps = 0.f;
#pragma unroll
      for (int kb = 0; kb < 4; ++kb) { p[kb][r] = __expf(s[kb][r] - mnew); ps += p[kb][r]; }
#pragma unroll
      for (int mm = 8; mm >= 1; mm >>= 1) ps += __shfl_xor(ps, mm, 64);
      lrun[r] = lrun[r] * scl[r] + ps;
      mrun[r] = mnew;
      o0[r] *= scl[r];
      o1[r] *= scl[r];
    }
    // P: C-layout -> A-layout via per-wave LDS (bf16)
#pragma unroll
    for (int kb = 0; kb < 4; ++kb)
#pragma unroll
      for (int r = 0; r < 4; ++r)
        pl[(4 * g + r) * RS + kb * 16 + li] = f2bf(p[kb][r]);
    __threadfence_block();
    // O += P V : A[row=li][k], B[k][d]; V[k][d] = VT[d][k] contiguous
#pragma unroll
    for (int c = 0; c < 2; ++c) {
      frag_bf16 pa = *reinterpret_cast<const frag_bf16*>(&pl[li * RS + c * 32 + g * 8]);
      frag_bf16 v0 = *reinterpret_cast<const frag_bf16*>(&svt[li * RS + c * 32 + g * 8]);
      frag_bf16 v1 = *reinterpret_cast<const frag_bf16*>(&svt[(16 + li) * RS + c * 32 + g * 8]);
      o0 = __builtin_amdgcn_mfma_f32_16x16x32_bf16(pa, v0, o0, 0, 0, 0);
      o1 = __builtin_amdgcn_mfma_f32_16x16x32_bf16(pa, v1, o1, 0, 0, 0);
    }
  }
  const float rt = routing8[b * NHEADS + h];
#pragma unroll
  for (int r = 0; r < 4; ++r) {
    const float mult = rt / lrun[r];
    const size_t row = (size_t)(b * SEQ + qw + 4 * g + r) * DMODEL + h * DKDIM;
    out[row + li] = o0[r] * mult;
    out[row + 16 + li] = o1[r] * mult;
  }
}

// For mask_val==0 the ref's row 0 is all-masked -> softmax uniform over ALL 1024
// keys. Tile-skipping breaks that one row; overwrite it with routing * mean(V).
__global__ __launch_bounds__(256)
void attn_row0_patch_k(const unsigned short* __restrict__ vbT,
                       const float* __restrict__ routing8, float* __restrict__ out) {
  const int b = blockIdx.x;
  const int t = threadIdx.x;
  const int h = t >> 5, d = t & 31;
  const unsigned short* src = &vbT[(((size_t)(b * NHEADS + h)) * DKDIM + d) * SEQ];
  float s = 0.f;
  for (int k = 0; k < SEQ; k += 8) {
    frag_bf16 v = *reinterpret_cast<const frag_bf16*>(&src[k]);
#pragma unroll
    for (int j = 0; j < 8; ++j)
      s += __uint_as_float(((unsigned)(unsigned short)v[j]) << 16);
  }
  out[(size_t)(b * SEQ) * DMODEL + h * DKDIM + d] =
      s * (1.0f / 1024.0f) * routing8[b * NHEADS + h];
}

// ---------------- Router ----------------
__global__ __launch_bounds__(128)
void router_k(const float* __restrict__ R, const float* __restrict__ Wg,
              float* __restrict__ partials) {
  __shared__ float sW[DMODEL * NDYN_C];
  __shared__ float red[18][128];
  const int tid = threadIdx.x;
  for (int t = tid; t < DMODEL * NDYN_C; t += 128) sW[t] = Wg[t];
  __syncthreads();
  const int r = blockIdx.x * 128 + tid;
  const int b = r >> 10;
  const int h = (r >> 7) & 7;
  const int s8 = r & 127;
  float lg[NDYN_C] = {};
  for (int t8 = 0; t8 < 8; ++t8) {
    const float* base = &R[((size_t)(b * SEQ + s8 * 8 + t8)) * DMODEL + h * DKDIM];
#pragma unroll
    for (int d = 0; d < DKDIM; ++d) {
      const float x = base[d];
      const float* w = &sW[(t8 * 32 + d) * NDYN_C];
#pragma unroll
      for (int j = 0; j < NDYN_C; ++j) lg[j] = fmaf(x, w[j], lg[j]);
    }
  }
  float mx = lg[0];
#pragma unroll
  for (int j = 1; j < NDYN_C; ++j) mx = fmaxf(mx, lg[j]);
  float e[NDYN_C], sum = 0.0f;
#pragma unroll
  for (int j = 0; j < NDYN_C; ++j) { e[j] = expf(lg[j] - mx); sum += e[j]; }
  float g[NDYN_C];
#pragma unroll
  for (int j = 0; j < NDYN_C; ++j) g[j] = e[j] / sum;
  int j1 = 0;
#pragma unroll
  for (int j = 1; j < NDYN_C; ++j) if (g[j] > g[j1]) j1 = j;
  int j2 = -1;
#pragma unroll
  for (int j = 0; j < NDYN_C; ++j) {
    if (j == j1) continue;
    if (j2 < 0 || g[j] > g[j2]) j2 = j;
  }
#pragma unroll
  for (int j = 0; j < NDYN_C; ++j) {
    const bool sel = (j == j1) || (j == j2);
    red[j][tid] = sel ? g[j] : 0.0f;
    red[6 + j][tid] = sel ? 1.0f : 0.0f;
    red[12 + j][tid] = g[j];
  }
  __syncthreads();
  if (tid < 18) {
    float s = 0.0f;
    for (int i = 0; i < 128; ++i) s += red[tid][i];
    partials[blockIdx.x * 18 + tid] = s;
  }
}

__global__ void router_reduce_k(const float* __restrict__ partials,
                                float* __restrict__ routing8,
                                float* __restrict__ bal_out) {
  const int tid = threadIdx.x;
  if (tid < 48) {
    const int b = tid / 6, j = tid % 6;
    float s = 0.0f;
    for (int t = 0; t < 8; ++t) s += partials[(b * 8 + t) * 18 + j];
    routing8[b * NHEADS + 2 + j] = s * (1.0f / 1024.0f);
  } else if (tid < 56) {
    const int b = tid - 48;
    routing8[b * NHEADS + 0] = 1.0f;
    routing8[b * NHEADS + 1] = 1.0f;
  } else if (tid == 56) {
    float hs[6], hp[6];
    float hssum = 0.0f, hpsum = 0.0f;
    for (int j = 0; j < 6; ++j) {
      float a = 0.0f, c = 0.0f;
      for (int bi = 0; bi < 64; ++bi) {
        a += partials[bi * 18 + 6 + j];
        c += partials[bi * 18 + 12 + j];
      }
      hs[j] = a;
      hp[j] = c * (1.0f / 8192.0f);
      hssum += hs[j];
      hpsum += hp[j];
    }
    float bal = 0.0f;
    for (int j = 0; j < 6; ++j)
      bal += (hs[j] / (hssum + 1e-5f)) * (hp[j] / (hpsum + 1e-5f));
    *bal_out = bal;
  }
}

// ---------------- residual add + layernorm (in place on X) ----------------
__global__ __launch_bounds__(256)
void add_ln_k(float* __restrict__ X, const float* __restrict__ Y,
              const float* __restrict__ g, const float* __restrict__ be) {
  const int r = blockIdx.x;
  const int c = threadIdx.x;
  const size_t idx = (size_t)r * DMODEL + c;
  const float x = X[idx] + Y[idx];
  __shared__ float sh[4];
  float s = x;
#pragma unroll
  for (int o = 32; o >= 1; o >>= 1) s += __shfl_xor(s, o, 64);
  if ((c & 63) == 0) sh[c >> 6] = s;
  __syncthreads();
  const float mean = (sh[0] + sh[1] + sh[2] + sh[3]) * (1.0f / DMODEL);
  const float d = x - mean;
  float vsum = d * d;
  __syncthreads();
#pragma unroll
  for (int o = 32; o >= 1; o >>= 1) vsum += __shfl_xor(vsum, o, 64);
  if ((c & 63) == 0) sh[c >> 6] = vsum;
  __syncthreads();
  const float var = (sh[0] + sh[1] + sh[2] + sh[3]) * (1.0f / DMODEL);
  X[idx] = d * (1.0f / sqrtf(var + 1e-5f)) * g[c] + be[c];
}

// ---------------- driver ----------------
extern "C" void kernel_launch(void* const* d_in, const int* in_sizes, int n_in,
                              void* d_out, int out_size, void* d_ws, size_t ws_size,
                              hipStream_t stream) {
  const float* q_embed  = (const float*)d_in[0];
  const float* qa_embed = (const float*)d_in[1];
  const float* Wq  = (const float*)d_in[2];
  const float* bq  = (const float*)d_in[3];
  const float* Wv  = (const float*)d_in[4];
  const float* bv  = (const float*)d_in[5];
  const float* Wg  = (const float*)d_in[6];
  const float* Wo  = (const float*)d_in[7];
  const float* bo  = (const float*)d_in[8];
  const float* ln1w = (const float*)d_in[9];
  const float* ln1b = (const float*)d_in[10];
  const float* Wf1 = (const float*)d_in[11];
  const float* bf1 = (const float*)d_in[12];
  const float* Wf2 = (const float*)d_in[13];
  const float* bf2 = (const float*)d_in[14];
  const float* ln2w = (const float*)d_in[15];
  const float* ln2b = (const float*)d_in[16];
  float* out = (float*)d_out;

  float* ws = (float*)d_ws;
  const size_t NA = (size_t)NTOK_C * DMODEL;  // 2097152
  float* xbuf = ws;
  float* ybuf = xbuf + NA;
  float* ab   = ybuf + NA;
  float* ob   = ab + NA;
  float* hb   = ob + NA;                       // NTOK * DFF
  float* routing8   = hb + (size_t)NTOK_C * DFF_C;
  float* partials   = routing8 + 64;
  float* balscratch = partials + 64 * 18;
  unsigned short* qb_bf = (unsigned short*)(balscratch + 16);
  unsigned short* vbT   = qb_bf + NA;          // bf16 [b][h][32][1024]

  hipMemcpyAsync(xbuf, q_embed, NA * sizeof(float), hipMemcpyDeviceToDevice, stream);
  hipMemcpyAsync(ybuf, qa_embed, NA * sizeof(float), hipMemcpyDeviceToDevice, stream);

  auto run_layer = [&](int l, float* Q, const float* V, const float* R,
                       int mask_val, bool ffn, bool last) {
    const float* Wq_l = Wq + (size_t)l * DMODEL * DMODEL;
    const float* bq_l = bq + (size_t)l * DMODEL;
    const float* Wv_l = Wv + (size_t)l * DMODEL * DMODEL;
    const float* bv_l = bv + (size_t)l * DMODEL;
    const float* Wg_l = Wg + (size_t)l * DMODEL * NDYN_C;
    const float* Wo_l = Wo + (size_t)l * DMODEL * DMODEL;
    const float* bo_l = bo + (size_t)l * DMODEL;
    const float* g1_l = ln1w + (size_t)l * DMODEL;
    const float* b1_l = ln1b + (size_t)l * DMODEL;

    router_k<<<64, 128, 0, stream>>>(R, Wg_l, partials);
    router_reduce_k<<<1, 64, 0, stream>>>(partials, routing8,
                                          last ? (out + NA) : balscratch);
    gemm_bias_k<2><<<dim3(DMODEL / 64, NTOK_C / 64), 256, 0, stream>>>(
        Q, Wq_l, bq_l, qb_bf, NTOK_C, DMODEL, DMODEL);
    gemm_bias_k<3><<<dim3(DMODEL / 64, NTOK_C / 64), 256, 0, stream>>>(
        V, Wv_l, bv_l, vbT, NTOK_C, DMODEL, DMODEL);
    attn_mfma_k<<<dim3(SEQ / 64, NHEADS, BATCH), 256, 0, stream>>>(
        qb_bf, vbT, routing8, ab, mask_val);
    if (mask_val == 0)
      attn_row0_patch_k<<<BATCH, 256, 0, stream>>>(vbT, routing8, ab);
    gemm_bias_k<0><<<dim3(DMODEL / 64, NTOK_C / 64), 256, 0, stream>>>(
        ab, Wo_l, bo_l, ob, NTOK_C, DMODEL, DMODEL);
    add_ln_k<<<NTOK_C, DMODEL, 0, stream>>>(Q, ob, g1_l, b1_l);
    if (ffn) {
      const float* Wf1_l = Wf1 + (size_t)l * DMODEL * DFF_C;
      const float* bf1_l = bf1 + (size_t)l * DFF_C;
      const float* Wf2_l = Wf2 + (size_t)l * DFF_C * DMODEL;
      const float* bf2_l = bf2 + (size_t)l * DMODEL;
      const float* g2_l = ln2w + (size_t)l * DMODEL;
      const float* b2_l = ln2b + (size_t)l * DMODEL;
      gemm_bias_k<1><<<dim3(DFF_C / 64, NTOK_C / 64), 256, 0, stream>>>(
          Q, Wf1_l, bf1_l, hb, NTOK_C, DFF_C, DMODEL);
      gemm_bias_k<0><<<dim3(DMODEL / 64, NTOK_C / 64), 256, 0, stream>>>(
          hb, Wf2_l, bf2_l, ob, NTOK_C, DMODEL, DFF_C);
      add_ln_k<<<NTOK_C, DMODEL, 0, stream>>>(Q, ob, g2_l, b2_l);
    }
  };

  // blocks_1: y-stream, router input = original x (q_embed)
  run_layer(0, ybuf, ybuf, xbuf, 1, true, false);
  run_layer(1, ybuf, ybuf, xbuf, 1, true, false);
  // blocks_2: (self, no FFN) then (cross to y, strict causal, FFN)
  run_layer(2, xbuf, xbuf, xbuf, 1, false, false);
  run_layer(3, xbuf, ybuf, xbuf, 0, true, false);
  run_layer(4, xbuf, xbuf, xbuf, 1, false, false);
  run_layer(5, xbuf, ybuf, xbuf, 0, true, true);

  hipMemcpyAsync(out, xbuf, NA * sizeof(float), hipMemcpyDeviceToDevice, stream);
}

// Round 3
// 852.136 us; speedup vs baseline: 3.4233x; 1.7092x over previous
//
#include <hip/hip_runtime.h>

// RouterKT forward. Round 3: all GEMMs -> bf16 MFMA (global_load_lds + XOR swizzle),
// weights pre-transposed to [N][K] bf16 per launch. Residual stream stays f32.

constexpr int DMODEL = 256;
constexpr int SEQ    = 1024;
constexpr int BATCH  = 8;
constexpr int NHEADS = 8;
constexpr int DKDIM  = 32;
constexpr int NDYN_C = 6;
constexpr int NTOK_C = BATCH * SEQ;   // 8192
constexpr int DFF_C  = 1024;

using frag_bf16 = __attribute__((ext_vector_type(8))) short;  // 8 bf16 = 4 VGPR
using f32x4    = __attribute__((ext_vector_type(4))) float;
typedef unsigned short ushort_t;

__device__ __forceinline__ ushort_t f2bf(float f) {
  unsigned u = __float_as_uint(f);
  unsigned r = (u + 0x7fffu + ((u >> 16) & 1u)) >> 16;   // RNE, finite inputs
  return (ushort_t)r;
}

#define GLOAD_LDS16(gsrc, ldst)                                             \
  __builtin_amdgcn_global_load_lds(                                         \
      (const __attribute__((address_space(1))) void*)(gsrc),                \
      (__attribute__((address_space(3))) void*)(ldst), 16, 0, 0)

// ---------------- bf16 MFMA GEMM ----------------
// C[m][n] = sum_k A[m][k] * B[n][k] + bias.   A:[M][K] bf16, B:[N][K] bf16.
// Tile: BM=128, BN=64, BK=32. 256 threads = 4 waves (2x2), wave tile 64x32.
// MODE: 0 = f32 C[M][N], 1 = bf16 C[M][N], 2 = bf16+relu, 3 = vbT scatter
//       (C rows = head*32+d, cols = tok; bias indexed by m).
template<int MODE>
__global__ __launch_bounds__(256)
void gemm_mfma_k(const ushort_t* __restrict__ A, const ushort_t* __restrict__ B,
                 const float* __restrict__ bias, void* __restrict__ Cp,
                 int M, int N, int K) {
  __shared__ ushort_t sA[128 * 32];
  __shared__ ushort_t sB[64 * 32];
  const int tid = threadIdx.x;
  const int wid = tid >> 6, lane = tid & 63;
  const int li = lane & 15, g = lane >> 4;
  const int wr = wid >> 1, wc = wid & 1;
  const int m0 = blockIdx.y * 128, n0 = blockIdx.x * 64;
  f32x4 acc[4][2] = {};
  // staging slots (16B chunks): row = slot>>2, chunk = slot&3, swizzle chunk^((row>>1)&3)
  const int ar1 = tid >> 2;
  const int ar2 = (tid + 256) >> 2;
  const int cs = tid & 3;
  ushort_t* dstA1 = sA + wid * 512;          // + lane*8 added by hardware
  ushort_t* dstA2 = sA + 2048 + wid * 512;
  ushort_t* dstB  = sB + wid * 512;
  const ushort_t* gA1 = &A[(size_t)(m0 + ar1) * K + (cs ^ ((ar1 >> 1) & 3)) * 8];
  const ushort_t* gA2 = &A[(size_t)(m0 + ar2) * K + (cs ^ ((ar2 >> 1) & 3)) * 8];
  const ushort_t* gB  = &B[(size_t)(n0 + (tid >> 2)) * K + (cs ^ (((tid >> 2) >> 1) & 3)) * 8];

  for (int k0 = 0; k0 < K; k0 += 32) {
    __syncthreads();
    GLOAD_LDS16(gA1 + k0, dstA1);
    GLOAD_LDS16(gA2 + k0, dstA2);
    GLOAD_LDS16(gB + k0, dstB);
    __syncthreads();
    frag_bf16 af[4], bf[2];
#pragma unroll
    for (int m = 0; m < 4; ++m) {
      const int row = wr * 64 + m * 16 + li;
      af[m] = *reinterpret_cast<const frag_bf16*>(&sA[(row * 4 + (g ^ ((row >> 1) & 3))) * 8]);
    }
#pragma unroll
    for (int n = 0; n < 2; ++n) {
      const int row = wc * 32 + n * 16 + li;
      bf[n] = *reinterpret_cast<const frag_bf16*>(&sB[(row * 4 + (g ^ ((row >> 1) & 3))) * 8]);
    }
#pragma unroll
    for (int m = 0; m < 4; ++m)
#pragma unroll
      for (int n = 0; n < 2; ++n)
        acc[m][n] = __builtin_amdgcn_mfma_f32_16x16x32_bf16(af[m], bf[n], acc[m][n], 0, 0, 0);
  }

#pragma unroll
  for (int m = 0; m < 4; ++m)
#pragma unroll
    for (int n = 0; n < 2; ++n)
#pragma unroll
      for (int r = 0; r < 4; ++r) {
        const int mg = m0 + wr * 64 + m * 16 + g * 4 + r;
        const int ng = n0 + wc * 32 + n * 16 + li;
        if (MODE == 0) {
          ((float*)Cp)[(size_t)mg * N + ng] = acc[m][n][r] + bias[ng];
        } else if (MODE == 1) {
          ((ushort_t*)Cp)[(size_t)mg * N + ng] = f2bf(acc[m][n][r] + bias[ng]);
        } else if (MODE == 2) {
          ((ushort_t*)Cp)[(size_t)mg * N + ng] = f2bf(fmaxf(acc[m][n][r] + bias[ng], 0.0f));
        } else {
          // rows mg = h*32+d (M=256), cols ng = global tok
          ((ushort_t*)Cp)[((size_t)((ng >> 10) * 256 + mg)) * SEQ + (ng & 1023)] =
              f2bf(acc[m][n][r] + bias[mg]);
        }
      }
}

// ---------------- weight transpose+convert: in [z][R][C] f32 -> out [z][C][R] bf16 ----
__global__ __launch_bounds__(256)
void transpose_k(const float* __restrict__ in, ushort_t* __restrict__ out, int R, int C) {
  __shared__ float t[32][33];
  const int z = blockIdx.z;
  const int c0 = blockIdx.x * 32, r0 = blockIdx.y * 32;
  const int tx = threadIdx.x & 31, ty = threadIdx.x >> 5;   // ty 0..7
  const float* ip = in + (size_t)z * R * C;
  ushort_t* op = out + (size_t)z * R * C;
#pragma unroll
  for (int i = 0; i < 4; ++i) t[ty + 8 * i][tx] = ip[(size_t)(r0 + ty + 8 * i) * C + c0 + tx];
  __syncthreads();
#pragma unroll
  for (int i = 0; i < 4; ++i)
    op[(size_t)(c0 + ty + 8 * i) * R + r0 + tx] = f2bf(t[tx][ty + 8 * i]);
}

// ---------------- f32 copy + bf16 mirror ----------------
__global__ __launch_bounds__(256)
void conv_init_k(const float* __restrict__ src, float* __restrict__ dstF,
                 ushort_t* __restrict__ dstB) {
  const int i = blockIdx.x * 256 + threadIdx.x;   // over float4 elements
  const float4 v = reinterpret_cast<const float4*>(src)[i];
  reinterpret_cast<float4*>(dstF)[i] = v;
  ushort4 b;
  b.x = f2bf(v.x); b.y = f2bf(v.y); b.z = f2bf(v.z); b.w = f2bf(v.w);
  reinterpret_cast<ushort4*>(dstB)[i] = b;
}

// ---------------- MFMA flash attention (bf16 in, bf16 out) ----------------
__global__ __launch_bounds__(256)
void attn_mfma_k(const ushort_t* __restrict__ qb, const ushort_t* __restrict__ vbT,
                 const float* __restrict__ routing8, ushort_t* __restrict__ out,
                 int mask_val) {
  constexpr int RS = 72;
  __shared__ ushort_t sk[64 * RS];
  __shared__ ushort_t svt[32 * RS];
  __shared__ ushort_t splds[4 * 16 * RS];
  const int b = blockIdx.z, h = blockIdx.y;
  const int q0 = blockIdx.x * 64;
  const int tid = threadIdx.x;
  const int wave = tid >> 6, lane = tid & 63;
  const int g = lane >> 4, li = lane & 15;
  const int qw = q0 + wave * 16;

  const frag_bf16 qf = *reinterpret_cast<const frag_bf16*>(
      &qb[((size_t)(b * SEQ + qw + li)) * DMODEL + h * DKDIM + g * 8]);

  float mrun[4], lrun[4];
  f32x4 o0 = {0.f, 0.f, 0.f, 0.f}, o1 = {0.f, 0.f, 0.f, 0.f};
#pragma unroll
  for (int r = 0; r < 4; ++r) { mrun[r] = -INFINITY; lrun[r] = 0.f; }
  ushort_t* pl = &splds[wave * 16 * RS];

  const int ntiles = blockIdx.x + 1;
  for (int t = 0; t < ntiles; ++t) {
    const int kt = t * 64;
    __syncthreads();
    {
      const int key = tid >> 2, ch = tid & 3;
      *reinterpret_cast<frag_bf16*>(&sk[key * RS + ch * 8]) =
          *reinterpret_cast<const frag_bf16*>(
              &qb[((size_t)(b * SEQ + kt + key)) * DMODEL + h * DKDIM + ch * 8]);
      const int dr = tid >> 3, ck = tid & 7;
      *reinterpret_cast<frag_bf16*>(&svt[dr * RS + ck * 8]) =
          *reinterpret_cast<const frag_bf16*>(
              &vbT[(((size_t)(b * NHEADS + h)) * DKDIM + dr) * SEQ + kt + ck * 8]);
    }
    __syncthreads();

    f32x4 s[4];
#pragma unroll
    for (int kb = 0; kb < 4; ++kb) {
      frag_bf16 kf = *reinterpret_cast<const frag_bf16*>(&sk[(kb * 16 + li) * RS + g * 8]);
      f32x4 z = {0.f, 0.f, 0.f, 0.f};
      s[kb] = __builtin_amdgcn_mfma_f32_16x16x32_bf16(qf, kf, z, 0, 0, 0);
    }
    const bool need_mask = (kt + 63) >= (qw + mask_val);
#pragma unroll
    for (int kb = 0; kb < 4; ++kb) {
      const int col = kt + kb * 16 + li;
#pragma unroll
      for (int r = 0; r < 4; ++r) {
        float v = s[kb][r] * 0.17677669529663687f;
        if (need_mask && col >= (qw + 4 * g + r + mask_val)) v = -1e9f;
        s[kb][r] = v;
      }
    }
    float p[4][4], scl[4];
#pragma unroll
    for (int r = 0; r < 4; ++r) {
      float tm = fmaxf(fmaxf(s[0][r], s[1][r]), fmaxf(s[2][r], s[3][r]));
#pragma unroll
      for (int mm = 8; mm >= 1; mm >>= 1) tm = fmaxf(tm, __shfl_xor(tm, mm, 64));
      const float mnew = fmaxf(mrun[r], tm);
      scl[r] = __expf(mrun[r] - mnew);
      float ps = 0.f;
#pragma unroll
      for (int kb = 0; kb < 4; ++kb) { p[kb][r] = __expf(s[kb][r] - mnew); ps += p[kb][r]; }
#pragma unroll
      for (int mm = 8; mm >= 1; mm >>= 1) ps += __shfl_xor(ps, mm, 64);
      lrun[r] = lrun[r] * scl[r] + ps;
      mrun[r] = mnew;
      o0[r] *= scl[r];
      o1[r] *= scl[r];
    }
#pragma unroll
    for (int kb = 0; kb < 4; ++kb)
#pragma unroll
      for (int r = 0; r < 4; ++r)
        pl[(4 * g + r) * RS + kb * 16 + li] = f2bf(p[kb][r]);
    __threadfence_block();
#pragma unroll
    for (int c = 0; c < 2; ++c) {
      frag_bf16 pa = *reinterpret_cast<const frag_bf16*>(&pl[li * RS + c * 32 + g * 8]);
      frag_bf16 v0 = *reinterpret_cast<const frag_bf16*>(&svt[li * RS + c * 32 + g * 8]);
      frag_bf16 v1 = *reinterpret_cast<const frag_bf16*>(&svt[(16 + li) * RS + c * 32 + g * 8]);
      o0 = __builtin_amdgcn_mfma_f32_16x16x32_bf16(pa, v0, o0, 0, 0, 0);
      o1 = __builtin_amdgcn_mfma_f32_16x16x32_bf16(pa, v1, o1, 0, 0, 0);
    }
  }
  const float rt = routing8[b * NHEADS + h];
#pragma unroll
  for (int r = 0; r < 4; ++r) {
    const float mult = rt / lrun[r];
    const size_t row = (size_t)(b * SEQ + qw + 4 * g + r) * DMODEL + h * DKDIM;
    out[row + li] = f2bf(o0[r] * mult);
    out[row + 16 + li] = f2bf(o1[r] * mult);
  }
}

// mask_val==0 row 0: ref softmax degenerates to uniform over ALL keys.
__global__ __launch_bounds__(256)
void attn_row0_patch_k(const ushort_t* __restrict__ vbT,
                       const float* __restrict__ routing8, ushort_t* __restrict__ out) {
  const int b = blockIdx.x;
  const int t = threadIdx.x;
  const int h = t >> 5, d = t & 31;
  const ushort_t* src = &vbT[(((size_t)(b * NHEADS + h)) * DKDIM + d) * SEQ];
  float s = 0.f;
  for (int k = 0; k < SEQ; k += 8) {
    frag_bf16 v = *reinterpret_cast<const frag_bf16*>(&src[k]);
#pragma unroll
    for (int j = 0; j < 8; ++j)
      s += __uint_as_float(((unsigned)(ushort_t)v[j]) << 16);
  }
  out[(size_t)(b * SEQ) * DMODEL + h * DKDIM + d] =
      f2bf(s * (1.0f / 1024.0f) * routing8[b * NHEADS + h]);
}

// ---------------- Router ----------------
__global__ __launch_bounds__(128)
void router_k(const float* __restrict__ R, const float* __restrict__ Wg,
              float* __restrict__ partials) {
  __shared__ float sW[DMODEL * NDYN_C];
  __shared__ float red[18][128];
  const int tid = threadIdx.x;
  for (int t = tid; t < DMODEL * NDYN_C; t += 128) sW[t] = Wg[t];
  __syncthreads();
  const int r = blockIdx.x * 128 + tid;
  const int b = r >> 10;
  const int h = (r >> 7) & 7;
  const int s8 = r & 127;
  float lg[NDYN_C] = {};
  for (int t8 = 0; t8 < 8; ++t8) {
    const float* base = &R[((size_t)(b * SEQ + s8 * 8 + t8)) * DMODEL + h * DKDIM];
#pragma unroll
    for (int d = 0; d < DKDIM; ++d) {
      const float x = base[d];
      const float* w = &sW[(t8 * 32 + d) * NDYN_C];
#pragma unroll
      for (int j = 0; j < NDYN_C; ++j) lg[j] = fmaf(x, w[j], lg[j]);
    }
  }
  float mx = lg[0];
#pragma unroll
  for (int j = 1; j < NDYN_C; ++j) mx = fmaxf(mx, lg[j]);
  float e[NDYN_C], sum = 0.0f;
#pragma unroll
  for (int j = 0; j < NDYN_C; ++j) { e[j] = expf(lg[j] - mx); sum += e[j]; }
  float g[NDYN_C];
#pragma unroll
  for (int j = 0; j < NDYN_C; ++j) g[j] = e[j] / sum;
  int j1 = 0;
#pragma unroll
  for (int j = 1; j < NDYN_C; ++j) if (g[j] > g[j1]) j1 = j;
  int j2 = -1;
#pragma unroll
  for (int j = 0; j < NDYN_C; ++j) {
    if (j == j1) continue;
    if (j2 < 0 || g[j] > g[j2]) j2 = j;
  }
#pragma unroll
  for (int j = 0; j < NDYN_C; ++j) {
    const bool sel = (j == j1) || (j == j2);
    red[j][tid] = sel ? g[j] : 0.0f;
    red[6 + j][tid] = sel ? 1.0f : 0.0f;
    red[12 + j][tid] = g[j];
  }
  __syncthreads();
  if (tid < 18) {
    float s = 0.0f;
    for (int i = 0; i < 128; ++i) s += red[tid][i];
    partials[blockIdx.x * 18 + tid] = s;
  }
}

__global__ void router_reduce_k(const float* __restrict__ partials,
                                float* __restrict__ routing8,
                                float* __restrict__ bal_out) {
  const int tid = threadIdx.x;
  if (tid < 48) {
    const int b = tid / 6, j = tid % 6;
    float s = 0.0f;
    for (int t = 0; t < 8; ++t) s += partials[(b * 8 + t) * 18 + j];
    routing8[b * NHEADS + 2 + j] = s * (1.0f / 1024.0f);
  } else if (tid < 56) {
    const int b = tid - 48;
    routing8[b * NHEADS + 0] = 1.0f;
    routing8[b * NHEADS + 1] = 1.0f;
  } else if (tid == 56) {
    float hs[6], hp[6];
    float hssum = 0.0f, hpsum = 0.0f;
    for (int j = 0; j < 6; ++j) {
      float a = 0.0f, c = 0.0f;
      for (int bi = 0; bi < 64; ++bi) {
        a += partials[bi * 18 + 6 + j];
        c += partials[bi * 18 + 12 + j];
      }
      hs[j] = a;
      hp[j] = c * (1.0f / 8192.0f);
      hssum += hs[j];
      hpsum += hp[j];
    }
    float bal = 0.0f;
    for (int j = 0; j < 6; ++j)
      bal += (hs[j] / (hssum + 1e-5f)) * (hp[j] / (hpsum + 1e-5f));
    *bal_out = bal;
  }
}

// ---------------- residual add + layernorm (in place, dual write f32+bf16) ----
__global__ __launch_bounds__(256)
void add_ln_k(float* __restrict__ X, ushort_t* __restrict__ Xbf,
              const float* __restrict__ Y,
              const float* __restrict__ g, const float* __restrict__ be) {
  const int r = blockIdx.x;
  const int c = threadIdx.x;
  const size_t idx = (size_t)r * DMODEL + c;
  const float x = X[idx] + Y[idx];
  __shared__ float sh[4];
  float s = x;
#pragma unroll
  for (int o = 32; o >= 1; o >>= 1) s += __shfl_xor(s, o, 64);
  if ((c & 63) == 0) sh[c >> 6] = s;
  __syncthreads();
  const float mean = (sh[0] + sh[1] + sh[2] + sh[3]) * (1.0f / DMODEL);
  const float d = x - mean;
  float vsum = d * d;
  __syncthreads();
#pragma unroll
  for (int o = 32; o >= 1; o >>= 1) vsum += __shfl_xor(vsum, o, 64);
  if ((c & 63) == 0) sh[c >> 6] = vsum;
  __syncthreads();
  const float var = (sh[0] + sh[1] + sh[2] + sh[3]) * (1.0f / DMODEL);
  const float rv = d * (1.0f / sqrtf(var + 1e-5f)) * g[c] + be[c];
  X[idx] = rv;
  Xbf[idx] = f2bf(rv);
}

// ---------------- driver ----------------
extern "C" void kernel_launch(void* const* d_in, const int* in_sizes, int n_in,
                              void* d_out, int out_size, void* d_ws, size_t ws_size,
                              hipStream_t stream) {
  const float* q_embed  = (const float*)d_in[0];
  const float* qa_embed = (const float*)d_in[1];
  const float* Wq  = (const float*)d_in[2];
  const float* bq  = (const float*)d_in[3];
  const float* Wv  = (const float*)d_in[4];
  const float* bv  = (const float*)d_in[5];
  const float* Wg  = (const float*)d_in[6];
  const float* Wo  = (const float*)d_in[7];
  const float* bo  = (const float*)d_in[8];
  const float* ln1w = (const float*)d_in[9];
  const float* ln1b = (const float*)d_in[10];
  const float* Wf1 = (const float*)d_in[11];
  const float* bf1 = (const float*)d_in[12];
  const float* Wf2 = (const float*)d_in[13];
  const float* bf2 = (const float*)d_in[14];
  const float* ln2w = (const float*)d_in[15];
  const float* ln2b = (const float*)d_in[16];
  float* out = (float*)d_out;

  const size_t NA = (size_t)NTOK_C * DMODEL;  // 2097152
  float* xbuf = (float*)d_ws;
  float* ybuf = xbuf + NA;
  float* ob   = ybuf + NA;
  float* routing8   = ob + NA;
  float* partials   = routing8 + 64;
  float* balscratch = partials + 64 * 18;
  ushort_t* xbf   = (ushort_t*)(balscratch + 16);
  ushort_t* ybf   = xbf + NA;
  ushort_t* qb_bf = ybf + NA;
  ushort_t* vbT   = qb_bf + NA;
  ushort_t* ab_bf = vbT + NA;
  ushort_t* hb    = ab_bf + NA;                       // NTOK * DFF bf16
  ushort_t* WqT   = hb + (size_t)NTOK_C * DFF_C;
  ushort_t* WvT   = WqT + (size_t)6 * DMODEL * DMODEL;
  ushort_t* WoT   = WvT + (size_t)6 * DMODEL * DMODEL;
  ushort_t* Wf1T  = WoT + (size_t)6 * DMODEL * DMODEL;
  ushort_t* Wf2T  = Wf1T + (size_t)6 * DMODEL * DFF_C;

  // weight prep
  transpose_k<<<dim3(8, 8, 6), 256, 0, stream>>>(Wq, WqT, DMODEL, DMODEL);
  transpose_k<<<dim3(8, 8, 6), 256, 0, stream>>>(Wv, WvT, DMODEL, DMODEL);
  transpose_k<<<dim3(8, 8, 6), 256, 0, stream>>>(Wo, WoT, DMODEL, DMODEL);
  transpose_k<<<dim3(32, 8, 6), 256, 0, stream>>>(Wf1, Wf1T, DMODEL, DFF_C);
  transpose_k<<<dim3(8, 32, 6), 256, 0, stream>>>(Wf2, Wf2T, DFF_C, DMODEL);
  conv_init_k<<<NA / 1024, 256, 0, stream>>>(q_embed, xbuf, xbf);
  conv_init_k<<<NA / 1024, 256, 0, stream>>>(qa_embed, ybuf, ybf);

  auto run_layer = [&](int l, float* Q, ushort_t* Qbf, const ushort_t* Vbf,
                       int mask_val, bool ffn, bool last) {
    const float* bq_l = bq + (size_t)l * DMODEL;
    const float* bv_l = bv + (size_t)l * DMODEL;
    const float* Wg_l = Wg + (size_t)l * DMODEL * NDYN_C;
    const float* bo_l = bo + (size_t)l * DMODEL;
    const float* g1_l = ln1w + (size_t)l * DMODEL;
    const float* b1_l = ln1b + (size_t)l * DMODEL;
    const ushort_t* WqT_l = WqT + (size_t)l * DMODEL * DMODEL;
    const ushort_t* WvT_l = WvT + (size_t)l * DMODEL * DMODEL;
    const ushort_t* WoT_l = WoT + (size_t)l * DMODEL * DMODEL;

    router_k<<<64, 128, 0, stream>>>(xbuf, Wg_l, partials);
    router_reduce_k<<<1, 64, 0, stream>>>(partials, routing8,
                                          last ? (out + NA) : balscratch);
    gemm_mfma_k<1><<<dim3(4, 64), 256, 0, stream>>>(
        Qbf, WqT_l, bq_l, qb_bf, NTOK_C, DMODEL, DMODEL);
    gemm_mfma_k<3><<<dim3(128, 2), 256, 0, stream>>>(
        WvT_l, Vbf, bv_l, vbT, DMODEL, NTOK_C, DMODEL);
    attn_mfma_k<<<dim3(SEQ / 64, NHEADS, BATCH), 256, 0, stream>>>(
        qb_bf, vbT, routing8, ab_bf, mask_val);
    if (mask_val == 0)
      attn_row0_patch_k<<<BATCH, 256, 0, stream>>>(vbT, routing8, ab_bf);
    gemm_mfma_k<0><<<dim3(4, 64), 256, 0, stream>>>(
        ab_bf, WoT_l, bo_l, ob, NTOK_C, DMODEL, DMODEL);
    add_ln_k<<<NTOK_C, DMODEL, 0, stream>>>(Q, Qbf, ob, g1_l, b1_l);
    if (ffn) {
      const float* bf1_l = bf1 + (size_t)l * DFF_C;
      const float* bf2_l = bf2 + (size_t)l * DMODEL;
      const float* g2_l = ln2w + (size_t)l * DMODEL;
      const float* b2_l = ln2b + (size_t)l * DMODEL;
      const ushort_t* Wf1T_l = Wf1T + (size_t)l * DMODEL * DFF_C;
      const ushort_t* Wf2T_l = Wf2T + (size_t)l * DFF_C * DMODEL;
      gemm_mfma_k<2><<<dim3(16, 64), 256, 0, stream>>>(
          Qbf, Wf1T_l, bf1_l, hb, NTOK_C, DFF_C, DMODEL);
      gemm_mfma_k<0><<<dim3(4, 64), 256, 0, stream>>>(
          hb, Wf2T_l, bf2_l, ob, NTOK_C, DMODEL, DFF_C);
      add_ln_k<<<NTOK_C, DMODEL, 0, stream>>>(Q, Qbf, ob, g2_l, b2_l);
    }
  };

  // blocks_1: y-stream, router input = x (q_embed, unchanged during blocks_1)
  run_layer(0, ybuf, ybf, ybf, 1, true, false);
  run_layer(1, ybuf, ybf, ybf, 1, true, false);
  // blocks_2: (self, no FFN) then (cross to y, strict causal, FFN)
  run_layer(2, xbuf, xbf, xbf, 1, false, false);
  run_layer(3, xbuf, xbf, ybf, 0, true, false);
  run_layer(4, xbuf, xbf, xbf, 1, false, false);
  run_layer(5, xbuf, xbf, ybf, 0, true, true);

  hipMemcpyAsync(out, xbuf, NA * sizeof(float), hipMemcpyDeviceToDevice, stream);
}

// Round 4
// 803.768 us; speedup vs baseline: 3.6293x; 1.0602x over previous
//
#include <hip/hip_runtime.h>

// RouterKT forward. Round 4: attn XCD-locality remap + fragment-linear LDS
// (conflict-free ds_read_b128) + GEMM retile 64x64xBK64 for multi-block/CU overlap.

constexpr int DMODEL = 256;
constexpr int SEQ    = 1024;
constexpr int BATCH  = 8;
constexpr int NHEADS = 8;
constexpr int DKDIM  = 32;
constexpr int NDYN_C = 6;
constexpr int NTOK_C = BATCH * SEQ;   // 8192
constexpr int DFF_C  = 1024;

using frag_bf16 = __attribute__((ext_vector_type(8))) short;  // 8 bf16 = 4 VGPR
using f32x4    = __attribute__((ext_vector_type(4))) float;
typedef unsigned short ushort_t;

__device__ __forceinline__ ushort_t f2bf(float f) {
  unsigned u = __float_as_uint(f);
  unsigned r = (u + 0x7fffu + ((u >> 16) & 1u)) >> 16;   // RNE, finite inputs
  return (ushort_t)r;
}

#define GLOAD_LDS16(gsrc, ldst)                                             \
  __builtin_amdgcn_global_load_lds(                                         \
      (const __attribute__((address_space(1))) void*)(gsrc),                \
      (__attribute__((address_space(3))) void*)(ldst), 16, 0, 0)

// ---------------- bf16 MFMA GEMM ----------------
// C[m][n] = sum_k A[m][k] * B[n][k] + bias.   A:[M][K] bf16, B:[N][K] bf16.
// Tile: BM=64, BN=64, BK=64. 256 threads = 4 waves (2x2), wave tile 32x32.
// LDS layout: [row][64 elems], 16B chunk at slot s holds global chunk s^(row&7).
// MODE: 0 = f32 C[M][N], 1 = bf16 C[M][N], 2 = bf16+relu, 3 = vbT scatter
//       (C rows = head*32+d, cols = tok; bias indexed by m).
template<int MODE>
__global__ __launch_bounds__(256)
void gemm_mfma_k(const ushort_t* __restrict__ A, const ushort_t* __restrict__ B,
                 const float* __restrict__ bias, void* __restrict__ Cp,
                 int M, int N, int K) {
  __shared__ ushort_t sA[64 * 64];
  __shared__ ushort_t sB[64 * 64];
  const int tid = threadIdx.x;
  const int wid = tid >> 6, lane = tid & 63;
  const int li = lane & 15, g = lane >> 4;
  const int wr = wid >> 1, wc = wid & 1;
  const int m0 = blockIdx.y * 64, n0 = blockIdx.x * 64;
  f32x4 acc[2][2] = {};
  // staging: gload #1 covers rows wid*8+(lane>>3) (rows 0..31), #2 rows +32.
  // dest is wave-uniform base + lane*16 (hardware); slot = lane&7 holds
  // global chunk (lane&7)^(lane>>3)  [row&7 == lane>>3].
  const int srow = wid * 8 + (lane >> 3);
  const int schk = (lane & 7) ^ (lane >> 3);
  const ushort_t* gA1 = &A[(size_t)(m0 + srow) * K + schk * 8];
  const ushort_t* gA2 = &A[(size_t)(m0 + 32 + srow) * K + schk * 8];
  const ushort_t* gB1 = &B[(size_t)(n0 + srow) * K + schk * 8];
  const ushort_t* gB2 = &B[(size_t)(n0 + 32 + srow) * K + schk * 8];
  ushort_t* dA1 = sA + wid * 512;
  ushort_t* dA2 = sA + 2048 + wid * 512;
  ushort_t* dB1 = sB + wid * 512;
  ushort_t* dB2 = sB + 2048 + wid * 512;

  for (int k0 = 0; k0 < K; k0 += 64) {
    __syncthreads();
    GLOAD_LDS16(gA1 + k0, dA1);
    GLOAD_LDS16(gA2 + k0, dA2);
    GLOAD_LDS16(gB1 + k0, dB1);
    GLOAD_LDS16(gB2 + k0, dB2);
    __syncthreads();
#pragma unroll
    for (int s = 0; s < 2; ++s) {
      frag_bf16 af[2], bf[2];
#pragma unroll
      for (int m = 0; m < 2; ++m) {
        const int row = wr * 32 + m * 16 + li;
        af[m] = *reinterpret_cast<const frag_bf16*>(
            &sA[row * 64 + ((s * 4 + g) ^ (row & 7)) * 8]);
      }
#pragma unroll
      for (int n = 0; n < 2; ++n) {
        const int row = wc * 32 + n * 16 + li;
        bf[n] = *reinterpret_cast<const frag_bf16*>(
            &sB[row * 64 + ((s * 4 + g) ^ (row & 7)) * 8]);
      }
#pragma unroll
      for (int m = 0; m < 2; ++m)
#pragma unroll
        for (int n = 0; n < 2; ++n)
          acc[m][n] = __builtin_amdgcn_mfma_f32_16x16x32_bf16(af[m], bf[n], acc[m][n], 0, 0, 0);
    }
  }

#pragma unroll
  for (int m = 0; m < 2; ++m)
#pragma unroll
    for (int n = 0; n < 2; ++n)
#pragma unroll
      for (int r = 0; r < 4; ++r) {
        const int mg = m0 + wr * 32 + m * 16 + g * 4 + r;
        const int ng = n0 + wc * 32 + n * 16 + li;
        if (MODE == 0) {
          ((float*)Cp)[(size_t)mg * N + ng] = acc[m][n][r] + bias[ng];
        } else if (MODE == 1) {
          ((ushort_t*)Cp)[(size_t)mg * N + ng] = f2bf(acc[m][n][r] + bias[ng]);
        } else if (MODE == 2) {
          ((ushort_t*)Cp)[(size_t)mg * N + ng] = f2bf(fmaxf(acc[m][n][r] + bias[ng], 0.0f));
        } else {
          ((ushort_t*)Cp)[((size_t)((ng >> 10) * 256 + mg)) * SEQ + (ng & 1023)] =
              f2bf(acc[m][n][r] + bias[mg]);
        }
      }
}

// ---------------- weight transpose+convert: in [z][R][C] f32 -> out [z][C][R] bf16 ----
__global__ __launch_bounds__(256)
void transpose_k(const float* __restrict__ in, ushort_t* __restrict__ out, int R, int C) {
  __shared__ float t[32][33];
  const int z = blockIdx.z;
  const int c0 = blockIdx.x * 32, r0 = blockIdx.y * 32;
  const int tx = threadIdx.x & 31, ty = threadIdx.x >> 5;   // ty 0..7
  const float* ip = in + (size_t)z * R * C;
  ushort_t* op = out + (size_t)z * R * C;
#pragma unroll
  for (int i = 0; i < 4; ++i) t[ty + 8 * i][tx] = ip[(size_t)(r0 + ty + 8 * i) * C + c0 + tx];
  __syncthreads();
#pragma unroll
  for (int i = 0; i < 4; ++i)
    op[(size_t)(c0 + ty + 8 * i) * R + r0 + tx] = f2bf(t[tx][ty + 8 * i]);
}

// ---------------- f32 copy + bf16 mirror ----------------
__global__ __launch_bounds__(256)
void conv_init_k(const float* __restrict__ src, float* __restrict__ dstF,
                 ushort_t* __restrict__ dstB) {
  const int i = blockIdx.x * 256 + threadIdx.x;   // over float4 elements
  const float4 v = reinterpret_cast<const float4*>(src)[i];
  reinterpret_cast<float4*>(dstF)[i] = v;
  ushort4 b;
  b.x = f2bf(v.x); b.y = f2bf(v.y); b.z = f2bf(v.z); b.w = f2bf(v.w);
  reinterpret_cast<ushort4*>(dstB)[i] = b;
}

// ---------------- MFMA flash attention ----------------
// 1D grid of 1024: xcd = gid&7 -> batch (XCD-local K/V), slot = gid>>3:
// h = slot>>4, qblk = slot&15. Fragment-linear LDS: conflict-free b128 reads.
__global__ __launch_bounds__(256)
void attn_mfma_k(const ushort_t* __restrict__ qb, const ushort_t* __restrict__ vbT,
                 const float* __restrict__ routing8, ushort_t* __restrict__ out,
                 int mask_val) {
  __shared__ ushort_t sk2[2048];    // [kb 4][g 4][li 16][8]
  __shared__ ushort_t svt2[4096];   // [set 2][c 2][g 4][li 16][8]
  __shared__ ushort_t plf4[4 * 1024];  // per wave [c 2][g 4][q 16][8]
  const int gid = blockIdx.x;
  const int b = gid & 7;
  const int slot = gid >> 3;
  const int h = (slot >> 4) & 7;
  const int qblk = slot & 15;
  const int q0 = qblk * 64;
  const int tid = threadIdx.x;
  const int wave = tid >> 6, lane = tid & 63;
  const int g = lane >> 4, li = lane & 15;
  const int qw = q0 + wave * 16;

  const frag_bf16 qf = *reinterpret_cast<const frag_bf16*>(
      &qb[((size_t)(b * SEQ + qw + li)) * DMODEL + h * DKDIM + g * 8]);

  float mrun[4], lrun[4];
  f32x4 o0 = {0.f, 0.f, 0.f, 0.f}, o1 = {0.f, 0.f, 0.f, 0.f};
#pragma unroll
  for (int r = 0; r < 4; ++r) { mrun[r] = -INFINITY; lrun[r] = 0.f; }
  ushort_t* pl = &plf4[wave * 1024];

  // staging sources (linear LDS dest = wave base + lane*16):
  // sk2 unit = wave*64+lane -> kb=wave, g=lane>>4, li=lane&15
  const ushort_t* gK = &qb[((size_t)(b * SEQ + wave * 16 + li)) * DMODEL + h * DKDIM + g * 8];
  // svt2 unit = wave*64+lane -> set=wave>>1, c=wave&1, g=lane>>4, li=lane&15
  const ushort_t* gV = &vbT[(((size_t)(b * NHEADS + h)) * DKDIM + (wave >> 1) * 16 + li) * SEQ
                            + (wave & 1) * 32 + g * 8];
  ushort_t* dK = sk2 + wave * 512;
  ushort_t* dV = svt2 + wave * 512;

  const int ntiles = qblk + 1;
  for (int t = 0; t < ntiles; ++t) {
    const int kt = t * 64;
    __syncthreads();
    GLOAD_LDS16(gK + (size_t)kt * DMODEL, dK);
    GLOAD_LDS16(gV + kt, dV);
    __syncthreads();

    // S = Q K^T
    f32x4 s[4];
#pragma unroll
    for (int kb = 0; kb < 4; ++kb) {
      frag_bf16 kf = *reinterpret_cast<const frag_bf16*>(&sk2[(kb * 64 + g * 16 + li) * 8]);
      f32x4 z = {0.f, 0.f, 0.f, 0.f};
      s[kb] = __builtin_amdgcn_mfma_f32_16x16x32_bf16(qf, kf, z, 0, 0, 0);
    }
    const bool need_mask = (kt + 63) >= (qw + mask_val);
#pragma unroll
    for (int kb = 0; kb < 4; ++kb) {
      const int col = kt + kb * 16 + li;
#pragma unroll
      for (int r = 0; r < 4; ++r) {
        float v = s[kb][r] * 0.17677669529663687f;
        if (need_mask && col >= (qw + 4 * g + r + mask_val)) v = -1e9f;
        s[kb][r] = v;
      }
    }
    // online softmax per row (reduce over li lanes: xor 1..8)
    float p[4][4], scl[4];
#pragma unroll
    for (int r = 0; r < 4; ++r) {
      float tm = fmaxf(fmaxf(s[0][r], s[1][r]), fmaxf(s[2][r], s[3][r]));
#pragma unroll
      for (int mm = 8; mm >= 1; mm >>= 1) tm = fmaxf(tm, __shfl_xor(tm, mm, 64));
      const float mnew = fmaxf(mrun[r], tm);
      scl[r] = __expf(mrun[r] - mnew);
      float ps = 0.f;
#pragma unroll
      for (int kb = 0; kb < 4; ++kb) { p[kb][r] = __expf(s[kb][r] - mnew); ps += p[kb][r]; }
#pragma unroll
      for (int mm = 8; mm >= 1; mm >>= 1) ps += __shfl_xor(ps, mm, 64);
      lrun[r] = lrun[r] * scl[r] + ps;
      mrun[r] = mnew;
      o0[r] *= scl[r];
      o1[r] *= scl[r];
    }
    // P: C-layout -> fragment-linear A-layout (per-wave scratch)
#pragma unroll
    for (int kb = 0; kb < 4; ++kb) {
      const int k = kb * 16 + li;
      const int c = k >> 5, g2 = (k >> 3) & 3, j = k & 7;
#pragma unroll
      for (int r = 0; r < 4; ++r)
        pl[((c * 4 + g2) * 16 + 4 * g + r) * 8 + j] = f2bf(p[kb][r]);
    }
    __threadfence_block();
    // O += P V
#pragma unroll
    for (int c = 0; c < 2; ++c) {
      frag_bf16 pa = *reinterpret_cast<const frag_bf16*>(&pl[((c * 4 + g) * 16 + li) * 8]);
      frag_bf16 v0 = *reinterpret_cast<const frag_bf16*>(&svt2[(c * 64 + g * 16 + li) * 8]);
      frag_bf16 v1 = *reinterpret_cast<const frag_bf16*>(&svt2[(128 + c * 64 + g * 16 + li) * 8]);
      o0 = __builtin_amdgcn_mfma_f32_16x16x32_bf16(pa, v0, o0, 0, 0, 0);
      o1 = __builtin_amdgcn_mfma_f32_16x16x32_bf16(pa, v1, o1, 0, 0, 0);
    }
  }
  const float rt = routing8[b * NHEADS + h];
#pragma unroll
  for (int r = 0; r < 4; ++r) {
    const float mult = rt / lrun[r];
    const size_t row = (size_t)(b * SEQ + qw + 4 * g + r) * DMODEL + h * DKDIM;
    out[row + li] = f2bf(o0[r] * mult);
    out[row + 16 + li] = f2bf(o1[r] * mult);
  }
}

// mask_val==0 row 0: ref softmax degenerates to uniform over ALL keys.
__global__ __launch_bounds__(256)
void attn_row0_patch_k(const ushort_t* __restrict__ vbT,
                       const float* __restrict__ routing8, ushort_t* __restrict__ out) {
  const int b = blockIdx.x;
  const int t = threadIdx.x;
  const int h = t >> 5, d = t & 31;
  const ushort_t* src = &vbT[(((size_t)(b * NHEADS + h)) * DKDIM + d) * SEQ];
  float s = 0.f;
  for (int k = 0; k < SEQ; k += 8) {
    frag_bf16 v = *reinterpret_cast<const frag_bf16*>(&src[k]);
#pragma unroll
    for (int j = 0; j < 8; ++j)
      s += __uint_as_float(((unsigned)(ushort_t)v[j]) << 16);
  }
  out[(size_t)(b * SEQ) * DMODEL + h * DKDIM + d] =
      f2bf(s * (1.0f / 1024.0f) * routing8[b * NHEADS + h]);
}

// ---------------- Router ----------------
__global__ __launch_bounds__(128)
void router_k(const float* __restrict__ R, const float* __restrict__ Wg,
              float* __restrict__ partials) {
  __shared__ float sW[DMODEL * NDYN_C];
  __shared__ float red[18][128];
  const int tid = threadIdx.x;
  for (int t = tid; t < DMODEL * NDYN_C; t += 128) sW[t] = Wg[t];
  __syncthreads();
  const int r = blockIdx.x * 128 + tid;
  const int b = r >> 10;
  const int h = (r >> 7) & 7;
  const int s8 = r & 127;
  float lg[NDYN_C] = {};
  for (int t8 = 0; t8 < 8; ++t8) {
    const float* base = &R[((size_t)(b * SEQ + s8 * 8 + t8)) * DMODEL + h * DKDIM];
#pragma unroll
    for (int d = 0; d < DKDIM; ++d) {
      const float x = base[d];
      const float* w = &sW[(t8 * 32 + d) * NDYN_C];
#pragma unroll
      for (int j = 0; j < NDYN_C; ++j) lg[j] = fmaf(x, w[j], lg[j]);
    }
  }
  float mx = lg[0];
#pragma unroll
  for (int j = 1; j < NDYN_C; ++j) mx = fmaxf(mx, lg[j]);
  float e[NDYN_C], sum = 0.0f;
#pragma unroll
  for (int j = 0; j < NDYN_C; ++j) { e[j] = expf(lg[j] - mx); sum += e[j]; }
  float g[NDYN_C];
#pragma unroll
  for (int j = 0; j < NDYN_C; ++j) g[j] = e[j] / sum;
  int j1 = 0;
#pragma unroll
  for (int j = 1; j < NDYN_C; ++j) if (g[j] > g[j1]) j1 = j;
  int j2 = -1;
#pragma unroll
  for (int j = 0; j < NDYN_C; ++j) {
    if (j == j1) continue;
    if (j2 < 0 || g[j] > g[j2]) j2 = j;
  }
#pragma unroll
  for (int j = 0; j < NDYN_C; ++j) {
    const bool sel = (j == j1) || (j == j2);
    red[j][tid] = sel ? g[j] : 0.0f;
    red[6 + j][tid] = sel ? 1.0f : 0.0f;
    red[12 + j][tid] = g[j];
  }
  __syncthreads();
  if (tid < 18) {
    float s = 0.0f;
    for (int i = 0; i < 128; ++i) s += red[tid][i];
    partials[blockIdx.x * 18 + tid] = s;
  }
}

__global__ void router_reduce_k(const float* __restrict__ partials,
                                float* __restrict__ routing8,
                                float* __restrict__ bal_out) {
  const int tid = threadIdx.x;
  if (tid < 48) {
    const int b = tid / 6, j = tid % 6;
    float s = 0.0f;
    for (int t = 0; t < 8; ++t) s += partials[(b * 8 + t) * 18 + j];
    routing8[b * NHEADS + 2 + j] = s * (1.0f / 1024.0f);
  } else if (tid < 56) {
    const int b = tid - 48;
    routing8[b * NHEADS + 0] = 1.0f;
    routing8[b * NHEADS + 1] = 1.0f;
  } else if (tid == 56) {
    float hs[6], hp[6];
    float hssum = 0.0f, hpsum = 0.0f;
    for (int j = 0; j < 6; ++j) {
      float a = 0.0f, c = 0.0f;
      for (int bi = 0; bi < 64; ++bi) {
        a += partials[bi * 18 + 6 + j];
        c += partials[bi * 18 + 12 + j];
      }
      hs[j] = a;
      hp[j] = c * (1.0f / 8192.0f);
      hssum += hs[j];
      hpsum += hp[j];
    }
    float bal = 0.0f;
    for (int j = 0; j < 6; ++j)
      bal += (hs[j] / (hssum + 1e-5f)) * (hp[j] / (hpsum + 1e-5f));
    *bal_out = bal;
  }
}

// ---------------- residual add + layernorm (in place, dual write f32+bf16) ----
__global__ __launch_bounds__(256)
void add_ln_k(float* __restrict__ X, ushort_t* __restrict__ Xbf,
              const float* __restrict__ Y,
              const float* __restrict__ g, const float* __restrict__ be) {
  const int r = blockIdx.x;
  const int c = threadIdx.x;
  const size_t idx = (size_t)r * DMODEL + c;
  const float x = X[idx] + Y[idx];
  __shared__ float sh[4];
  float s = x;
#pragma unroll
  for (int o = 32; o >= 1; o >>= 1) s += __shfl_xor(s, o, 64);
  if ((c & 63) == 0) sh[c >> 6] = s;
  __syncthreads();
  const float mean = (sh[0] + sh[1] + sh[2] + sh[3]) * (1.0f / DMODEL);
  const float d = x - mean;
  float vsum = d * d;
  __syncthreads();
#pragma unroll
  for (int o = 32; o >= 1; o >>= 1) vsum += __shfl_xor(vsum, o, 64);
  if ((c & 63) == 0) sh[c >> 6] = vsum;
  __syncthreads();
  const float var = (sh[0] + sh[1] + sh[2] + sh[3]) * (1.0f / DMODEL);
  const float rv = d * (1.0f / sqrtf(var + 1e-5f)) * g[c] + be[c];
  X[idx] = rv;
  Xbf[idx] = f2bf(rv);
}

// ---------------- driver ----------------
extern "C" void kernel_launch(void* const* d_in, const int* in_sizes, int n_in,
                              void* d_out, int out_size, void* d_ws, size_t ws_size,
                              hipStream_t stream) {
  const float* q_embed  = (const float*)d_in[0];
  const float* qa_embed = (const float*)d_in[1];
  const float* Wq  = (const float*)d_in[2];
  const float* bq  = (const float*)d_in[3];
  const float* Wv  = (const float*)d_in[4];
  const float* bv  = (const float*)d_in[5];
  const float* Wg  = (const float*)d_in[6];
  const float* Wo  = (const float*)d_in[7];
  const float* bo  = (const float*)d_in[8];
  const float* ln1w = (const float*)d_in[9];
  const float* ln1b = (const float*)d_in[10];
  const float* Wf1 = (const float*)d_in[11];
  const float* bf1 = (const float*)d_in[12];
  const float* Wf2 = (const float*)d_in[13];
  const float* bf2 = (const float*)d_in[14];
  const float* ln2w = (const float*)d_in[15];
  const float* ln2b = (const float*)d_in[16];
  float* out = (float*)d_out;

  const size_t NA = (size_t)NTOK_C * DMODEL;  // 2097152
  float* xbuf = (float*)d_ws;
  float* ybuf = xbuf + NA;
  float* ob   = ybuf + NA;
  float* routing8   = ob + NA;
  float* partials   = routing8 + 64;
  float* balscratch = partials + 64 * 18;
  ushort_t* xbf   = (ushort_t*)(balscratch + 16);
  ushort_t* ybf   = xbf + NA;
  ushort_t* qb_bf = ybf + NA;
  ushort_t* vbT   = qb_bf + NA;
  ushort_t* ab_bf = vbT + NA;
  ushort_t* hb    = ab_bf + NA;                       // NTOK * DFF bf16
  ushort_t* WqT   = hb + (size_t)NTOK_C * DFF_C;
  ushort_t* WvT   = WqT + (size_t)6 * DMODEL * DMODEL;
  ushort_t* WoT   = WvT + (size_t)6 * DMODEL * DMODEL;
  ushort_t* Wf1T  = WoT + (size_t)6 * DMODEL * DMODEL;
  ushort_t* Wf2T  = Wf1T + (size_t)6 * DMODEL * DFF_C;

  // weight prep
  transpose_k<<<dim3(8, 8, 6), 256, 0, stream>>>(Wq, WqT, DMODEL, DMODEL);
  transpose_k<<<dim3(8, 8, 6), 256, 0, stream>>>(Wv, WvT, DMODEL, DMODEL);
  transpose_k<<<dim3(8, 8, 6), 256, 0, stream>>>(Wo, WoT, DMODEL, DMODEL);
  transpose_k<<<dim3(32, 8, 6), 256, 0, stream>>>(Wf1, Wf1T, DMODEL, DFF_C);
  transpose_k<<<dim3(8, 32, 6), 256, 0, stream>>>(Wf2, Wf2T, DFF_C, DMODEL);
  conv_init_k<<<NA / 1024, 256, 0, stream>>>(q_embed, xbuf, xbf);
  conv_init_k<<<NA / 1024, 256, 0, stream>>>(qa_embed, ybuf, ybf);

  auto run_layer = [&](int l, float* Q, ushort_t* Qbf, const ushort_t* Vbf,
                       int mask_val, bool ffn, bool last) {
    const float* bq_l = bq + (size_t)l * DMODEL;
    const float* bv_l = bv + (size_t)l * DMODEL;
    const float* Wg_l = Wg + (size_t)l * DMODEL * NDYN_C;
    const float* bo_l = bo + (size_t)l * DMODEL;
    const float* g1_l = ln1w + (size_t)l * DMODEL;
    const float* b1_l = ln1b + (size_t)l * DMODEL;
    const ushort_t* WqT_l = WqT + (size_t)l * DMODEL * DMODEL;
    const ushort_t* WvT_l = WvT + (size_t)l * DMODEL * DMODEL;
    const ushort_t* WoT_l = WoT + (size_t)l * DMODEL * DMODEL;

    router_k<<<64, 128, 0, stream>>>(xbuf, Wg_l, partials);
    router_reduce_k<<<1, 64, 0, stream>>>(partials, routing8,
                                          last ? (out + NA) : balscratch);
    gemm_mfma_k<1><<<dim3(4, 128), 256, 0, stream>>>(
        Qbf, WqT_l, bq_l, qb_bf, NTOK_C, DMODEL, DMODEL);
    gemm_mfma_k<3><<<dim3(128, 4), 256, 0, stream>>>(
        WvT_l, Vbf, bv_l, vbT, DMODEL, NTOK_C, DMODEL);
    attn_mfma_k<<<1024, 256, 0, stream>>>(qb_bf, vbT, routing8, ab_bf, mask_val);
    if (mask_val == 0)
      attn_row0_patch_k<<<BATCH, 256, 0, stream>>>(vbT, routing8, ab_bf);
    gemm_mfma_k<0><<<dim3(4, 128), 256, 0, stream>>>(
        ab_bf, WoT_l, bo_l, ob, NTOK_C, DMODEL, DMODEL);
    add_ln_k<<<NTOK_C, DMODEL, 0, stream>>>(Q, Qbf, ob, g1_l, b1_l);
    if (ffn) {
      const float* bf1_l = bf1 + (size_t)l * DFF_C;
      const float* bf2_l = bf2 + (size_t)l * DMODEL;
      const float* g2_l = ln2w + (size_t)l * DMODEL;
      const float* b2_l = ln2b + (size_t)l * DMODEL;
      const ushort_t* Wf1T_l = Wf1T + (size_t)l * DMODEL * DFF_C;
      const ushort_t* Wf2T_l = Wf2T + (size_t)l * DFF_C * DMODEL;
      gemm_mfma_k<2><<<dim3(16, 128), 256, 0, stream>>>(
          Qbf, Wf1T_l, bf1_l, hb, NTOK_C, DFF_C, DMODEL);
      gemm_mfma_k<0><<<dim3(4, 128), 256, 0, stream>>>(
          hb, Wf2T_l, bf2_l, ob, NTOK_C, DMODEL, DFF_C);
      add_ln_k<<<NTOK_C, DMODEL, 0, stream>>>(Q, Qbf, ob, g2_l, b2_l);
    }
  };

  // blocks_1: y-stream, router input = x (q_embed, unchanged during blocks_1)
  run_layer(0, ybuf, ybf, ybf, 1, true, false);
  run_layer(1, ybuf, ybf, ybf, 1, true, false);
  // blocks_2: (self, no FFN) then (cross to y, strict causal, FFN)
  run_layer(2, xbuf, xbf, xbf, 1, false, false);
  run_layer(3, xbuf, xbf, ybf, 0, true, false);
  run_layer(4, xbuf, xbf, xbf, 1, false, false);
  run_layer(5, xbuf, xbf, ybf, 0, true, true);

  hipMemcpyAsync(out, xbuf, NA * sizeof(float), hipMemcpyDeviceToDevice, stream);
}

// Round 6
// 737.501 us; speedup vs baseline: 3.9554x; 1.0899x over previous
//
#include <hip/hip_runtime.h>

// RouterKT forward. Round 6: R5 pipeline + EXPLICIT vmcnt/lgkmcnt drain before
// every pipeline barrier (m230 2-phase template compliance; closes the replay race).

constexpr int DMODEL = 256;
constexpr int SEQ    = 1024;
constexpr int BATCH  = 8;
constexpr int NHEADS = 8;
constexpr int DKDIM  = 32;
constexpr int NDYN_C = 6;
constexpr int NTOK_C = BATCH * SEQ;   // 8192
constexpr int DFF_C  = 1024;

using frag_bf16 = __attribute__((ext_vector_type(8))) short;  // 8 bf16 = 4 VGPR
using f32x4    = __attribute__((ext_vector_type(4))) float;
typedef unsigned short ushort_t;

__device__ __forceinline__ ushort_t f2bf(float f) {
  unsigned u = __float_as_uint(f);
  unsigned r = (u + 0x7fffu + ((u >> 16) & 1u)) >> 16;   // RNE, finite inputs
  return (ushort_t)r;
}

#define GLOAD_LDS16(gsrc, ldst)                                             \
  __builtin_amdgcn_global_load_lds(                                         \
      (const __attribute__((address_space(1))) void*)(gsrc),                \
      (__attribute__((address_space(3))) void*)(ldst), 16, 0, 0)

// Explicit drain + order pin + barrier: guarantees all in-flight
// global_load_lds have landed before ANY wave crosses (race-proof handoff).
#define SYNC_DRAIN()                                                        \
  do {                                                                      \
    asm volatile("s_waitcnt vmcnt(0) lgkmcnt(0)" ::: "memory");             \
    __builtin_amdgcn_sched_barrier(0);                                      \
    __syncthreads();                                                        \
  } while (0)

// ---------------- bf16 MFMA GEMM (2-phase prefetch, explicit drain) ----------
// C[m][n] = sum_k A[m][k] * B[n][k] + bias.   A:[M][K] bf16, B:[N][K] bf16.
// Tile: BM=64, BN=64, BK=64, double-buffered. 256 threads = 4 waves (2x2).
// MODE: 0 = f32 C[M][N], 1 = bf16 C[M][N], 2 = bf16+relu, 3 = vbT scatter.
template<int MODE>
__global__ __launch_bounds__(256)
void gemm_mfma_k(const ushort_t* __restrict__ A, const ushort_t* __restrict__ B,
                 const float* __restrict__ bias, void* __restrict__ Cp,
                 int M, int N, int K) {
  __shared__ ushort_t sA[2][4096];
  __shared__ ushort_t sB[2][4096];
  const int tid = threadIdx.x;
  const int wid = tid >> 6, lane = tid & 63;
  const int li = lane & 15, g = lane >> 4;
  const int wr = wid >> 1, wc = wid & 1;
  const int m0 = blockIdx.y * 64, n0 = blockIdx.x * 64;
  f32x4 acc[2][2] = {};
  // staging: rows wid*8+(lane>>3); slot lane&7 holds global chunk (lane&7)^(lane>>3)
  const int srow = wid * 8 + (lane >> 3);
  const int schk = (lane & 7) ^ (lane >> 3);
  const ushort_t* gA1 = &A[(size_t)(m0 + srow) * K + schk * 8];
  const ushort_t* gA2 = &A[(size_t)(m0 + 32 + srow) * K + schk * 8];
  const ushort_t* gB1 = &B[(size_t)(n0 + srow) * K + schk * 8];
  const ushort_t* gB2 = &B[(size_t)(n0 + 32 + srow) * K + schk * 8];
  const int nk = K >> 6;

  // prologue: stage k-step 0 into buf 0
  GLOAD_LDS16(gA1, sA[0] + wid * 512);
  GLOAD_LDS16(gA2, sA[0] + 2048 + wid * 512);
  GLOAD_LDS16(gB1, sB[0] + wid * 512);
  GLOAD_LDS16(gB2, sB[0] + 2048 + wid * 512);
  SYNC_DRAIN();

  auto compute = [&](int cur) {
#pragma unroll
    for (int s = 0; s < 2; ++s) {
      frag_bf16 af[2], bf[2];
#pragma unroll
      for (int m = 0; m < 2; ++m) {
        const int row = wr * 32 + m * 16 + li;
        af[m] = *reinterpret_cast<const frag_bf16*>(
            &sA[cur][row * 64 + ((s * 4 + g) ^ (row & 7)) * 8]);
      }
#pragma unroll
      for (int n = 0; n < 2; ++n) {
        const int row = wc * 32 + n * 16 + li;
        bf[n] = *reinterpret_cast<const frag_bf16*>(
            &sB[cur][row * 64 + ((s * 4 + g) ^ (row & 7)) * 8]);
      }
#pragma unroll
      for (int m = 0; m < 2; ++m)
#pragma unroll
        for (int n = 0; n < 2; ++n)
          acc[m][n] = __builtin_amdgcn_mfma_f32_16x16x32_bf16(af[m], bf[n], acc[m][n], 0, 0, 0);
    }
  };

  // steady state: prefetch next (unconditional), compute current, drain+barrier
  for (int kt = 0; kt < nk - 1; ++kt) {
    const int cur = kt & 1;
    const int k1 = (kt + 1) << 6;
    GLOAD_LDS16(gA1 + k1, sA[cur ^ 1] + wid * 512);
    GLOAD_LDS16(gA2 + k1, sA[cur ^ 1] + 2048 + wid * 512);
    GLOAD_LDS16(gB1 + k1, sB[cur ^ 1] + wid * 512);
    GLOAD_LDS16(gB2 + k1, sB[cur ^ 1] + 2048 + wid * 512);
    compute(cur);
    SYNC_DRAIN();
  }
  compute((nk - 1) & 1);   // peeled last step, no prefetch

#pragma unroll
  for (int m = 0; m < 2; ++m)
#pragma unroll
    for (int n = 0; n < 2; ++n)
#pragma unroll
      for (int r = 0; r < 4; ++r) {
        const int mg = m0 + wr * 32 + m * 16 + g * 4 + r;
        const int ng = n0 + wc * 32 + n * 16 + li;
        if (MODE == 0) {
          ((float*)Cp)[(size_t)mg * N + ng] = acc[m][n][r] + bias[ng];
        } else if (MODE == 1) {
          ((ushort_t*)Cp)[(size_t)mg * N + ng] = f2bf(acc[m][n][r] + bias[ng]);
        } else if (MODE == 2) {
          ((ushort_t*)Cp)[(size_t)mg * N + ng] = f2bf(fmaxf(acc[m][n][r] + bias[ng], 0.0f));
        } else {
          ((ushort_t*)Cp)[((size_t)((ng >> 10) * 256 + mg)) * SEQ + (ng & 1023)] =
              f2bf(acc[m][n][r] + bias[mg]);
        }
      }
}

// ---------------- weight transpose+convert: in [z][R][C] f32 -> out [z][C][R] bf16 ----
__global__ __launch_bounds__(256)
void transpose_k(const float* __restrict__ in, ushort_t* __restrict__ out, int R, int C) {
  __shared__ float t[32][33];
  const int z = blockIdx.z;
  const int c0 = blockIdx.x * 32, r0 = blockIdx.y * 32;
  const int tx = threadIdx.x & 31, ty = threadIdx.x >> 5;   // ty 0..7
  const float* ip = in + (size_t)z * R * C;
  ushort_t* op = out + (size_t)z * R * C;
#pragma unroll
  for (int i = 0; i < 4; ++i) t[ty + 8 * i][tx] = ip[(size_t)(r0 + ty + 8 * i) * C + c0 + tx];
  __syncthreads();
#pragma unroll
  for (int i = 0; i < 4; ++i)
    op[(size_t)(c0 + ty + 8 * i) * R + r0 + tx] = f2bf(t[tx][ty + 8 * i]);
}

// ---------------- f32 copy + bf16 mirror ----------------
__global__ __launch_bounds__(256)
void conv_init_k(const float* __restrict__ src, float* __restrict__ dstF,
                 ushort_t* __restrict__ dstB) {
  const int i = blockIdx.x * 256 + threadIdx.x;   // over float4 elements
  const float4 v = reinterpret_cast<const float4*>(src)[i];
  reinterpret_cast<float4*>(dstF)[i] = v;
  ushort4 b;
  b.x = f2bf(v.x); b.y = f2bf(v.y); b.z = f2bf(v.z); b.w = f2bf(v.w);
  reinterpret_cast<ushort4*>(dstB)[i] = b;
}

// ---------------- MFMA flash attention (2-phase prefetch, explicit drain) ------
// 1D grid of 1024: b = gid&7 (XCD-local K/V); slot=gid>>3: h=(slot>>4)&7,
// qblk = 15-(slot&15) (heavy-first). Fragment-linear LDS, double-buffered.
__global__ __launch_bounds__(256)
void attn_mfma_k(const ushort_t* __restrict__ qb, const ushort_t* __restrict__ vbT,
                 const float* __restrict__ routing8, ushort_t* __restrict__ out,
                 int mask_val) {
  __shared__ ushort_t sk[2][2048];    // [kb 4][g 4][li 16][8]
  __shared__ ushort_t sv[2][2048];    // [dset 2][c 2][g 4][li 16][8]
  __shared__ ushort_t plf4[4096];     // per wave [c 2][g 4][q 16][8]
  const int gid = blockIdx.x;
  const int b = gid & 7;
  const int slot = gid >> 3;
  const int h = (slot >> 4) & 7;
  const int qblk = 15 - (slot & 15);
  const int q0 = qblk * 64;
  const int tid = threadIdx.x;
  const int wave = tid >> 6, lane = tid & 63;
  const int g = lane >> 4, li = lane & 15;
  const int qw = q0 + wave * 16;

  const frag_bf16 qf = *reinterpret_cast<const frag_bf16*>(
      &qb[((size_t)(b * SEQ + qw + li)) * DMODEL + h * DKDIM + g * 8]);

  float mrun[4], lrun[4];
  f32x4 o0 = {0.f, 0.f, 0.f, 0.f}, o1 = {0.f, 0.f, 0.f, 0.f};
#pragma unroll
  for (int r = 0; r < 4; ++r) { mrun[r] = -INFINITY; lrun[r] = 0.f; }
  ushort_t* pl = &plf4[wave * 1024];

  const ushort_t* gK = &qb[((size_t)(b * SEQ + wave * 16 + li)) * DMODEL + h * DKDIM + g * 8];
  const ushort_t* gV = &vbT[(((size_t)(b * NHEADS + h)) * DKDIM + (wave >> 1) * 16 + li) * SEQ
                            + (wave & 1) * 32 + g * 8];

  const int nt = qblk + 1;
  // prologue: stage tile 0 into buf 0
  GLOAD_LDS16(gK, sk[0] + wave * 512);
  GLOAD_LDS16(gV, sv[0] + wave * 512);
  SYNC_DRAIN();

  auto tile_step = [&](int t, int cur) {
    const int kt = t * 64;
    // S = Q K^T
    f32x4 s[4];
#pragma unroll
    for (int kb = 0; kb < 4; ++kb) {
      frag_bf16 kf = *reinterpret_cast<const frag_bf16*>(&sk[cur][(kb * 64 + g * 16 + li) * 8]);
      f32x4 z = {0.f, 0.f, 0.f, 0.f};
      s[kb] = __builtin_amdgcn_mfma_f32_16x16x32_bf16(qf, kf, z, 0, 0, 0);
    }
    const bool need_mask = (kt + 63) >= (qw + mask_val);
#pragma unroll
    for (int kb = 0; kb < 4; ++kb) {
      const int col = kt + kb * 16 + li;
#pragma unroll
      for (int r = 0; r < 4; ++r) {
        float v = s[kb][r] * 0.17677669529663687f;
        if (need_mask && col >= (qw + 4 * g + r + mask_val)) v = -1e9f;
        s[kb][r] = v;
      }
    }
    // online softmax per row (reduce over li lanes: xor 1..8)
    float p[4][4], scl[4];
#pragma unroll
    for (int r = 0; r < 4; ++r) {
      float tm = fmaxf(fmaxf(s[0][r], s[1][r]), fmaxf(s[2][r], s[3][r]));
#pragma unroll
      for (int mm = 8; mm >= 1; mm >>= 1) tm = fmaxf(tm, __shfl_xor(tm, mm, 64));
      const float mnew = fmaxf(mrun[r], tm);
      scl[r] = __expf(mrun[r] - mnew);
      float ps = 0.f;
#pragma unroll
      for (int kb = 0; kb < 4; ++kb) { p[kb][r] = __expf(s[kb][r] - mnew); ps += p[kb][r]; }
#pragma unroll
      for (int mm = 8; mm >= 1; mm >>= 1) ps += __shfl_xor(ps, mm, 64);
      lrun[r] = lrun[r] * scl[r] + ps;
      mrun[r] = mnew;
      o0[r] *= scl[r];
      o1[r] *= scl[r];
    }
    // P: C-layout -> fragment-linear A-layout (per-wave scratch, same-wave RAW)
#pragma unroll
    for (int kb = 0; kb < 4; ++kb) {
      const int k = kb * 16 + li;
      const int c = k >> 5, g2 = (k >> 3) & 3, j = k & 7;
#pragma unroll
      for (int r = 0; r < 4; ++r)
        pl[((c * 4 + g2) * 16 + 4 * g + r) * 8 + j] = f2bf(p[kb][r]);
    }
    __threadfence_block();
    // O += P V
#pragma unroll
    for (int c = 0; c < 2; ++c) {
      frag_bf16 pa = *reinterpret_cast<const frag_bf16*>(&pl[((c * 4 + g) * 16 + li) * 8]);
      frag_bf16 v0 = *reinterpret_cast<const frag_bf16*>(&sv[cur][(c * 64 + g * 16 + li) * 8]);
      frag_bf16 v1 = *reinterpret_cast<const frag_bf16*>(&sv[cur][(128 + c * 64 + g * 16 + li) * 8]);
      o0 = __builtin_amdgcn_mfma_f32_16x16x32_bf16(pa, v0, o0, 0, 0, 0);
      o1 = __builtin_amdgcn_mfma_f32_16x16x32_bf16(pa, v1, o1, 0, 0, 0);
    }
  };

  // steady state: prefetch tile t+1 (unconditional), compute tile t, drain+barrier
  for (int t = 0; t < nt - 1; ++t) {
    const int cur = t & 1;
    const int kt = t * 64;
    GLOAD_LDS16(gK + (size_t)(kt + 64) * DMODEL, sk[cur ^ 1] + wave * 512);
    GLOAD_LDS16(gV + (kt + 64), sv[cur ^ 1] + wave * 512);
    tile_step(t, cur);
    SYNC_DRAIN();
  }
  tile_step(nt - 1, (nt - 1) & 1);   // peeled last tile, no prefetch

  const float rt = routing8[b * NHEADS + h];
#pragma unroll
  for (int r = 0; r < 4; ++r) {
    // ref: fully-masked row 0 (mask_val==0) -> uniform over ALL keys; patched below
    const bool skip0 = (mask_val == 0) && ((qw + 4 * g + r) == 0);
    if (!skip0) {
      const float mult = rt / lrun[r];
      const size_t row = (size_t)(b * SEQ + qw + 4 * g + r) * DMODEL + h * DKDIM;
      out[row + li] = f2bf(o0[r] * mult);
      out[row + 16 + li] = f2bf(o1[r] * mult);
    }
  }
  // fused row0 patch: out[b,0,h,:] = mean_k(V[k,:]) * rt
  if (mask_val == 0 && qblk == 0 && wave == 0) {
    const int d = lane >> 1, hf = lane & 1;
    const ushort_t* src = &vbT[(((size_t)(b * NHEADS + h)) * DKDIM + d) * SEQ + hf * 512];
    float s = 0.f;
    for (int k = 0; k < 512; k += 8) {
      frag_bf16 v = *reinterpret_cast<const frag_bf16*>(&src[k]);
#pragma unroll
      for (int j = 0; j < 8; ++j)
        s += __uint_as_float(((unsigned)(ushort_t)v[j]) << 16);
    }
    s += __shfl_xor(s, 1, 64);
    if (hf == 0)
      out[(size_t)(b * SEQ) * DMODEL + h * DKDIM + d] = f2bf(s * (1.0f / 1024.0f) * rt);
  }
}

// ---------------- Router ----------------
__global__ __launch_bounds__(128)
void router_k(const float* __restrict__ R, const float* __restrict__ Wg,
              float* __restrict__ partials) {
  __shared__ float sW[DMODEL * NDYN_C];
  __shared__ float red[18][128];
  const int tid = threadIdx.x;
  for (int t = tid; t < DMODEL * NDYN_C; t += 128) sW[t] = Wg[t];
  __syncthreads();
  const int r = blockIdx.x * 128 + tid;
  const int b = r >> 10;
  const int h = (r >> 7) & 7;
  const int s8 = r & 127;
  float lg[NDYN_C] = {};
  for (int t8 = 0; t8 < 8; ++t8) {
    const float* base = &R[((size_t)(b * SEQ + s8 * 8 + t8)) * DMODEL + h * DKDIM];
#pragma unroll
    for (int d = 0; d < DKDIM; ++d) {
      const float x = base[d];
      const float* w = &sW[(t8 * 32 + d) * NDYN_C];
#pragma unroll
      for (int j = 0; j < NDYN_C; ++j) lg[j] = fmaf(x, w[j], lg[j]);
    }
  }
  float mx = lg[0];
#pragma unroll
  for (int j = 1; j < NDYN_C; ++j) mx = fmaxf(mx, lg[j]);
  float e[NDYN_C], sum = 0.0f;
#pragma unroll
  for (int j = 0; j < NDYN_C; ++j) { e[j] = expf(lg[j] - mx); sum += e[j]; }
  float g[NDYN_C];
#pragma unroll
  for (int j = 0; j < NDYN_C; ++j) g[j] = e[j] / sum;
  int j1 = 0;
#pragma unroll
  for (int j = 1; j < NDYN_C; ++j) if (g[j] > g[j1]) j1 = j;
  int j2 = -1;
#pragma unroll
  for (int j = 0; j < NDYN_C; ++j) {
    if (j == j1) continue;
    if (j2 < 0 || g[j] > g[j2]) j2 = j;
  }
#pragma unroll
  for (int j = 0; j < NDYN_C; ++j) {
    const bool sel = (j == j1) || (j == j2);
    red[j][tid] = sel ? g[j] : 0.0f;
    red[6 + j][tid] = sel ? 1.0f : 0.0f;
    red[12 + j][tid] = g[j];
  }
  __syncthreads();
  if (tid < 18) {
    float s = 0.0f;
    for (int i = 0; i < 128; ++i) s += red[tid][i];
    partials[blockIdx.x * 18 + tid] = s;
  }
}

__global__ void router_reduce_k(const float* __restrict__ partials,
                                float* __restrict__ routing8,
                                float* __restrict__ bal_out) {
  const int tid = threadIdx.x;
  if (tid < 48) {
    const int b = tid / 6, j = tid % 6;
    float s = 0.0f;
    for (int t = 0; t < 8; ++t) s += partials[(b * 8 + t) * 18 + j];
    routing8[b * NHEADS + 2 + j] = s * (1.0f / 1024.0f);
  } else if (tid < 56) {
    const int b = tid - 48;
    routing8[b * NHEADS + 0] = 1.0f;
    routing8[b * NHEADS + 1] = 1.0f;
  } else if (tid == 56) {
    float hs[6], hp[6];
    float hssum = 0.0f, hpsum = 0.0f;
    for (int j = 0; j < 6; ++j) {
      float a = 0.0f, c = 0.0f;
      for (int bi = 0; bi < 64; ++bi) {
        a += partials[bi * 18 + 6 + j];
        c += partials[bi * 18 + 12 + j];
      }
      hs[j] = a;
      hp[j] = c * (1.0f / 8192.0f);
      hssum += hs[j];
      hpsum += hp[j];
    }
    float bal = 0.0f;
    for (int j = 0; j < 6; ++j)
      bal += (hs[j] / (hssum + 1e-5f)) * (hp[j] / (hpsum + 1e-5f));
    *bal_out = bal;
  }
}

// ---------------- residual add + layernorm (Xin -> Xout f32 + Xbf bf16) ----
__global__ __launch_bounds__(256)
void add_ln_k(const float* __restrict__ Xin, float* __restrict__ Xout,
              ushort_t* __restrict__ Xbf, const float* __restrict__ Y,
              const float* __restrict__ g, const float* __restrict__ be) {
  const int r = blockIdx.x;
  const int c = threadIdx.x;
  const size_t idx = (size_t)r * DMODEL + c;
  const float x = Xin[idx] + Y[idx];
  __shared__ float sh[4];
  float s = x;
#pragma unroll
  for (int o = 32; o >= 1; o >>= 1) s += __shfl_xor(s, o, 64);
  if ((c & 63) == 0) sh[c >> 6] = s;
  __syncthreads();
  const float mean = (sh[0] + sh[1] + sh[2] + sh[3]) * (1.0f / DMODEL);
  const float d = x - mean;
  float vsum = d * d;
  __syncthreads();
#pragma unroll
  for (int o = 32; o >= 1; o >>= 1) vsum += __shfl_xor(vsum, o, 64);
  if ((c & 63) == 0) sh[c >> 6] = vsum;
  __syncthreads();
  const float var = (sh[0] + sh[1] + sh[2] + sh[3]) * (1.0f / DMODEL);
  const float rv = d * (1.0f / sqrtf(var + 1e-5f)) * g[c] + be[c];
  Xout[idx] = rv;
  Xbf[idx] = f2bf(rv);
}

// ---------------- driver ----------------
extern "C" void kernel_launch(void* const* d_in, const int* in_sizes, int n_in,
                              void* d_out, int out_size, void* d_ws, size_t ws_size,
                              hipStream_t stream) {
  const float* q_embed  = (const float*)d_in[0];
  const float* qa_embed = (const float*)d_in[1];
  const float* Wq  = (const float*)d_in[2];
  const float* bq  = (const float*)d_in[3];
  const float* Wv  = (const float*)d_in[4];
  const float* bv  = (const float*)d_in[5];
  const float* Wg  = (const float*)d_in[6];
  const float* Wo  = (const float*)d_in[7];
  const float* bo  = (const float*)d_in[8];
  const float* ln1w = (const float*)d_in[9];
  const float* ln1b = (const float*)d_in[10];
  const float* Wf1 = (const float*)d_in[11];
  const float* bf1 = (const float*)d_in[12];
  const float* Wf2 = (const float*)d_in[13];
  const float* bf2 = (const float*)d_in[14];
  const float* ln2w = (const float*)d_in[15];
  const float* ln2b = (const float*)d_in[16];
  float* out = (float*)d_out;

  const size_t NA = (size_t)NTOK_C * DMODEL;  // 2097152
  float* xbuf = (float*)d_ws;
  float* ybuf = xbuf + NA;
  float* ob   = ybuf + NA;
  float* routing8   = ob + NA;
  float* partials   = routing8 + 64;
  float* balscratch = partials + 64 * 18;
  ushort_t* xbf   = (ushort_t*)(balscratch + 16);
  ushort_t* ybf   = xbf + NA;
  ushort_t* qb_bf = ybf + NA;
  ushort_t* vbT   = qb_bf + NA;
  ushort_t* ab_bf = vbT + NA;
  ushort_t* hb    = ab_bf + NA;                       // NTOK * DFF bf16
  ushort_t* WqT   = hb + (size_t)NTOK_C * DFF_C;
  ushort_t* WvT   = WqT + (size_t)6 * DMODEL * DMODEL;
  ushort_t* WoT   = WvT + (size_t)6 * DMODEL * DMODEL;
  ushort_t* Wf1T  = WoT + (size_t)6 * DMODEL * DMODEL;
  ushort_t* Wf2T  = Wf1T + (size_t)6 * DMODEL * DFF_C;

  // weight prep
  transpose_k<<<dim3(8, 8, 6), 256, 0, stream>>>(Wq, WqT, DMODEL, DMODEL);
  transpose_k<<<dim3(8, 8, 6), 256, 0, stream>>>(Wv, WvT, DMODEL, DMODEL);
  transpose_k<<<dim3(8, 8, 6), 256, 0, stream>>>(Wo, WoT, DMODEL, DMODEL);
  transpose_k<<<dim3(32, 8, 6), 256, 0, stream>>>(Wf1, Wf1T, DMODEL, DFF_C);
  transpose_k<<<dim3(8, 32, 6), 256, 0, stream>>>(Wf2, Wf2T, DFF_C, DMODEL);
  conv_init_k<<<NA / 1024, 256, 0, stream>>>(q_embed, xbuf, xbf);
  conv_init_k<<<NA / 1024, 256, 0, stream>>>(qa_embed, ybuf, ybf);

  auto run_layer = [&](int l, float* Q, ushort_t* Qbf, const ushort_t* Vbf,
                       int mask_val, bool ffn, bool last) {
    const float* bq_l = bq + (size_t)l * DMODEL;
    const float* bv_l = bv + (size_t)l * DMODEL;
    const float* Wg_l = Wg + (size_t)l * DMODEL * NDYN_C;
    const float* bo_l = bo + (size_t)l * DMODEL;
    const float* g1_l = ln1w + (size_t)l * DMODEL;
    const float* b1_l = ln1b + (size_t)l * DMODEL;
    const ushort_t* WqT_l = WqT + (size_t)l * DMODEL * DMODEL;
    const ushort_t* WvT_l = WvT + (size_t)l * DMODEL * DMODEL;
    const ushort_t* WoT_l = WoT + (size_t)l * DMODEL * DMODEL;

    router_k<<<64, 128, 0, stream>>>(xbuf, Wg_l, partials);
    router_reduce_k<<<1, 64, 0, stream>>>(partials, routing8,
                                          last ? (out + NA) : balscratch);
    gemm_mfma_k<1><<<dim3(4, 128), 256, 0, stream>>>(
        Qbf, WqT_l, bq_l, qb_bf, NTOK_C, DMODEL, DMODEL);
    gemm_mfma_k<3><<<dim3(128, 4), 256, 0, stream>>>(
        WvT_l, Vbf, bv_l, vbT, DMODEL, NTOK_C, DMODEL);
    attn_mfma_k<<<1024, 256, 0, stream>>>(qb_bf, vbT, routing8, ab_bf, mask_val);
    gemm_mfma_k<0><<<dim3(4, 128), 256, 0, stream>>>(
        ab_bf, WoT_l, bo_l, ob, NTOK_C, DMODEL, DMODEL);
    add_ln_k<<<NTOK_C, DMODEL, 0, stream>>>(Q, Q, Qbf, ob, g1_l, b1_l);
    if (ffn) {
      const float* bf1_l = bf1 + (size_t)l * DFF_C;
      const float* bf2_l = bf2 + (size_t)l * DMODEL;
      const float* g2_l = ln2w + (size_t)l * DMODEL;
      const float* b2_l = ln2b + (size_t)l * DMODEL;
      const ushort_t* Wf1T_l = Wf1T + (size_t)l * DMODEL * DFF_C;
      const ushort_t* Wf2T_l = Wf2T + (size_t)l * DFF_C * DMODEL;
      gemm_mfma_k<2><<<dim3(16, 128), 256, 0, stream>>>(
          Qbf, Wf1T_l, bf1_l, hb, NTOK_C, DFF_C, DMODEL);
      gemm_mfma_k<0><<<dim3(4, 128), 256, 0, stream>>>(
          hb, Wf2T_l, bf2_l, ob, NTOK_C, DMODEL, DFF_C);
      // last layer: write the final layernorm result straight to d_out
      add_ln_k<<<NTOK_C, DMODEL, 0, stream>>>(Q, last ? out : Q, Qbf, ob, g2_l, b2_l);
    }
  };

  // blocks_1: y-stream, router input = x (q_embed copy, unchanged during blocks_1)
  run_layer(0, ybuf, ybf, ybf, 1, true, false);
  run_layer(1, ybuf, ybf, ybf, 1, true, false);
  // blocks_2: (self, no FFN) then (cross to y, strict causal, FFN)
  run_layer(2, xbuf, xbf, xbf, 1, false, false);
  run_layer(3, xbuf, xbf, ybf, 0, true, false);
  run_layer(4, xbuf, xbf, xbf, 1, false, false);
  run_layer(5, xbuf, xbf, ybf, 0, true, true);
}

// Round 7
// 614.646 us; speedup vs baseline: 4.7460x; 1.1999x over previous
//
#include <hip/hip_runtime.h>

// RouterKT forward. Round 7: swapped-operand attention (S^T=mfma(K,Q),
// O^T=mfma(V^T,P^T)) -> lane-local softmax (4 shfls/tile), cvt_pk P repack,
// conflict-free fragment-linear P/V LDS; Q pre-scaled by dk^-1/4 in projection;
// Q-proj + V-proj merged into one dual-GEMM launch.

constexpr int DMODEL = 256;
constexpr int SEQ    = 1024;
constexpr int BATCH  = 8;
constexpr int NHEADS = 8;
constexpr int DKDIM  = 32;
constexpr int NDYN_C = 6;
constexpr int NTOK_C = BATCH * SEQ;   // 8192
constexpr int DFF_C  = 1024;

using frag_bf16 = __attribute__((ext_vector_type(8))) short;  // 8 bf16 = 4 VGPR
using f32x4    = __attribute__((ext_vector_type(4))) float;
typedef unsigned short ushort_t;

__device__ __forceinline__ ushort_t f2bf(float f) {
  unsigned u = __float_as_uint(f);
  unsigned r = (u + 0x7fffu + ((u >> 16) & 1u)) >> 16;   // RNE, finite inputs
  return (ushort_t)r;
}

__device__ __forceinline__ unsigned cvt_pk_bf16(float lo, float hi) {
  unsigned r;
  asm("v_cvt_pk_bf16_f32 %0, %1, %2" : "=v"(r) : "v"(lo), "v"(hi));
  return r;
}

#define GLOAD_LDS16(gsrc, ldst)                                             \
  __builtin_amdgcn_global_load_lds(                                         \
      (const __attribute__((address_space(1))) void*)(gsrc),                \
      (__attribute__((address_space(3))) void*)(ldst), 16, 0, 0)

// Explicit drain + order pin + barrier (race-proof prefetch handoff).
#define SYNC_DRAIN()                                                        \
  do {                                                                      \
    asm volatile("s_waitcnt vmcnt(0) lgkmcnt(0)" ::: "memory");             \
    __builtin_amdgcn_sched_barrier(0);                                      \
    __syncthreads();                                                        \
  } while (0)

// ---------------- bf16 MFMA GEMM body (2-phase prefetch, explicit drain) ------
// C[m][n] = sum_k A[m][k] * B[n][k] + bias.   A:[M][K] bf16, B:[N][K] bf16.
// Tile: BM=64, BN=64, BK=64, double-buffered. 256 threads = 4 waves (2x2).
// MODE: 0 = f32 C[M][N], 1 = bf16*QSCALE (q-proj), 2 = bf16+relu, 3 = vbT scatter.
template<int MODE>
__device__ __forceinline__
void gemm_body(int bx, int by,
               const ushort_t* __restrict__ A, const ushort_t* __restrict__ B,
               const float* __restrict__ bias, void* __restrict__ Cp,
               int M, int N, int K) {
  __shared__ ushort_t sA[2][4096];
  __shared__ ushort_t sB[2][4096];
  const int tid = threadIdx.x;
  const int wid = tid >> 6, lane = tid & 63;
  const int li = lane & 15, g = lane >> 4;
  const int wr = wid >> 1, wc = wid & 1;
  const int m0 = by * 64, n0 = bx * 64;
  f32x4 acc[2][2] = {};
  const int srow = wid * 8 + (lane >> 3);
  const int schk = (lane & 7) ^ (lane >> 3);
  const ushort_t* gA1 = &A[(size_t)(m0 + srow) * K + schk * 8];
  const ushort_t* gA2 = &A[(size_t)(m0 + 32 + srow) * K + schk * 8];
  const ushort_t* gB1 = &B[(size_t)(n0 + srow) * K + schk * 8];
  const ushort_t* gB2 = &B[(size_t)(n0 + 32 + srow) * K + schk * 8];
  const int nk = K >> 6;

  GLOAD_LDS16(gA1, sA[0] + wid * 512);
  GLOAD_LDS16(gA2, sA[0] + 2048 + wid * 512);
  GLOAD_LDS16(gB1, sB[0] + wid * 512);
  GLOAD_LDS16(gB2, sB[0] + 2048 + wid * 512);
  SYNC_DRAIN();

  auto compute = [&](int cur) {
#pragma unroll
    for (int s = 0; s < 2; ++s) {
      frag_bf16 af[2], bf[2];
#pragma unroll
      for (int m = 0; m < 2; ++m) {
        const int row = wr * 32 + m * 16 + li;
        af[m] = *reinterpret_cast<const frag_bf16*>(
            &sA[cur][row * 64 + ((s * 4 + g) ^ (row & 7)) * 8]);
      }
#pragma unroll
      for (int n = 0; n < 2; ++n) {
        const int row = wc * 32 + n * 16 + li;
        bf[n] = *reinterpret_cast<const frag_bf16*>(
            &sB[cur][row * 64 + ((s * 4 + g) ^ (row & 7)) * 8]);
      }
#pragma unroll
      for (int m = 0; m < 2; ++m)
#pragma unroll
        for (int n = 0; n < 2; ++n)
          acc[m][n] = __builtin_amdgcn_mfma_f32_16x16x32_bf16(af[m], bf[n], acc[m][n], 0, 0, 0);
    }
  };

  for (int kt = 0; kt < nk - 1; ++kt) {
    const int cur = kt & 1;
    const int k1 = (kt + 1) << 6;
    GLOAD_LDS16(gA1 + k1, sA[cur ^ 1] + wid * 512);
    GLOAD_LDS16(gA2 + k1, sA[cur ^ 1] + 2048 + wid * 512);
    GLOAD_LDS16(gB1 + k1, sB[cur ^ 1] + wid * 512);
    GLOAD_LDS16(gB2 + k1, sB[cur ^ 1] + 2048 + wid * 512);
    compute(cur);
    SYNC_DRAIN();
  }
  compute((nk - 1) & 1);

  constexpr float QSCALE = 0.42044820762685725f;  // 32^-0.25; (qs)(ks)=qk/sqrt(32)
#pragma unroll
  for (int m = 0; m < 2; ++m)
#pragma unroll
    for (int n = 0; n < 2; ++n)
#pragma unroll
      for (int r = 0; r < 4; ++r) {
        const int mg = m0 + wr * 32 + m * 16 + g * 4 + r;
        const int ng = n0 + wc * 32 + n * 16 + li;
        if (MODE == 0) {
          ((float*)Cp)[(size_t)mg * N + ng] = acc[m][n][r] + bias[ng];
        } else if (MODE == 1) {
          ((ushort_t*)Cp)[(size_t)mg * N + ng] = f2bf((acc[m][n][r] + bias[ng]) * QSCALE);
        } else if (MODE == 2) {
          ((ushort_t*)Cp)[(size_t)mg * N + ng] = f2bf(fmaxf(acc[m][n][r] + bias[ng], 0.0f));
        } else {
          ((ushort_t*)Cp)[((size_t)((ng >> 10) * 256 + mg)) * SEQ + (ng & 1023)] =
              f2bf(acc[m][n][r] + bias[mg]);
        }
      }
}

template<int MODE>
__global__ __launch_bounds__(256)
void gemm_mfma_k(const ushort_t* __restrict__ A, const ushort_t* __restrict__ B,
                 const float* __restrict__ bias, void* __restrict__ Cp,
                 int M, int N, int K) {
  gemm_body<MODE>(blockIdx.x, blockIdx.y, A, B, bias, Cp, M, N, K);
}

// merged Q-projection (MODE 1) + V-projection (MODE 3): grid (128,4,2)
__global__ __launch_bounds__(256)
void gemm_qv_k(const ushort_t* __restrict__ Aq, const ushort_t* __restrict__ Bq,
               const float* __restrict__ biasq, void* __restrict__ Cq,
               const ushort_t* __restrict__ Av, const ushort_t* __restrict__ Bv,
               const float* __restrict__ biasv, void* __restrict__ Cv) {
  if (blockIdx.z == 0)
    gemm_body<1>(blockIdx.y, blockIdx.x, Aq, Bq, biasq, Cq, NTOK_C, DMODEL, DMODEL);
  else
    gemm_body<3>(blockIdx.x, blockIdx.y, Av, Bv, biasv, Cv, DMODEL, NTOK_C, DMODEL);
}

// ---------------- weight transpose+convert: in [z][R][C] f32 -> out [z][C][R] bf16 ----
__global__ __launch_bounds__(256)
void transpose_k(const float* __restrict__ in, ushort_t* __restrict__ out, int R, int C) {
  __shared__ float t[32][33];
  const int z = blockIdx.z;
  const int c0 = blockIdx.x * 32, r0 = blockIdx.y * 32;
  const int tx = threadIdx.x & 31, ty = threadIdx.x >> 5;   // ty 0..7
  const float* ip = in + (size_t)z * R * C;
  ushort_t* op = out + (size_t)z * R * C;
#pragma unroll
  for (int i = 0; i < 4; ++i) t[ty + 8 * i][tx] = ip[(size_t)(r0 + ty + 8 * i) * C + c0 + tx];
  __syncthreads();
#pragma unroll
  for (int i = 0; i < 4; ++i)
    op[(size_t)(c0 + ty + 8 * i) * R + r0 + tx] = f2bf(t[tx][ty + 8 * i]);
}

// ---------------- f32 copy + bf16 mirror ----------------
__global__ __launch_bounds__(256)
void conv_init_k(const float* __restrict__ src, float* __restrict__ dstF,
                 ushort_t* __restrict__ dstB) {
  const int i = blockIdx.x * 256 + threadIdx.x;   // over float4 elements
  const float4 v = reinterpret_cast<const float4*>(src)[i];
  reinterpret_cast<float4*>(dstF)[i] = v;
  ushort4 b;
  b.x = f2bf(v.x); b.y = f2bf(v.y); b.z = f2bf(v.z); b.w = f2bf(v.w);
  reinterpret_cast<ushort4*>(dstB)[i] = b;
}

// ---------------- MFMA flash attention (swapped operands) ----------------
// 1D grid of 1024: b = gid&7 (XCD-local K/V); h=(slot>>4)&7, qblk=15-(slot&15).
// S^T = mfma(K,Q): lane owns q-row li entirely -> scalar mrun/lrun, 4 shfls/tile.
// O^T = mfma(V^T,P^T): rescale lane-local; output packs as 2x8B stores.
__global__ __launch_bounds__(256)
void attn_mfma_k(const ushort_t* __restrict__ qb, const ushort_t* __restrict__ vbT,
                 const float* __restrict__ routing8, ushort_t* __restrict__ out,
                 int mask_val) {
  __shared__ ushort_t sk[2][2048];   // K tile: [kb 4][g 4][li=key 16][8] frag-linear
  __shared__ ushort_t sv[2][2048];   // V^T tile: [d 32][8 chunks, slot = ch^(d&7)][8]
  __shared__ ushort_t pbuf[4096];    // per-wave P^T frag-linear: [c 2][g 4][li=q 16][8]
  const int gid = blockIdx.x;
  const int b = gid & 7;
  const int slot = gid >> 3;
  const int h = (slot >> 4) & 7;
  const int qblk = 15 - (slot & 15);
  const int q0 = qblk * 64;
  const int tid = threadIdx.x;
  const int wave = tid >> 6, lane = tid & 63;
  const int g = lane >> 4, li = lane & 15;
  const int qw = q0 + wave * 16;
  const int qrow = qw + li;          // this lane's q row

  const frag_bf16 qf = *reinterpret_cast<const frag_bf16*>(
      &qb[((size_t)(b * SEQ + qrow)) * DMODEL + h * DKDIM + g * 8]);

  float mrun = -INFINITY, lrun = 0.f;
  f32x4 o0 = {0.f, 0.f, 0.f, 0.f}, o1 = {0.f, 0.f, 0.f, 0.f};  // O^T: d=4g+r(+16), q=li
  ushort_t* pP = &pbuf[wave * 1024];

  // K staging: unit (wave=kb, g, li) <- K[kb*16+li][g*8..]
  const ushort_t* gK = &qb[((size_t)(b * SEQ + wave * 16 + li)) * DMODEL + h * DKDIM + g * 8];
  // V staging: unit u=wave*64+lane -> row d=wave*8+(lane>>3), slot=lane&7,
  // content chunk = slot^(d&7)  (XOR pre-swizzled source, linear dest)
  const ushort_t* gV = &vbT[((size_t)((b * NHEADS + h) * DKDIM) + wave * 8 + (lane >> 3)) * SEQ
                            + ((lane & 7) ^ (lane >> 3)) * 8];

  const int nt = qblk + 1;
  GLOAD_LDS16(gK, sk[0] + wave * 512);
  GLOAD_LDS16(gV, sv[0] + wave * 512);
  SYNC_DRAIN();

  auto tile_step = [&](int t, int cur) {
    const int kt = t * 64;
    // S^T = K Q^T: lane holds rows key=kb*16+4g+r, col q=li
    f32x4 s[4];
#pragma unroll
    for (int kb = 0; kb < 4; ++kb) {
      frag_bf16 kf = *reinterpret_cast<const frag_bf16*>(&sk[cur][(kb * 64 + g * 16 + li) * 8]);
      f32x4 z = {0.f, 0.f, 0.f, 0.f};
      s[kb] = __builtin_amdgcn_mfma_f32_16x16x32_bf16(kf, qf, z, 0, 0, 0);
    }
    const bool need_mask = (kt + 63) >= (qw + mask_val);
    if (need_mask) {
#pragma unroll
      for (int kb = 0; kb < 4; ++kb)
#pragma unroll
        for (int r = 0; r < 4; ++r) {
          const int col = kt + kb * 16 + 4 * g + r;
          if (col >= (qrow + mask_val)) s[kb][r] = -1e9f;
        }
    }
    // row max (lane-local 16 values + 2 shfls across the 4 g-lanes of this row)
    float tm = -INFINITY;
#pragma unroll
    for (int kb = 0; kb < 4; ++kb)
#pragma unroll
      for (int r = 0; r < 4; ++r) tm = fmaxf(tm, s[kb][r]);
    tm = fmaxf(tm, __shfl_xor(tm, 16, 64));
    tm = fmaxf(tm, __shfl_xor(tm, 32, 64));
    const float mnew = fmaxf(mrun, tm);
    const float scl = __expf(mrun - mnew);
    float p[4][4];
    float psum = 0.f;
#pragma unroll
    for (int kb = 0; kb < 4; ++kb)
#pragma unroll
      for (int r = 0; r < 4; ++r) { p[kb][r] = __expf(s[kb][r] - mnew); psum += p[kb][r]; }
    psum += __shfl_xor(psum, 16, 64);
    psum += __shfl_xor(psum, 32, 64);
    lrun = lrun * scl + psum;
    mrun = mnew;
#pragma unroll
    for (int r = 0; r < 4; ++r) { o0[r] *= scl; o1[r] *= scl; }
    // P^T pack into fragment-linear: key k=kb*16+g*4+pair*2 -> unit(c,gg,li), ofs j
    //   c=kb>>1, gg=(kb&1)*2+(g>>1), j=4*(g&1)+2*pair   (4B-aligned b32 writes)
#pragma unroll
    for (int kb = 0; kb < 4; ++kb)
#pragma unroll
      for (int pair = 0; pair < 2; ++pair) {
        const unsigned pk = cvt_pk_bf16(p[kb][2 * pair], p[kb][2 * pair + 1]);
        const int addr = (((kb >> 1) * 4 + (kb & 1) * 2 + (g >> 1)) * 16 + li) * 8
                         + 4 * (g & 1) + 2 * pair;
        *reinterpret_cast<unsigned*>(&pP[addr]) = pk;
      }
    __threadfence_block();
    // O^T += V^T P^T : A-frag V^T[d=li(+16)][k=c*32+g*8+j], B-frag P^T[k][q=li]
#pragma unroll
    for (int c = 0; c < 2; ++c) {
      frag_bf16 pf = *reinterpret_cast<const frag_bf16*>(&pP[((c * 4 + g) * 16 + li) * 8]);
      frag_bf16 vf0 = *reinterpret_cast<const frag_bf16*>(
          &sv[cur][li * 64 + ((4 * c + g) ^ (li & 7)) * 8]);
      frag_bf16 vf1 = *reinterpret_cast<const frag_bf16*>(
          &sv[cur][(16 + li) * 64 + ((4 * c + g) ^ (li & 7)) * 8]);
      o0 = __builtin_amdgcn_mfma_f32_16x16x32_bf16(vf0, pf, o0, 0, 0, 0);
      o1 = __builtin_amdgcn_mfma_f32_16x16x32_bf16(vf1, pf, o1, 0, 0, 0);
    }
  };

  for (int t = 0; t < nt - 1; ++t) {
    const int cur = t & 1;
    const int kt = t * 64;
    GLOAD_LDS16(gK + (size_t)(kt + 64) * DMODEL, sk[cur ^ 1] + wave * 512);
    GLOAD_LDS16(gV + (kt + 64), sv[cur ^ 1] + wave * 512);
    tile_step(t, cur);
    SYNC_DRAIN();
  }
  tile_step(nt - 1, (nt - 1) & 1);

  const float rt = routing8[b * NHEADS + h];
  const float mult = rt / lrun;
  // ref: fully-masked row 0 (mask_val==0) -> uniform over ALL keys; patched below
  if (!(mask_val == 0 && qrow == 0)) {
    const size_t base = (size_t)(b * SEQ + qrow) * DMODEL + h * DKDIM;
    ushort4 w0, w1;
    w0.x = f2bf(o0[0] * mult); w0.y = f2bf(o0[1] * mult);
    w0.z = f2bf(o0[2] * mult); w0.w = f2bf(o0[3] * mult);
    w1.x = f2bf(o1[0] * mult); w1.y = f2bf(o1[1] * mult);
    w1.z = f2bf(o1[2] * mult); w1.w = f2bf(o1[3] * mult);
    *reinterpret_cast<ushort4*>(&out[base + 4 * g]) = w0;
    *reinterpret_cast<ushort4*>(&out[base + 16 + 4 * g]) = w1;
  }
  // fused row0 patch: out[b,0,h,:] = mean_k(V[k,:]) * rt
  if (mask_val == 0 && qblk == 0 && wave == 0) {
    const int d = lane >> 1, hf = lane & 1;
    const ushort_t* src = &vbT[(((size_t)(b * NHEADS + h)) * DKDIM + d) * SEQ + hf * 512];
    float s = 0.f;
    for (int k = 0; k < 512; k += 8) {
      frag_bf16 v = *reinterpret_cast<const frag_bf16*>(&src[k]);
#pragma unroll
      for (int j = 0; j < 8; ++j)
        s += __uint_as_float(((unsigned)(ushort_t)v[j]) << 16);
    }
    s += __shfl_xor(s, 1, 64);
    if (hf == 0)
      out[(size_t)(b * SEQ) * DMODEL + h * DKDIM + d] = f2bf(s * (1.0f / 1024.0f) * rt);
  }
}

// ---------------- Router ----------------
__global__ __launch_bounds__(128)
void router_k(const float* __restrict__ R, const float* __restrict__ Wg,
              float* __restrict__ partials) {
  __shared__ float sW[DMODEL * NDYN_C];
  __shared__ float red[18][128];
  const int tid = threadIdx.x;
  for (int t = tid; t < DMODEL * NDYN_C; t += 128) sW[t] = Wg[t];
  __syncthreads();
  const int r = blockIdx.x * 128 + tid;
  const int b = r >> 10;
  const int h = (r >> 7) & 7;
  const int s8 = r & 127;
  float lg[NDYN_C] = {};
  for (int t8 = 0; t8 < 8; ++t8) {
    const float* base = &R[((size_t)(b * SEQ + s8 * 8 + t8)) * DMODEL + h * DKDIM];
#pragma unroll
    for (int d = 0; d < DKDIM; ++d) {
      const float x = base[d];
      const float* w = &sW[(t8 * 32 + d) * NDYN_C];
#pragma unroll
      for (int j = 0; j < NDYN_C; ++j) lg[j] = fmaf(x, w[j], lg[j]);
    }
  }
  float mx = lg[0];
#pragma unroll
  for (int j = 1; j < NDYN_C; ++j) mx = fmaxf(mx, lg[j]);
  float e[NDYN_C], sum = 0.0f;
#pragma unroll
  for (int j = 0; j < NDYN_C; ++j) { e[j] = expf(lg[j] - mx); sum += e[j]; }
  float g[NDYN_C];
#pragma unroll
  for (int j = 0; j < NDYN_C; ++j) g[j] = e[j] / sum;
  int j1 = 0;
#pragma unroll
  for (int j = 1; j < NDYN_C; ++j) if (g[j] > g[j1]) j1 = j;
  int j2 = -1;
#pragma unroll
  for (int j = 0; j < NDYN_C; ++j) {
    if (j == j1) continue;
    if (j2 < 0 || g[j] > g[j2]) j2 = j;
  }
#pragma unroll
  for (int j = 0; j < NDYN_C; ++j) {
    const bool sel = (j == j1) || (j == j2);
    red[j][tid] = sel ? g[j] : 0.0f;
    red[6 + j][tid] = sel ? 1.0f : 0.0f;
    red[12 + j][tid] = g[j];
  }
  __syncthreads();
  if (tid < 18) {
    float s = 0.0f;
    for (int i = 0; i < 128; ++i) s += red[tid][i];
    partials[blockIdx.x * 18 + tid] = s;
  }
}

__global__ void router_reduce_k(const float* __restrict__ partials,
                                float* __restrict__ routing8,
                                float* __restrict__ bal_out) {
  const int tid = threadIdx.x;
  if (tid < 48) {
    const int b = tid / 6, j = tid % 6;
    float s = 0.0f;
    for (int t = 0; t < 8; ++t) s += partials[(b * 8 + t) * 18 + j];
    routing8[b * NHEADS + 2 + j] = s * (1.0f / 1024.0f);
  } else if (tid < 56) {
    const int b = tid - 48;
    routing8[b * NHEADS + 0] = 1.0f;
    routing8[b * NHEADS + 1] = 1.0f;
  } else if (tid == 56) {
    float hs[6], hp[6];
    float hssum = 0.0f, hpsum = 0.0f;
    for (int j = 0; j < 6; ++j) {
      float a = 0.0f, c = 0.0f;
      for (int bi = 0; bi < 64; ++bi) {
        a += partials[bi * 18 + 6 + j];
        c += partials[bi * 18 + 12 + j];
      }
      hs[j] = a;
      hp[j] = c * (1.0f / 8192.0f);
      hssum += hs[j];
      hpsum += hp[j];
    }
    float bal = 0.0f;
    for (int j = 0; j < 6; ++j)
      bal += (hs[j] / (hssum + 1e-5f)) * (hp[j] / (hpsum + 1e-5f));
    *bal_out = bal;
  }
}

// ---------------- residual add + layernorm (Xin -> Xout f32 + Xbf bf16) ----
__global__ __launch_bounds__(256)
void add_ln_k(const float* __restrict__ Xin, float* __restrict__ Xout,
              ushort_t* __restrict__ Xbf, const float* __restrict__ Y,
              const float* __restrict__ g, const float* __restrict__ be) {
  const int r = blockIdx.x;
  const int c = threadIdx.x;
  const size_t idx = (size_t)r * DMODEL + c;
  const float x = Xin[idx] + Y[idx];
  __shared__ float sh[4];
  float s = x;
#pragma unroll
  for (int o = 32; o >= 1; o >>= 1) s += __shfl_xor(s, o, 64);
  if ((c & 63) == 0) sh[c >> 6] = s;
  __syncthreads();
  const float mean = (sh[0] + sh[1] + sh[2] + sh[3]) * (1.0f / DMODEL);
  const float d = x - mean;
  float vsum = d * d;
  __syncthreads();
#pragma unroll
  for (int o = 32; o >= 1; o >>= 1) vsum += __shfl_xor(vsum, o, 64);
  if ((c & 63) == 0) sh[c >> 6] = vsum;
  __syncthreads();
  const float var = (sh[0] + sh[1] + sh[2] + sh[3]) * (1.0f / DMODEL);
  const float rv = d * (1.0f / sqrtf(var + 1e-5f)) * g[c] + be[c];
  Xout[idx] = rv;
  Xbf[idx] = f2bf(rv);
}

// ---------------- driver ----------------
extern "C" void kernel_launch(void* const* d_in, const int* in_sizes, int n_in,
                              void* d_out, int out_size, void* d_ws, size_t ws_size,
                              hipStream_t stream) {
  const float* q_embed  = (const float*)d_in[0];
  const float* qa_embed = (const float*)d_in[1];
  const float* Wq  = (const float*)d_in[2];
  const float* bq  = (const float*)d_in[3];
  const float* Wv  = (const float*)d_in[4];
  const float* bv  = (const float*)d_in[5];
  const float* Wg  = (const float*)d_in[6];
  const float* Wo  = (const float*)d_in[7];
  const float* bo  = (const float*)d_in[8];
  const float* ln1w = (const float*)d_in[9];
  const float* ln1b = (const float*)d_in[10];
  const float* Wf1 = (const float*)d_in[11];
  const float* bf1 = (const float*)d_in[12];
  const float* Wf2 = (const float*)d_in[13];
  const float* bf2 = (const float*)d_in[14];
  const float* ln2w = (const float*)d_in[15];
  const float* ln2b = (const float*)d_in[16];
  float* out = (float*)d_out;

  const size_t NA = (size_t)NTOK_C * DMODEL;  // 2097152
  float* xbuf = (float*)d_ws;
  float* ybuf = xbuf + NA;
  float* ob   = ybuf + NA;
  float* routing8   = ob + NA;
  float* partials   = routing8 + 64;
  float* balscratch = partials + 64 * 18;
  ushort_t* xbf   = (ushort_t*)(balscratch + 16);
  ushort_t* ybf   = xbf + NA;
  ushort_t* qb_bf = ybf + NA;
  ushort_t* vbT   = qb_bf + NA;
  ushort_t* ab_bf = vbT + NA;
  ushort_t* hb    = ab_bf + NA;                       // NTOK * DFF bf16
  ushort_t* WqT   = hb + (size_t)NTOK_C * DFF_C;
  ushort_t* WvT   = WqT + (size_t)6 * DMODEL * DMODEL;
  ushort_t* WoT   = WvT + (size_t)6 * DMODEL * DMODEL;
  ushort_t* Wf1T  = WoT + (size_t)6 * DMODEL * DMODEL;
  ushort_t* Wf2T  = Wf1T + (size_t)6 * DMODEL * DFF_C;

  // weight prep
  transpose_k<<<dim3(8, 8, 6), 256, 0, stream>>>(Wq, WqT, DMODEL, DMODEL);
  transpose_k<<<dim3(8, 8, 6), 256, 0, stream>>>(Wv, WvT, DMODEL, DMODEL);
  transpose_k<<<dim3(8, 8, 6), 256, 0, stream>>>(Wo, WoT, DMODEL, DMODEL);
  transpose_k<<<dim3(32, 8, 6), 256, 0, stream>>>(Wf1, Wf1T, DMODEL, DFF_C);
  transpose_k<<<dim3(8, 32, 6), 256, 0, stream>>>(Wf2, Wf2T, DFF_C, DMODEL);
  conv_init_k<<<NA / 1024, 256, 0, stream>>>(q_embed, xbuf, xbf);
  conv_init_k<<<NA / 1024, 256, 0, stream>>>(qa_embed, ybuf, ybf);

  auto run_layer = [&](int l, float* Q, ushort_t* Qbf, const ushort_t* Vbf,
                       int mask_val, bool ffn, bool last) {
    const float* bq_l = bq + (size_t)l * DMODEL;
    const float* bv_l = bv + (size_t)l * DMODEL;
    const float* Wg_l = Wg + (size_t)l * DMODEL * NDYN_C;
    const float* bo_l = bo + (size_t)l * DMODEL;
    const float* g1_l = ln1w + (size_t)l * DMODEL;
    const float* b1_l = ln1b + (size_t)l * DMODEL;
    const ushort_t* WqT_l = WqT + (size_t)l * DMODEL * DMODEL;
    const ushort_t* WvT_l = WvT + (size_t)l * DMODEL * DMODEL;
    const ushort_t* WoT_l = WoT + (size_t)l * DMODEL * DMODEL;

    router_k<<<64, 128, 0, stream>>>(xbuf, Wg_l, partials);
    router_reduce_k<<<1, 64, 0, stream>>>(partials, routing8,
                                          last ? (out + NA) : balscratch);
    gemm_qv_k<<<dim3(128, 4, 2), 256, 0, stream>>>(
        Qbf, WqT_l, bq_l, qb_bf, WvT_l, Vbf, bv_l, vbT);
    attn_mfma_k<<<1024, 256, 0, stream>>>(qb_bf, vbT, routing8, ab_bf, mask_val);
    gemm_mfma_k<0><<<dim3(4, 128), 256, 0, stream>>>(
        ab_bf, WoT_l, bo_l, ob, NTOK_C, DMODEL, DMODEL);
    add_ln_k<<<NTOK_C, DMODEL, 0, stream>>>(Q, Q, Qbf, ob, g1_l, b1_l);
    if (ffn) {
      const float* bf1_l = bf1 + (size_t)l * DFF_C;
      const float* bf2_l = bf2 + (size_t)l * DMODEL;
      const float* g2_l = ln2w + (size_t)l * DMODEL;
      const float* b2_l = ln2b + (size_t)l * DMODEL;
      const ushort_t* Wf1T_l = Wf1T + (size_t)l * DMODEL * DFF_C;
      const ushort_t* Wf2T_l = Wf2T + (size_t)l * DFF_C * DMODEL;
      gemm_mfma_k<2><<<dim3(16, 128), 256, 0, stream>>>(
          Qbf, Wf1T_l, bf1_l, hb, NTOK_C, DFF_C, DMODEL);
      gemm_mfma_k<0><<<dim3(4, 128), 256, 0, stream>>>(
          hb, Wf2T_l, bf2_l, ob, NTOK_C, DMODEL, DFF_C);
      // last layer: write the final layernorm result straight to d_out
      add_ln_k<<<NTOK_C, DMODEL, 0, stream>>>(Q, last ? out : Q, Qbf, ob, g2_l, b2_l);
    }
  };

  // blocks_1: y-stream, router input = x (q_embed copy, unchanged during blocks_1)
  run_layer(0, ybuf, ybf, ybf, 1, true, false);
  run_layer(1, ybuf, ybf, ybf, 1, true, false);
  // blocks_2: (self, no FFN) then (cross to y, strict causal, FFN)
  run_layer(2, xbuf, xbf, xbf, 1, false, false);
  run_layer(3, xbuf, xbf, ybf, 0, true, false);
  run_layer(4, xbuf, xbf, xbf, 1, false, false);
  run_layer(5, xbuf, xbf, ybf, 0, true, true);
}

// Round 10
// 587.150 us; speedup vs baseline: 4.9682x; 1.0468x over previous
//
#include <hip/hip_runtime.h>

// RouterKT forward. Round 10: BISECTION — exact verified R7 kernel + ONLY the
// wave-per-row add_ln changed. (R8/R9's 2-qtile attention is excluded; if this
// passes, that attention rewrite is the proven culprit.)

constexpr int DMODEL = 256;
constexpr int SEQ    = 1024;
constexpr int BATCH  = 8;
constexpr int NHEADS = 8;
constexpr int DKDIM  = 32;
constexpr int NDYN_C = 6;
constexpr int NTOK_C = BATCH * SEQ;   // 8192
constexpr int DFF_C  = 1024;

using frag_bf16 = __attribute__((ext_vector_type(8))) short;  // 8 bf16 = 4 VGPR
using f32x4    = __attribute__((ext_vector_type(4))) float;
typedef unsigned short ushort_t;

__device__ __forceinline__ ushort_t f2bf(float f) {
  unsigned u = __float_as_uint(f);
  unsigned r = (u + 0x7fffu + ((u >> 16) & 1u)) >> 16;   // RNE, finite inputs
  return (ushort_t)r;
}

__device__ __forceinline__ unsigned cvt_pk_bf16(float lo, float hi) {
  unsigned r;
  asm("v_cvt_pk_bf16_f32 %0, %1, %2" : "=v"(r) : "v"(lo), "v"(hi));
  return r;
}

#define GLOAD_LDS16(gsrc, ldst)                                             \
  __builtin_amdgcn_global_load_lds(                                         \
      (const __attribute__((address_space(1))) void*)(gsrc),                \
      (__attribute__((address_space(3))) void*)(ldst), 16, 0, 0)

// Explicit drain + order pin + barrier (race-proof prefetch handoff).
#define SYNC_DRAIN()                                                        \
  do {                                                                      \
    asm volatile("s_waitcnt vmcnt(0) lgkmcnt(0)" ::: "memory");             \
    __builtin_amdgcn_sched_barrier(0);                                      \
    __syncthreads();                                                        \
  } while (0)

// ---------------- bf16 MFMA GEMM body (2-phase prefetch, explicit drain) ------
// C[m][n] = sum_k A[m][k] * B[n][k] + bias.   A:[M][K] bf16, B:[N][K] bf16.
// Tile: BM=64, BN=64, BK=64, double-buffered. 256 threads = 4 waves (2x2).
// MODE: 0 = f32 C[M][N], 1 = bf16*QSCALE (q-proj), 2 = bf16+relu, 3 = vbT scatter.
template<int MODE>
__device__ __forceinline__
void gemm_body(int bx, int by,
               const ushort_t* __restrict__ A, const ushort_t* __restrict__ B,
               const float* __restrict__ bias, void* __restrict__ Cp,
               int M, int N, int K) {
  __shared__ ushort_t sA[2][4096];
  __shared__ ushort_t sB[2][4096];
  const int tid = threadIdx.x;
  const int wid = tid >> 6, lane = tid & 63;
  const int li = lane & 15, g = lane >> 4;
  const int wr = wid >> 1, wc = wid & 1;
  const int m0 = by * 64, n0 = bx * 64;
  f32x4 acc[2][2] = {};
  const int srow = wid * 8 + (lane >> 3);
  const int schk = (lane & 7) ^ (lane >> 3);
  const ushort_t* gA1 = &A[(size_t)(m0 + srow) * K + schk * 8];
  const ushort_t* gA2 = &A[(size_t)(m0 + 32 + srow) * K + schk * 8];
  const ushort_t* gB1 = &B[(size_t)(n0 + srow) * K + schk * 8];
  const ushort_t* gB2 = &B[(size_t)(n0 + 32 + srow) * K + schk * 8];
  const int nk = K >> 6;

  GLOAD_LDS16(gA1, sA[0] + wid * 512);
  GLOAD_LDS16(gA2, sA[0] + 2048 + wid * 512);
  GLOAD_LDS16(gB1, sB[0] + wid * 512);
  GLOAD_LDS16(gB2, sB[0] + 2048 + wid * 512);
  SYNC_DRAIN();

  auto compute = [&](int cur) {
#pragma unroll
    for (int s = 0; s < 2; ++s) {
      frag_bf16 af[2], bf[2];
#pragma unroll
      for (int m = 0; m < 2; ++m) {
        const int row = wr * 32 + m * 16 + li;
        af[m] = *reinterpret_cast<const frag_bf16*>(
            &sA[cur][row * 64 + ((s * 4 + g) ^ (row & 7)) * 8]);
      }
#pragma unroll
      for (int n = 0; n < 2; ++n) {
        const int row = wc * 32 + n * 16 + li;
        bf[n] = *reinterpret_cast<const frag_bf16*>(
            &sB[cur][row * 64 + ((s * 4 + g) ^ (row & 7)) * 8]);
      }
#pragma unroll
      for (int m = 0; m < 2; ++m)
#pragma unroll
        for (int n = 0; n < 2; ++n)
          acc[m][n] = __builtin_amdgcn_mfma_f32_16x16x32_bf16(af[m], bf[n], acc[m][n], 0, 0, 0);
    }
  };

  for (int kt = 0; kt < nk - 1; ++kt) {
    const int cur = kt & 1;
    const int k1 = (kt + 1) << 6;
    GLOAD_LDS16(gA1 + k1, sA[cur ^ 1] + wid * 512);
    GLOAD_LDS16(gA2 + k1, sA[cur ^ 1] + 2048 + wid * 512);
    GLOAD_LDS16(gB1 + k1, sB[cur ^ 1] + wid * 512);
    GLOAD_LDS16(gB2 + k1, sB[cur ^ 1] + 2048 + wid * 512);
    compute(cur);
    SYNC_DRAIN();
  }
  compute((nk - 1) & 1);

  constexpr float QSCALE = 0.42044820762685725f;  // 32^-0.25; k=q so (qs)(ks)=qk/sqrt(32)
#pragma unroll
  for (int m = 0; m < 2; ++m)
#pragma unroll
    for (int n = 0; n < 2; ++n)
#pragma unroll
      for (int r = 0; r < 4; ++r) {
        const int mg = m0 + wr * 32 + m * 16 + g * 4 + r;
        const int ng = n0 + wc * 32 + n * 16 + li;
        if (MODE == 0) {
          ((float*)Cp)[(size_t)mg * N + ng] = acc[m][n][r] + bias[ng];
        } else if (MODE == 1) {
          ((ushort_t*)Cp)[(size_t)mg * N + ng] = f2bf((acc[m][n][r] + bias[ng]) * QSCALE);
        } else if (MODE == 2) {
          ((ushort_t*)Cp)[(size_t)mg * N + ng] = f2bf(fmaxf(acc[m][n][r] + bias[ng], 0.0f));
        } else {
          ((ushort_t*)Cp)[((size_t)((ng >> 10) * 256 + mg)) * SEQ + (ng & 1023)] =
              f2bf(acc[m][n][r] + bias[mg]);
        }
      }
}

template<int MODE>
__global__ __launch_bounds__(256)
void gemm_mfma_k(const ushort_t* __restrict__ A, const ushort_t* __restrict__ B,
                 const float* __restrict__ bias, void* __restrict__ Cp,
                 int M, int N, int K) {
  gemm_body<MODE>(blockIdx.x, blockIdx.y, A, B, bias, Cp, M, N, K);
}

// merged Q-projection (MODE 1) + V-projection (MODE 3): grid (128,4,2)
__global__ __launch_bounds__(256)
void gemm_qv_k(const ushort_t* __restrict__ Aq, const ushort_t* __restrict__ Bq,
               const float* __restrict__ biasq, void* __restrict__ Cq,
               const ushort_t* __restrict__ Av, const ushort_t* __restrict__ Bv,
               const float* __restrict__ biasv, void* __restrict__ Cv) {
  if (blockIdx.z == 0)
    gemm_body<1>(blockIdx.y, blockIdx.x, Aq, Bq, biasq, Cq, NTOK_C, DMODEL, DMODEL);
  else
    gemm_body<3>(blockIdx.x, blockIdx.y, Av, Bv, biasv, Cv, DMODEL, NTOK_C, DMODEL);
}

// ---------------- weight transpose+convert: in [z][R][C] f32 -> out [z][C][R] bf16 ----
__global__ __launch_bounds__(256)
void transpose_k(const float* __restrict__ in, ushort_t* __restrict__ out, int R, int C) {
  __shared__ float t[32][33];
  const int z = blockIdx.z;
  const int c0 = blockIdx.x * 32, r0 = blockIdx.y * 32;
  const int tx = threadIdx.x & 31, ty = threadIdx.x >> 5;   // ty 0..7
  const float* ip = in + (size_t)z * R * C;
  ushort_t* op = out + (size_t)z * R * C;
#pragma unroll
  for (int i = 0; i < 4; ++i) t[ty + 8 * i][tx] = ip[(size_t)(r0 + ty + 8 * i) * C + c0 + tx];
  __syncthreads();
#pragma unroll
  for (int i = 0; i < 4; ++i)
    op[(size_t)(c0 + ty + 8 * i) * R + r0 + tx] = f2bf(t[tx][ty + 8 * i]);
}

// ---------------- f32 copy + bf16 mirror ----------------
__global__ __launch_bounds__(256)
void conv_init_k(const float* __restrict__ src, float* __restrict__ dstF,
                 ushort_t* __restrict__ dstB) {
  const int i = blockIdx.x * 256 + threadIdx.x;   // over float4 elements
  const float4 v = reinterpret_cast<const float4*>(src)[i];
  reinterpret_cast<float4*>(dstF)[i] = v;
  ushort4 b;
  b.x = f2bf(v.x); b.y = f2bf(v.y); b.z = f2bf(v.z); b.w = f2bf(v.w);
  reinterpret_cast<ushort4*>(dstB)[i] = b;
}

// ---------------- MFMA flash attention (swapped operands) — R7 verified -------
// 1D grid of 1024: b = gid&7 (XCD-local K/V); h=(slot>>4)&7, qblk=15-(slot&15).
// S^T = mfma(K,Q): lane owns q-row li entirely -> scalar mrun/lrun, 4 shfls/tile.
// O^T = mfma(V^T,P^T): rescale lane-local; output packs as 2x8B stores.
__global__ __launch_bounds__(256)
void attn_mfma_k(const ushort_t* __restrict__ qb, const ushort_t* __restrict__ vbT,
                 const float* __restrict__ routing8, ushort_t* __restrict__ out,
                 int mask_val) {
  __shared__ ushort_t sk[2][2048];   // K tile: [kb 4][g 4][li=key 16][8] frag-linear
  __shared__ ushort_t sv[2][2048];   // V^T tile: [d 32][8 chunks, slot = ch^(d&7)][8]
  __shared__ ushort_t pbuf[4096];    // per-wave P^T frag-linear: [c 2][g 4][li=q 16][8]
  const int gid = blockIdx.x;
  const int b = gid & 7;
  const int slot = gid >> 3;
  const int h = (slot >> 4) & 7;
  const int qblk = 15 - (slot & 15);
  const int q0 = qblk * 64;
  const int tid = threadIdx.x;
  const int wave = tid >> 6, lane = tid & 63;
  const int g = lane >> 4, li = lane & 15;
  const int qw = q0 + wave * 16;
  const int qrow = qw + li;          // this lane's q row

  const frag_bf16 qf = *reinterpret_cast<const frag_bf16*>(
      &qb[((size_t)(b * SEQ + qrow)) * DMODEL + h * DKDIM + g * 8]);

  float mrun = -INFINITY, lrun = 0.f;
  f32x4 o0 = {0.f, 0.f, 0.f, 0.f}, o1 = {0.f, 0.f, 0.f, 0.f};  // O^T: d=4g+r(+16), q=li
  ushort_t* pP = &pbuf[wave * 1024];

  // K staging: unit (wave=kb, g, li) <- K[kb*16+li][g*8..]
  const ushort_t* gK = &qb[((size_t)(b * SEQ + wave * 16 + li)) * DMODEL + h * DKDIM + g * 8];
  // V staging: unit u=wave*64+lane -> row d=wave*8+(lane>>3), slot=lane&7,
  // content chunk = slot^(d&7)  (XOR pre-swizzled source, linear dest)
  const ushort_t* gV = &vbT[((size_t)((b * NHEADS + h) * DKDIM) + wave * 8 + (lane >> 3)) * SEQ
                            + ((lane & 7) ^ (lane >> 3)) * 8];

  const int nt = qblk + 1;
  GLOAD_LDS16(gK, sk[0] + wave * 512);
  GLOAD_LDS16(gV, sv[0] + wave * 512);
  SYNC_DRAIN();

  auto tile_step = [&](int t, int cur) {
    const int kt = t * 64;
    // S^T = K Q^T: lane holds rows key=kb*16+4g+r, col q=li
    f32x4 s[4];
#pragma unroll
    for (int kb = 0; kb < 4; ++kb) {
      frag_bf16 kf = *reinterpret_cast<const frag_bf16*>(&sk[cur][(kb * 64 + g * 16 + li) * 8]);
      f32x4 z = {0.f, 0.f, 0.f, 0.f};
      s[kb] = __builtin_amdgcn_mfma_f32_16x16x32_bf16(kf, qf, z, 0, 0, 0);
    }
    const bool need_mask = (kt + 63) >= (qw + mask_val);
    if (need_mask) {
#pragma unroll
      for (int kb = 0; kb < 4; ++kb)
#pragma unroll
        for (int r = 0; r < 4; ++r) {
          const int col = kt + kb * 16 + 4 * g + r;
          if (col >= (qrow + mask_val)) s[kb][r] = -1e9f;
        }
    }
    // row max (lane-local 16 values + 2 shfls across the 4 g-lanes of this row)
    float tm = -INFINITY;
#pragma unroll
    for (int kb = 0; kb < 4; ++kb)
#pragma unroll
      for (int r = 0; r < 4; ++r) tm = fmaxf(tm, s[kb][r]);
    tm = fmaxf(tm, __shfl_xor(tm, 16, 64));
    tm = fmaxf(tm, __shfl_xor(tm, 32, 64));
    const float mnew = fmaxf(mrun, tm);
    const float scl = __expf(mrun - mnew);
    float p[4][4];
    float psum = 0.f;
#pragma unroll
    for (int kb = 0; kb < 4; ++kb)
#pragma unroll
      for (int r = 0; r < 4; ++r) { p[kb][r] = __expf(s[kb][r] - mnew); psum += p[kb][r]; }
    psum += __shfl_xor(psum, 16, 64);
    psum += __shfl_xor(psum, 32, 64);
    lrun = lrun * scl + psum;
    mrun = mnew;
#pragma unroll
    for (int r = 0; r < 4; ++r) { o0[r] *= scl; o1[r] *= scl; }
    // P^T pack into fragment-linear: key k=kb*16+g*4+pair*2 -> unit(c,gg,li), ofs j
    //   c=kb>>1, gg=(kb&1)*2+(g>>1), j=4*(g&1)+2*pair   (4B-aligned b32 writes)
#pragma unroll
    for (int kb = 0; kb < 4; ++kb)
#pragma unroll
      for (int pair = 0; pair < 2; ++pair) {
        const unsigned pk = cvt_pk_bf16(p[kb][2 * pair], p[kb][2 * pair + 1]);
        const int addr = (((kb >> 1) * 4 + (kb & 1) * 2 + (g >> 1)) * 16 + li) * 8
                         + 4 * (g & 1) + 2 * pair;
        *reinterpret_cast<unsigned*>(&pP[addr]) = pk;
      }
    __threadfence_block();
    // O^T += V^T P^T : A-frag V^T[d=li(+16)][k=c*32+g*8+j], B-frag P^T[k][q=li]
#pragma unroll
    for (int c = 0; c < 2; ++c) {
      frag_bf16 pf = *reinterpret_cast<const frag_bf16*>(&pP[((c * 4 + g) * 16 + li) * 8]);
      frag_bf16 vf0 = *reinterpret_cast<const frag_bf16*>(
          &sv[cur][li * 64 + ((4 * c + g) ^ (li & 7)) * 8]);
      frag_bf16 vf1 = *reinterpret_cast<const frag_bf16*>(
          &sv[cur][(16 + li) * 64 + ((4 * c + g) ^ (li & 7)) * 8]);
      o0 = __builtin_amdgcn_mfma_f32_16x16x32_bf16(vf0, pf, o0, 0, 0, 0);
      o1 = __builtin_amdgcn_mfma_f32_16x16x32_bf16(vf1, pf, o1, 0, 0, 0);
    }
  };

  for (int t = 0; t < nt - 1; ++t) {
    const int cur = t & 1;
    const int kt = t * 64;
    GLOAD_LDS16(gK + (size_t)(kt + 64) * DMODEL, sk[cur ^ 1] + wave * 512);
    GLOAD_LDS16(gV + (kt + 64), sv[cur ^ 1] + wave * 512);
    tile_step(t, cur);
    SYNC_DRAIN();
  }
  tile_step(nt - 1, (nt - 1) & 1);

  const float rt = routing8[b * NHEADS + h];
  const float mult = rt / lrun;
  // ref: fully-masked row 0 (mask_val==0) -> uniform over ALL keys; patched below
  if (!(mask_val == 0 && qrow == 0)) {
    const size_t base = (size_t)(b * SEQ + qrow) * DMODEL + h * DKDIM;
    ushort4 w0, w1;
    w0.x = f2bf(o0[0] * mult); w0.y = f2bf(o0[1] * mult);
    w0.z = f2bf(o0[2] * mult); w0.w = f2bf(o0[3] * mult);
    w1.x = f2bf(o1[0] * mult); w1.y = f2bf(o1[1] * mult);
    w1.z = f2bf(o1[2] * mult); w1.w = f2bf(o1[3] * mult);
    *reinterpret_cast<ushort4*>(&out[base + 4 * g]) = w0;
    *reinterpret_cast<ushort4*>(&out[base + 16 + 4 * g]) = w1;
  }
  // fused row0 patch: out[b,0,h,:] = mean_k(V[k,:]) * rt
  if (mask_val == 0 && qblk == 0 && wave == 0) {
    const int d = lane >> 1, hf = lane & 1;
    const ushort_t* src = &vbT[(((size_t)(b * NHEADS + h)) * DKDIM + d) * SEQ + hf * 512];
    float s = 0.f;
    for (int k = 0; k < 512; k += 8) {
      frag_bf16 v = *reinterpret_cast<const frag_bf16*>(&src[k]);
#pragma unroll
      for (int j = 0; j < 8; ++j)
        s += __uint_as_float(((unsigned)(ushort_t)v[j]) << 16);
    }
    s += __shfl_xor(s, 1, 64);
    if (hf == 0)
      out[(size_t)(b * SEQ) * DMODEL + h * DKDIM + d] = f2bf(s * (1.0f / 1024.0f) * rt);
  }
}

// ---------------- Router ----------------
__global__ __launch_bounds__(128)
void router_k(const float* __restrict__ R, const float* __restrict__ Wg,
              float* __restrict__ partials) {
  __shared__ float sW[DMODEL * NDYN_C];
  __shared__ float red[18][128];
  const int tid = threadIdx.x;
  for (int t = tid; t < DMODEL * NDYN_C; t += 128) sW[t] = Wg[t];
  __syncthreads();
  const int r = blockIdx.x * 128 + tid;
  const int b = r >> 10;
  const int h = (r >> 7) & 7;
  const int s8 = r & 127;
  float lg[NDYN_C] = {};
  for (int t8 = 0; t8 < 8; ++t8) {
    const float* base = &R[((size_t)(b * SEQ + s8 * 8 + t8)) * DMODEL + h * DKDIM];
#pragma unroll
    for (int d = 0; d < DKDIM; ++d) {
      const float x = base[d];
      const float* w = &sW[(t8 * 32 + d) * NDYN_C];
#pragma unroll
      for (int j = 0; j < NDYN_C; ++j) lg[j] = fmaf(x, w[j], lg[j]);
    }
  }
  float mx = lg[0];
#pragma unroll
  for (int j = 1; j < NDYN_C; ++j) mx = fmaxf(mx, lg[j]);
  float e[NDYN_C], sum = 0.0f;
#pragma unroll
  for (int j = 0; j < NDYN_C; ++j) { e[j] = expf(lg[j] - mx); sum += e[j]; }
  float g[NDYN_C];
#pragma unroll
  for (int j = 0; j < NDYN_C; ++j) g[j] = e[j] / sum;
  int j1 = 0;
#pragma unroll
  for (int j = 1; j < NDYN_C; ++j) if (g[j] > g[j1]) j1 = j;
  int j2 = -1;
#pragma unroll
  for (int j = 0; j < NDYN_C; ++j) {
    if (j == j1) continue;
    if (j2 < 0 || g[j] > g[j2]) j2 = j;
  }
#pragma unroll
  for (int j = 0; j < NDYN_C; ++j) {
    const bool sel = (j == j1) || (j == j2);
    red[j][tid] = sel ? g[j] : 0.0f;
    red[6 + j][tid] = sel ? 1.0f : 0.0f;
    red[12 + j][tid] = g[j];
  }
  __syncthreads();
  if (tid < 18) {
    float s = 0.0f;
    for (int i = 0; i < 128; ++i) s += red[tid][i];
    partials[blockIdx.x * 18 + tid] = s;
  }
}

__global__ void router_reduce_k(const float* __restrict__ partials,
                                float* __restrict__ routing8,
                                float* __restrict__ bal_out) {
  const int tid = threadIdx.x;
  if (tid < 48) {
    const int b = tid / 6, j = tid % 6;
    float s = 0.0f;
    for (int t = 0; t < 8; ++t) s += partials[(b * 8 + t) * 18 + j];
    routing8[b * NHEADS + 2 + j] = s * (1.0f / 1024.0f);
  } else if (tid < 56) {
    const int b = tid - 48;
    routing8[b * NHEADS + 0] = 1.0f;
    routing8[b * NHEADS + 1] = 1.0f;
  } else if (tid == 56) {
    float hs[6], hp[6];
    float hssum = 0.0f, hpsum = 0.0f;
    for (int j = 0; j < 6; ++j) {
      float a = 0.0f, c = 0.0f;
      for (int bi = 0; bi < 64; ++bi) {
        a += partials[bi * 18 + 6 + j];
        c += partials[bi * 18 + 12 + j];
      }
      hs[j] = a;
      hp[j] = c * (1.0f / 8192.0f);
      hssum += hs[j];
      hpsum += hp[j];
    }
    float bal = 0.0f;
    for (int j = 0; j < 6; ++j)
      bal += (hs[j] / (hssum + 1e-5f)) * (hp[j] / (hpsum + 1e-5f));
    *bal_out = bal;
  }
}

// ---------------- residual add + layernorm: one wave per row, shfl-only ----
__global__ __launch_bounds__(256)
void add_ln_k(const float* __restrict__ Xin, float* __restrict__ Xout,
              ushort_t* __restrict__ Xbf, const float* __restrict__ Y,
              const float* __restrict__ g, const float* __restrict__ be) {
  const int wave = threadIdx.x >> 6, lane = threadIdx.x & 63;
  const int r = blockIdx.x * 4 + wave;
  const size_t base = (size_t)r * DMODEL + lane * 4;
  float4 x = *reinterpret_cast<const float4*>(&Xin[base]);
  const float4 y = *reinterpret_cast<const float4*>(&Y[base]);
  x.x += y.x; x.y += y.y; x.z += y.z; x.w += y.w;
  float s = x.x + x.y + x.z + x.w;
#pragma unroll
  for (int o = 32; o >= 1; o >>= 1) s += __shfl_xor(s, o, 64);
  const float mean = s * (1.0f / DMODEL);
  const float4 d = {x.x - mean, x.y - mean, x.z - mean, x.w - mean};
  float v = d.x * d.x + d.y * d.y + d.z * d.z + d.w * d.w;
#pragma unroll
  for (int o = 32; o >= 1; o >>= 1) v += __shfl_xor(v, o, 64);
  const float rstd = 1.0f / sqrtf(v * (1.0f / DMODEL) + 1e-5f);
  const float4 gg = *reinterpret_cast<const float4*>(&g[lane * 4]);
  const float4 bb = *reinterpret_cast<const float4*>(&be[lane * 4]);
  float4 rv;
  rv.x = d.x * rstd * gg.x + bb.x;
  rv.y = d.y * rstd * gg.y + bb.y;
  rv.z = d.z * rstd * gg.z + bb.z;
  rv.w = d.w * rstd * gg.w + bb.w;
  *reinterpret_cast<float4*>(&Xout[base]) = rv;
  ushort4 o4;
  o4.x = f2bf(rv.x); o4.y = f2bf(rv.y); o4.z = f2bf(rv.z); o4.w = f2bf(rv.w);
  *reinterpret_cast<ushort4*>(&Xbf[base]) = o4;
}

// ---------------- driver ----------------
extern "C" void kernel_launch(void* const* d_in, const int* in_sizes, int n_in,
                              void* d_out, int out_size, void* d_ws, size_t ws_size,
                              hipStream_t stream) {
  const float* q_embed  = (const float*)d_in[0];
  const float* qa_embed = (const float*)d_in[1];
  const float* Wq  = (const float*)d_in[2];
  const float* bq  = (const float*)d_in[3];
  const float* Wv  = (const float*)d_in[4];
  const float* bv  = (const float*)d_in[5];
  const float* Wg  = (const float*)d_in[6];
  const float* Wo  = (const float*)d_in[7];
  const float* bo  = (const float*)d_in[8];
  const float* ln1w = (const float*)d_in[9];
  const float* ln1b = (const float*)d_in[10];
  const float* Wf1 = (const float*)d_in[11];
  const float* bf1 = (const float*)d_in[12];
  const float* Wf2 = (const float*)d_in[13];
  const float* bf2 = (const float*)d_in[14];
  const float* ln2w = (const float*)d_in[15];
  const float* ln2b = (const float*)d_in[16];
  float* out = (float*)d_out;

  const size_t NA = (size_t)NTOK_C * DMODEL;  // 2097152
  float* xbuf = (float*)d_ws;
  float* ybuf = xbuf + NA;
  float* ob   = ybuf + NA;
  float* routing8   = ob + NA;
  float* partials   = routing8 + 64;
  float* balscratch = partials + 64 * 18;
  ushort_t* xbf   = (ushort_t*)(balscratch + 16);
  ushort_t* ybf   = xbf + NA;
  ushort_t* qb_bf = ybf + NA;
  ushort_t* vbT   = qb_bf + NA;
  ushort_t* ab_bf = vbT + NA;
  ushort_t* hb    = ab_bf + NA;                       // NTOK * DFF bf16
  ushort_t* WqT   = hb + (size_t)NTOK_C * DFF_C;
  ushort_t* WvT   = WqT + (size_t)6 * DMODEL * DMODEL;
  ushort_t* WoT   = WvT + (size_t)6 * DMODEL * DMODEL;
  ushort_t* Wf1T  = WoT + (size_t)6 * DMODEL * DMODEL;
  ushort_t* Wf2T  = Wf1T + (size_t)6 * DMODEL * DFF_C;

  // weight prep
  transpose_k<<<dim3(8, 8, 6), 256, 0, stream>>>(Wq, WqT, DMODEL, DMODEL);
  transpose_k<<<dim3(8, 8, 6), 256, 0, stream>>>(Wv, WvT, DMODEL, DMODEL);
  transpose_k<<<dim3(8, 8, 6), 256, 0, stream>>>(Wo, WoT, DMODEL, DMODEL);
  transpose_k<<<dim3(32, 8, 6), 256, 0, stream>>>(Wf1, Wf1T, DMODEL, DFF_C);
  transpose_k<<<dim3(8, 32, 6), 256, 0, stream>>>(Wf2, Wf2T, DFF_C, DMODEL);
  conv_init_k<<<NA / 1024, 256, 0, stream>>>(q_embed, xbuf, xbf);
  conv_init_k<<<NA / 1024, 256, 0, stream>>>(qa_embed, ybuf, ybf);

  auto run_layer = [&](int l, float* Q, ushort_t* Qbf, const ushort_t* Vbf,
                       int mask_val, bool ffn, bool last) {
    const float* bq_l = bq + (size_t)l * DMODEL;
    const float* bv_l = bv + (size_t)l * DMODEL;
    const float* Wg_l = Wg + (size_t)l * DMODEL * NDYN_C;
    const float* bo_l = bo + (size_t)l * DMODEL;
    const float* g1_l = ln1w + (size_t)l * DMODEL;
    const float* b1_l = ln1b + (size_t)l * DMODEL;
    const ushort_t* WqT_l = WqT + (size_t)l * DMODEL * DMODEL;
    const ushort_t* WvT_l = WvT + (size_t)l * DMODEL * DMODEL;
    const ushort_t* WoT_l = WoT + (size_t)l * DMODEL * DMODEL;

    router_k<<<64, 128, 0, stream>>>(xbuf, Wg_l, partials);
    router_reduce_k<<<1, 64, 0, stream>>>(partials, routing8,
                                          last ? (out + NA) : balscratch);
    gemm_qv_k<<<dim3(128, 4, 2), 256, 0, stream>>>(
        Qbf, WqT_l, bq_l, qb_bf, WvT_l, Vbf, bv_l, vbT);
    attn_mfma_k<<<1024, 256, 0, stream>>>(qb_bf, vbT, routing8, ab_bf, mask_val);
    gemm_mfma_k<0><<<dim3(4, 128), 256, 0, stream>>>(
        ab_bf, WoT_l, bo_l, ob, NTOK_C, DMODEL, DMODEL);
    add_ln_k<<<NTOK_C / 4, 256, 0, stream>>>(Q, Q, Qbf, ob, g1_l, b1_l);
    if (ffn) {
      const float* bf1_l = bf1 + (size_t)l * DFF_C;
      const float* bf2_l = bf2 + (size_t)l * DMODEL;
      const float* g2_l = ln2w + (size_t)l * DMODEL;
      const float* b2_l = ln2b + (size_t)l * DMODEL;
      const ushort_t* Wf1T_l = Wf1T + (size_t)l * DMODEL * DFF_C;
      const ushort_t* Wf2T_l = Wf2T + (size_t)l * DFF_C * DMODEL;
      gemm_mfma_k<2><<<dim3(16, 128), 256, 0, stream>>>(
          Qbf, Wf1T_l, bf1_l, hb, NTOK_C, DFF_C, DMODEL);
      gemm_mfma_k<0><<<dim3(4, 128), 256, 0, stream>>>(
          hb, Wf2T_l, bf2_l, ob, NTOK_C, DMODEL, DFF_C);
      // last layer: write the final layernorm result straight to d_out
      add_ln_k<<<NTOK_C / 4, 256, 0, stream>>>(Q, last ? out : Q, Qbf, ob, g2_l, b2_l);
    }
  };

  // blocks_1: y-stream, router input = x (q_embed copy, unchanged during blocks_1)
  run_layer(0, ybuf, ybf, ybf, 1, true, false);
  run_layer(1, ybuf, ybf, ybf, 1, true, false);
  // blocks_2: (self, no FFN) then (cross to y, strict causal, FFN)
  run_layer(2, xbuf, xbf, xbf, 1, false, false);
  run_layer(3, xbuf, xbf, ybf, 0, true, false);
  run_layer(4, xbuf, xbf, xbf, 1, false, false);
  run_layer(5, xbuf, xbf, ybf, 0, true, true);
}

// Round 11
// 547.059 us; speedup vs baseline: 5.3323x; 1.0733x over previous
//
#include <hip/hip_runtime.h>

// RouterKT forward. Round 11: dispatch-count reduction on the verified R10 base.
// Router fused into QV dual-GEMM (shared LDS); attn computes rt from partials
// inline (reduce kernel only at layer 5 for bal); prep kernels merged. 41 dispatches.

constexpr int DMODEL = 256;
constexpr int SEQ    = 1024;
constexpr int BATCH  = 8;
constexpr int NHEADS = 8;
constexpr int DKDIM  = 32;
constexpr int NDYN_C = 6;
constexpr int NTOK_C = BATCH * SEQ;   // 8192
constexpr int DFF_C  = 1024;

using frag_bf16 = __attribute__((ext_vector_type(8))) short;  // 8 bf16 = 4 VGPR
using f32x4    = __attribute__((ext_vector_type(4))) float;
typedef unsigned short ushort_t;

__device__ __forceinline__ ushort_t f2bf(float f) {
  unsigned u = __float_as_uint(f);
  unsigned r = (u + 0x7fffu + ((u >> 16) & 1u)) >> 16;   // RNE, finite inputs
  return (ushort_t)r;
}

__device__ __forceinline__ unsigned cvt_pk_bf16(float lo, float hi) {
  unsigned r;
  asm("v_cvt_pk_bf16_f32 %0, %1, %2" : "=v"(r) : "v"(lo), "v"(hi));
  return r;
}

#define GLOAD_LDS16(gsrc, ldst)                                             \
  __builtin_amdgcn_global_load_lds(                                         \
      (const __attribute__((address_space(1))) void*)(gsrc),                \
      (__attribute__((address_space(3))) void*)(ldst), 16, 0, 0)

// Explicit drain + order pin + barrier (race-proof prefetch handoff).
#define SYNC_DRAIN()                                                        \
  do {                                                                      \
    asm volatile("s_waitcnt vmcnt(0) lgkmcnt(0)" ::: "memory");             \
    __builtin_amdgcn_sched_barrier(0);                                      \
    __syncthreads();                                                        \
  } while (0)

// ---------------- bf16 MFMA GEMM body (2-phase prefetch, explicit drain) ------
// C[m][n] = sum_k A[m][k] * B[n][k] + bias.   A:[M][K] bf16, B:[N][K] bf16.
// Tile: BM=64, BN=64, BK=64, double-buffered. 256 threads = 4 waves (2x2).
// mode: 0 = f32 C, 1 = bf16*QSCALE (q-proj), 2 = bf16+relu, 3 = vbT scatter.
// LDS owned by the calling kernel: exactly one 32 KB set per kernel.
__device__ __forceinline__
void gemm_body(int mode, int bx, int by,
               const ushort_t* __restrict__ A, const ushort_t* __restrict__ B,
               const float* __restrict__ bias, void* __restrict__ Cp,
               int M, int N, int K,
               ushort_t (*sA)[4096], ushort_t (*sB)[4096]) {
  const int tid = threadIdx.x;
  const int wid = tid >> 6, lane = tid & 63;
  const int li = lane & 15, g = lane >> 4;
  const int wr = wid >> 1, wc = wid & 1;
  const int m0 = by * 64, n0 = bx * 64;
  f32x4 acc[2][2] = {};
  const int srow = wid * 8 + (lane >> 3);
  const int schk = (lane & 7) ^ (lane >> 3);
  const ushort_t* gA1 = &A[(size_t)(m0 + srow) * K + schk * 8];
  const ushort_t* gA2 = &A[(size_t)(m0 + 32 + srow) * K + schk * 8];
  const ushort_t* gB1 = &B[(size_t)(n0 + srow) * K + schk * 8];
  const ushort_t* gB2 = &B[(size_t)(n0 + 32 + srow) * K + schk * 8];
  const int nk = K >> 6;

  GLOAD_LDS16(gA1, sA[0] + wid * 512);
  GLOAD_LDS16(gA2, sA[0] + 2048 + wid * 512);
  GLOAD_LDS16(gB1, sB[0] + wid * 512);
  GLOAD_LDS16(gB2, sB[0] + 2048 + wid * 512);
  SYNC_DRAIN();

  auto compute = [&](int cur) {
#pragma unroll
    for (int s = 0; s < 2; ++s) {
      frag_bf16 af[2], bf[2];
#pragma unroll
      for (int m = 0; m < 2; ++m) {
        const int row = wr * 32 + m * 16 + li;
        af[m] = *reinterpret_cast<const frag_bf16*>(
            &sA[cur][row * 64 + ((s * 4 + g) ^ (row & 7)) * 8]);
      }
#pragma unroll
      for (int n = 0; n < 2; ++n) {
        const int row = wc * 32 + n * 16 + li;
        bf[n] = *reinterpret_cast<const frag_bf16*>(
            &sB[cur][row * 64 + ((s * 4 + g) ^ (row & 7)) * 8]);
      }
#pragma unroll
      for (int m = 0; m < 2; ++m)
#pragma unroll
        for (int n = 0; n < 2; ++n)
          acc[m][n] = __builtin_amdgcn_mfma_f32_16x16x32_bf16(af[m], bf[n], acc[m][n], 0, 0, 0);
    }
  };

  for (int kt = 0; kt < nk - 1; ++kt) {
    const int cur = kt & 1;
    const int k1 = (kt + 1) << 6;
    GLOAD_LDS16(gA1 + k1, sA[cur ^ 1] + wid * 512);
    GLOAD_LDS16(gA2 + k1, sA[cur ^ 1] + 2048 + wid * 512);
    GLOAD_LDS16(gB1 + k1, sB[cur ^ 1] + wid * 512);
    GLOAD_LDS16(gB2 + k1, sB[cur ^ 1] + 2048 + wid * 512);
    compute(cur);
    SYNC_DRAIN();
  }
  compute((nk - 1) & 1);

  constexpr float QSCALE = 0.42044820762685725f;  // 32^-0.25; k=q so (qs)(ks)=qk/sqrt(32)
#pragma unroll
  for (int m = 0; m < 2; ++m)
#pragma unroll
    for (int n = 0; n < 2; ++n)
#pragma unroll
      for (int r = 0; r < 4; ++r) {
        const int mg = m0 + wr * 32 + m * 16 + g * 4 + r;
        const int ng = n0 + wc * 32 + n * 16 + li;
        if (mode == 0) {
          ((float*)Cp)[(size_t)mg * N + ng] = acc[m][n][r] + bias[ng];
        } else if (mode == 1) {
          ((ushort_t*)Cp)[(size_t)mg * N + ng] = f2bf((acc[m][n][r] + bias[ng]) * QSCALE);
        } else if (mode == 2) {
          ((ushort_t*)Cp)[(size_t)mg * N + ng] = f2bf(fmaxf(acc[m][n][r] + bias[ng], 0.0f));
        } else {
          ((ushort_t*)Cp)[((size_t)((ng >> 10) * 256 + mg)) * SEQ + (ng & 1023)] =
              f2bf(acc[m][n][r] + bias[mg]);
        }
      }
}

__global__ __launch_bounds__(256)
void gemm_mfma_k(int mode, const ushort_t* __restrict__ A, const ushort_t* __restrict__ B,
                 const float* __restrict__ bias, void* __restrict__ Cp,
                 int M, int N, int K) {
  __shared__ ushort_t sA[2][4096];
  __shared__ ushort_t sB[2][4096];
  gemm_body(mode, blockIdx.x, blockIdx.y, A, B, bias, Cp, M, N, K, sA, sB);
}

// ---------------- Router body (verified R7 128-row version, 256-thread guards) -
// sW: >=1536 floats; red: [18][128] floats (both live in the caller's LDS).
__device__ __forceinline__
void router_body(const float* __restrict__ R, const float* __restrict__ Wg,
                 float* __restrict__ partials, float* sW, float (*red)[128]) {
  const int tid = threadIdx.x;
  for (int t = tid; t < DMODEL * NDYN_C; t += 256) sW[t] = Wg[t];
  __syncthreads();
  if (tid < 128) {
    const int r = blockIdx.x * 128 + tid;
    const int b = r >> 10;
    const int h = (r >> 7) & 7;
    const int s8 = r & 127;
    float lg[NDYN_C] = {};
    for (int t8 = 0; t8 < 8; ++t8) {
      const float* base = &R[((size_t)(b * SEQ + s8 * 8 + t8)) * DMODEL + h * DKDIM];
#pragma unroll
      for (int d = 0; d < DKDIM; ++d) {
        const float x = base[d];
        const float* w = &sW[(t8 * 32 + d) * NDYN_C];
#pragma unroll
        for (int j = 0; j < NDYN_C; ++j) lg[j] = fmaf(x, w[j], lg[j]);
      }
    }
    float mx = lg[0];
#pragma unroll
    for (int j = 1; j < NDYN_C; ++j) mx = fmaxf(mx, lg[j]);
    float e[NDYN_C], sum = 0.0f;
#pragma unroll
    for (int j = 0; j < NDYN_C; ++j) { e[j] = expf(lg[j] - mx); sum += e[j]; }
    float g[NDYN_C];
#pragma unroll
    for (int j = 0; j < NDYN_C; ++j) g[j] = e[j] / sum;
    int j1 = 0;
#pragma unroll
    for (int j = 1; j < NDYN_C; ++j) if (g[j] > g[j1]) j1 = j;
    int j2 = -1;
#pragma unroll
    for (int j = 0; j < NDYN_C; ++j) {
      if (j == j1) continue;
      if (j2 < 0 || g[j] > g[j2]) j2 = j;
    }
#pragma unroll
    for (int j = 0; j < NDYN_C; ++j) {
      const bool sel = (j == j1) || (j == j2);
      red[j][tid] = sel ? g[j] : 0.0f;
      red[6 + j][tid] = sel ? 1.0f : 0.0f;
      red[12 + j][tid] = g[j];
    }
  }
  __syncthreads();
  if (tid < 18) {
    float s = 0.0f;
    for (int i = 0; i < 128; ++i) s += red[tid][i];
    partials[blockIdx.x * 18 + tid] = s;
  }
}

// merged Q-projection (mode 1) + V-projection (mode 3) + router slice.
// grid (128, 5, 2): y<4 -> GEMMs; y==4,z==0,x<64 -> router (LDS shared with GEMM).
__global__ __launch_bounds__(256)
void gemm_qv_router_k(const ushort_t* __restrict__ Aq, const ushort_t* __restrict__ Bq,
                      const float* __restrict__ biasq, void* __restrict__ Cq,
                      const ushort_t* __restrict__ Av, const ushort_t* __restrict__ Bv,
                      const float* __restrict__ biasv, void* __restrict__ Cv,
                      const float* __restrict__ R, const float* __restrict__ Wg,
                      float* __restrict__ partials) {
  __shared__ ushort_t sA[2][4096];   // 16 KB
  __shared__ ushort_t sB[2][4096];   // 16 KB
  if (blockIdx.y == 4) {
    if (blockIdx.z == 0 && blockIdx.x < 64) {
      float* sW = (float*)&sA[0][0];                   // 6 KB <= 16 KB
      float (*red)[128] = (float(*)[128])&sB[0][0];    // 9 KB <= 16 KB
      router_body(R, Wg, partials, sW, red);
    }
    return;
  }
  if (blockIdx.z == 0)
    gemm_body(1, blockIdx.y, blockIdx.x, Aq, Bq, biasq, Cq, NTOK_C, DMODEL, DMODEL, sA, sB);
  else
    gemm_body(3, blockIdx.x, blockIdx.y, Av, Bv, biasv, Cv, DMODEL, NTOK_C, DMODEL, sA, sB);
}

// ---------------- weight transpose bodies ----------------
__device__ __forceinline__
void transpose_body(const float* __restrict__ ip, ushort_t* __restrict__ op, int R, int C,
                    int c0, int r0) {
  __shared__ float t[32][33];
  const int tx = threadIdx.x & 31, ty = threadIdx.x >> 5;   // ty 0..7
#pragma unroll
  for (int i = 0; i < 4; ++i) t[ty + 8 * i][tx] = ip[(size_t)(r0 + ty + 8 * i) * C + c0 + tx];
  __syncthreads();
#pragma unroll
  for (int i = 0; i < 4; ++i)
    op[(size_t)(c0 + ty + 8 * i) * R + r0 + tx] = f2bf(t[tx][ty + 8 * i]);
}

// generic: in [z][R][C] f32 -> out [z][C][R] bf16
__global__ __launch_bounds__(256)
void transpose_k(const float* __restrict__ in, ushort_t* __restrict__ out, int R, int C) {
  const int z = blockIdx.z;
  transpose_body(in + (size_t)z * R * C, out + (size_t)z * R * C, R, C,
                 blockIdx.x * 32, blockIdx.y * 32);
}

// three 256x256 weight stacks in one launch: grid (8, 8, 18), zi = z/6 picks stack
__global__ __launch_bounds__(256)
void transpose3_k(const float* __restrict__ W0, ushort_t* __restrict__ O0,
                  const float* __restrict__ W1, ushort_t* __restrict__ O1,
                  const float* __restrict__ W2, ushort_t* __restrict__ O2) {
  const int z = blockIdx.z;
  const int zi = z / 6, zz = z % 6;
  const float* in = (zi == 0) ? W0 : (zi == 1) ? W1 : W2;
  ushort_t* out = (zi == 0) ? O0 : (zi == 1) ? O1 : O2;
  transpose_body(in + (size_t)zz * DMODEL * DMODEL, out + (size_t)zz * DMODEL * DMODEL,
                 DMODEL, DMODEL, blockIdx.x * 32, blockIdx.y * 32);
}

// ---------------- f32 copy + bf16 mirror (both streams in one launch) ----------
__global__ __launch_bounds__(256)
void conv_init_k(const float* __restrict__ s0, float* __restrict__ f0,
                 ushort_t* __restrict__ b0,
                 const float* __restrict__ s1, float* __restrict__ f1,
                 ushort_t* __restrict__ b1) {
  const float* src = blockIdx.y ? s1 : s0;
  float* dstF = blockIdx.y ? f1 : f0;
  ushort_t* dstB = blockIdx.y ? b1 : b0;
  const int i = blockIdx.x * 256 + threadIdx.x;   // over float4 elements
  const float4 v = reinterpret_cast<const float4*>(src)[i];
  reinterpret_cast<float4*>(dstF)[i] = v;
  ushort4 b;
  b.x = f2bf(v.x); b.y = f2bf(v.y); b.z = f2bf(v.z); b.w = f2bf(v.w);
  reinterpret_cast<ushort4*>(dstB)[i] = b;
}

// ---------------- MFMA flash attention (swapped operands) — verified R7 body ---
// rt computed inline from router partials (8 L2-hit loads, same sum order as the
// old reduce kernel -> bit-identical).
__global__ __launch_bounds__(256)
void attn_mfma_k(const ushort_t* __restrict__ qb, const ushort_t* __restrict__ vbT,
                 const float* __restrict__ partials, ushort_t* __restrict__ out,
                 int mask_val) {
  __shared__ ushort_t sk[2][2048];   // K tile: [kb 4][g 4][li=key 16][8] frag-linear
  __shared__ ushort_t sv[2][2048];   // V^T tile: [d 32][8 chunks, slot = ch^(d&7)][8]
  __shared__ ushort_t pbuf[4096];    // per-wave P^T frag-linear: [c 2][g 4][li=q 16][8]
  const int gid = blockIdx.x;
  const int b = gid & 7;
  const int slot = gid >> 3;
  const int h = (slot >> 4) & 7;
  const int qblk = 15 - (slot & 15);
  const int q0 = qblk * 64;
  const int tid = threadIdx.x;
  const int wave = tid >> 6, lane = tid & 63;
  const int g = lane >> 4, li = lane & 15;
  const int qw = q0 + wave * 16;
  const int qrow = qw + li;          // this lane's q row

  const frag_bf16 qf = *reinterpret_cast<const frag_bf16*>(
      &qb[((size_t)(b * SEQ + qrow)) * DMODEL + h * DKDIM + g * 8]);

  float mrun = -INFINITY, lrun = 0.f;
  f32x4 o0 = {0.f, 0.f, 0.f, 0.f}, o1 = {0.f, 0.f, 0.f, 0.f};  // O^T: d=4g+r(+16), q=li
  ushort_t* pP = &pbuf[wave * 1024];

  const ushort_t* gK = &qb[((size_t)(b * SEQ + wave * 16 + li)) * DMODEL + h * DKDIM + g * 8];
  const ushort_t* gV = &vbT[((size_t)((b * NHEADS + h) * DKDIM) + wave * 8 + (lane >> 3)) * SEQ
                            + ((lane & 7) ^ (lane >> 3)) * 8];

  const int nt = qblk + 1;
  GLOAD_LDS16(gK, sk[0] + wave * 512);
  GLOAD_LDS16(gV, sv[0] + wave * 512);
  SYNC_DRAIN();

  auto tile_step = [&](int t, int cur) {
    const int kt = t * 64;
    // S^T = K Q^T: lane holds rows key=kb*16+4g+r, col q=li
    f32x4 s[4];
#pragma unroll
    for (int kb = 0; kb < 4; ++kb) {
      frag_bf16 kf = *reinterpret_cast<const frag_bf16*>(&sk[cur][(kb * 64 + g * 16 + li) * 8]);
      f32x4 z = {0.f, 0.f, 0.f, 0.f};
      s[kb] = __builtin_amdgcn_mfma_f32_16x16x32_bf16(kf, qf, z, 0, 0, 0);
    }
    const bool need_mask = (kt + 63) >= (qw + mask_val);
    if (need_mask) {
#pragma unroll
      for (int kb = 0; kb < 4; ++kb)
#pragma unroll
        for (int r = 0; r < 4; ++r) {
          const int col = kt + kb * 16 + 4 * g + r;
          if (col >= (qrow + mask_val)) s[kb][r] = -1e9f;
        }
    }
    float tm = -INFINITY;
#pragma unroll
    for (int kb = 0; kb < 4; ++kb)
#pragma unroll
      for (int r = 0; r < 4; ++r) tm = fmaxf(tm, s[kb][r]);
    tm = fmaxf(tm, __shfl_xor(tm, 16, 64));
    tm = fmaxf(tm, __shfl_xor(tm, 32, 64));
    const float mnew = fmaxf(mrun, tm);
    const float scl = __expf(mrun - mnew);
    float p[4][4];
    float psum = 0.f;
#pragma unroll
    for (int kb = 0; kb < 4; ++kb)
#pragma unroll
      for (int r = 0; r < 4; ++r) { p[kb][r] = __expf(s[kb][r] - mnew); psum += p[kb][r]; }
    psum += __shfl_xor(psum, 16, 64);
    psum += __shfl_xor(psum, 32, 64);
    lrun = lrun * scl + psum;
    mrun = mnew;
#pragma unroll
    for (int r = 0; r < 4; ++r) { o0[r] *= scl; o1[r] *= scl; }
    // P^T pack into fragment-linear: key k=kb*16+g*4+pair*2 -> unit(c,gg,li), ofs j
#pragma unroll
    for (int kb = 0; kb < 4; ++kb)
#pragma unroll
      for (int pair = 0; pair < 2; ++pair) {
        const unsigned pk = cvt_pk_bf16(p[kb][2 * pair], p[kb][2 * pair + 1]);
        const int addr = (((kb >> 1) * 4 + (kb & 1) * 2 + (g >> 1)) * 16 + li) * 8
                         + 4 * (g & 1) + 2 * pair;
        *reinterpret_cast<unsigned*>(&pP[addr]) = pk;
      }
    __threadfence_block();
    // O^T += V^T P^T
#pragma unroll
    for (int c = 0; c < 2; ++c) {
      frag_bf16 pf = *reinterpret_cast<const frag_bf16*>(&pP[((c * 4 + g) * 16 + li) * 8]);
      frag_bf16 vf0 = *reinterpret_cast<const frag_bf16*>(
          &sv[cur][li * 64 + ((4 * c + g) ^ (li & 7)) * 8]);
      frag_bf16 vf1 = *reinterpret_cast<const frag_bf16*>(
          &sv[cur][(16 + li) * 64 + ((4 * c + g) ^ (li & 7)) * 8]);
      o0 = __builtin_amdgcn_mfma_f32_16x16x32_bf16(vf0, pf, o0, 0, 0, 0);
      o1 = __builtin_amdgcn_mfma_f32_16x16x32_bf16(vf1, pf, o1, 0, 0, 0);
    }
  };

  for (int t = 0; t < nt - 1; ++t) {
    const int cur = t & 1;
    const int kt = t * 64;
    GLOAD_LDS16(gK + (size_t)(kt + 64) * DMODEL, sk[cur ^ 1] + wave * 512);
    GLOAD_LDS16(gV + (kt + 64), sv[cur ^ 1] + wave * 512);
    tile_step(t, cur);
    SYNC_DRAIN();
  }
  tile_step(nt - 1, (nt - 1) & 1);

  // rt from partials: routing8[b][h] = 1 for shared heads, mean gate otherwise.
  float rt = 1.0f;
  if (h >= 2) {
    const int j = h - 2;
    float sr = 0.f;
#pragma unroll
    for (int t = 0; t < 8; ++t) sr += partials[(b * 8 + t) * 18 + j];
    rt = sr * (1.0f / 1024.0f);
  }
  const float mult = rt / lrun;
  // ref: fully-masked row 0 (mask_val==0) -> uniform over ALL keys; patched below
  if (!(mask_val == 0 && qrow == 0)) {
    const size_t base = (size_t)(b * SEQ + qrow) * DMODEL + h * DKDIM;
    ushort4 w0, w1;
    w0.x = f2bf(o0[0] * mult); w0.y = f2bf(o0[1] * mult);
    w0.z = f2bf(o0[2] * mult); w0.w = f2bf(o0[3] * mult);
    w1.x = f2bf(o1[0] * mult); w1.y = f2bf(o1[1] * mult);
    w1.z = f2bf(o1[2] * mult); w1.w = f2bf(o1[3] * mult);
    *reinterpret_cast<ushort4*>(&out[base + 4 * g]) = w0;
    *reinterpret_cast<ushort4*>(&out[base + 16 + 4 * g]) = w1;
  }
  // fused row0 patch: out[b,0,h,:] = mean_k(V[k,:]) * rt
  if (mask_val == 0 && qblk == 0 && wave == 0) {
    const int d = lane >> 1, hf = lane & 1;
    const ushort_t* src = &vbT[(((size_t)(b * NHEADS + h)) * DKDIM + d) * SEQ + hf * 512];
    float s = 0.f;
    for (int k = 0; k < 512; k += 8) {
      frag_bf16 v = *reinterpret_cast<const frag_bf16*>(&src[k]);
#pragma unroll
      for (int j = 0; j < 8; ++j)
        s += __uint_as_float(((unsigned)(ushort_t)v[j]) << 16);
    }
    s += __shfl_xor(s, 1, 64);
    if (hf == 0)
      out[(size_t)(b * SEQ) * DMODEL + h * DKDIM + d] = f2bf(s * (1.0f / 1024.0f) * rt);
  }
}

// ---------------- router finalize: launched ONLY for the last layer (bal) -----
__global__ void router_reduce_k(const float* __restrict__ partials,
                                float* __restrict__ bal_out) {
  const int tid = threadIdx.x;
  if (tid == 0) {
    float hs[6], hp[6];
    float hssum = 0.0f, hpsum = 0.0f;
    for (int j = 0; j < 6; ++j) {
      float a = 0.0f, c = 0.0f;
      for (int bi = 0; bi < 64; ++bi) {
        a += partials[bi * 18 + 6 + j];
        c += partials[bi * 18 + 12 + j];
      }
      hs[j] = a;
      hp[j] = c * (1.0f / 8192.0f);
      hssum += hs[j];
      hpsum += hp[j];
    }
    float bal = 0.0f;
    for (int j = 0; j < 6; ++j)
      bal += (hs[j] / (hssum + 1e-5f)) * (hp[j] / (hpsum + 1e-5f));
    *bal_out = bal;
  }
}

// ---------------- residual add + layernorm: one wave per row, shfl-only ----
__global__ __launch_bounds__(256)
void add_ln_k(const float* __restrict__ Xin, float* __restrict__ Xout,
              ushort_t* __restrict__ Xbf, const float* __restrict__ Y,
              const float* __restrict__ g, const float* __restrict__ be) {
  const int wave = threadIdx.x >> 6, lane = threadIdx.x & 63;
  const int r = blockIdx.x * 4 + wave;
  const size_t base = (size_t)r * DMODEL + lane * 4;
  float4 x = *reinterpret_cast<const float4*>(&Xin[base]);
  const float4 y = *reinterpret_cast<const float4*>(&Y[base]);
  x.x += y.x; x.y += y.y; x.z += y.z; x.w += y.w;
  float s = x.x + x.y + x.z + x.w;
#pragma unroll
  for (int o = 32; o >= 1; o >>= 1) s += __shfl_xor(s, o, 64);
  const float mean = s * (1.0f / DMODEL);
  const float4 d = {x.x - mean, x.y - mean, x.z - mean, x.w - mean};
  float v = d.x * d.x + d.y * d.y + d.z * d.z + d.w * d.w;
#pragma unroll
  for (int o = 32; o >= 1; o >>= 1) v += __shfl_xor(v, o, 64);
  const float rstd = 1.0f / sqrtf(v * (1.0f / DMODEL) + 1e-5f);
  const float4 gg = *reinterpret_cast<const float4*>(&g[lane * 4]);
  const float4 bb = *reinterpret_cast<const float4*>(&be[lane * 4]);
  float4 rv;
  rv.x = d.x * rstd * gg.x + bb.x;
  rv.y = d.y * rstd * gg.y + bb.y;
  rv.z = d.z * rstd * gg.z + bb.z;
  rv.w = d.w * rstd * gg.w + bb.w;
  *reinterpret_cast<float4*>(&Xout[base]) = rv;
  ushort4 o4;
  o4.x = f2bf(rv.x); o4.y = f2bf(rv.y); o4.z = f2bf(rv.z); o4.w = f2bf(rv.w);
  *reinterpret_cast<ushort4*>(&Xbf[base]) = o4;
}

// ---------------- driver ----------------
extern "C" void kernel_launch(void* const* d_in, const int* in_sizes, int n_in,
                              void* d_out, int out_size, void* d_ws, size_t ws_size,
                              hipStream_t stream) {
  const float* q_embed  = (const float*)d_in[0];
  const float* qa_embed = (const float*)d_in[1];
  const float* Wq  = (const float*)d_in[2];
  const float* bq  = (const float*)d_in[3];
  const float* Wv  = (const float*)d_in[4];
  const float* bv  = (const float*)d_in[5];
  const float* Wg  = (const float*)d_in[6];
  const float* Wo  = (const float*)d_in[7];
  const float* bo  = (const float*)d_in[8];
  const float* ln1w = (const float*)d_in[9];
  const float* ln1b = (const float*)d_in[10];
  const float* Wf1 = (const float*)d_in[11];
  const float* bf1 = (const float*)d_in[12];
  const float* Wf2 = (const float*)d_in[13];
  const float* bf2 = (const float*)d_in[14];
  const float* ln2w = (const float*)d_in[15];
  const float* ln2b = (const float*)d_in[16];
  float* out = (float*)d_out;

  const size_t NA = (size_t)NTOK_C * DMODEL;  // 2097152
  float* xbuf = (float*)d_ws;
  float* ybuf = xbuf + NA;
  float* ob   = ybuf + NA;
  float* routing8   = ob + NA;
  float* partials   = routing8 + 64;
  float* balscratch = partials + 64 * 18;
  ushort_t* xbf   = (ushort_t*)(balscratch + 16);
  ushort_t* ybf   = xbf + NA;
  ushort_t* qb_bf = ybf + NA;
  ushort_t* vbT   = qb_bf + NA;
  ushort_t* ab_bf = vbT + NA;
  ushort_t* hb    = ab_bf + NA;                       // NTOK * DFF bf16
  ushort_t* WqT   = hb + (size_t)NTOK_C * DFF_C;
  ushort_t* WvT   = WqT + (size_t)6 * DMODEL * DMODEL;
  ushort_t* WoT   = WvT + (size_t)6 * DMODEL * DMODEL;
  ushort_t* Wf1T  = WoT + (size_t)6 * DMODEL * DMODEL;
  ushort_t* Wf2T  = Wf1T + (size_t)6 * DMODEL * DFF_C;

  // weight prep (merged)
  transpose3_k<<<dim3(8, 8, 18), 256, 0, stream>>>(Wq, WqT, Wv, WvT, Wo, WoT);
  transpose_k<<<dim3(32, 8, 6), 256, 0, stream>>>(Wf1, Wf1T, DMODEL, DFF_C);
  transpose_k<<<dim3(8, 32, 6), 256, 0, stream>>>(Wf2, Wf2T, DFF_C, DMODEL);
  conv_init_k<<<dim3(NA / 1024, 2), 256, 0, stream>>>(q_embed, xbuf, xbf,
                                                      qa_embed, ybuf, ybf);

  auto run_layer = [&](int l, float* Q, ushort_t* Qbf, const ushort_t* Vbf,
                       int mask_val, bool ffn, bool last) {
    const float* bq_l = bq + (size_t)l * DMODEL;
    const float* bv_l = bv + (size_t)l * DMODEL;
    const float* Wg_l = Wg + (size_t)l * DMODEL * NDYN_C;
    const float* bo_l = bo + (size_t)l * DMODEL;
    const float* g1_l = ln1w + (size_t)l * DMODEL;
    const float* b1_l = ln1b + (size_t)l * DMODEL;
    const ushort_t* WqT_l = WqT + (size_t)l * DMODEL * DMODEL;
    const ushort_t* WvT_l = WvT + (size_t)l * DMODEL * DMODEL;
    const ushort_t* WoT_l = WoT + (size_t)l * DMODEL * DMODEL;

    gemm_qv_router_k<<<dim3(128, 5, 2), 256, 0, stream>>>(
        Qbf, WqT_l, bq_l, qb_bf, WvT_l, Vbf, bv_l, vbT, xbuf, Wg_l, partials);
    if (last)
      router_reduce_k<<<1, 64, 0, stream>>>(partials, out + NA);
    attn_mfma_k<<<1024, 256, 0, stream>>>(qb_bf, vbT, partials, ab_bf, mask_val);
    gemm_mfma_k<<<dim3(4, 128), 256, 0, stream>>>(
        0, ab_bf, WoT_l, bo_l, ob, NTOK_C, DMODEL, DMODEL);
    add_ln_k<<<NTOK_C / 4, 256, 0, stream>>>(Q, Q, Qbf, ob, g1_l, b1_l);
    if (ffn) {
      const float* bf1_l = bf1 + (size_t)l * DFF_C;
      const float* bf2_l = bf2 + (size_t)l * DMODEL;
      const float* g2_l = ln2w + (size_t)l * DMODEL;
      const float* b2_l = ln2b + (size_t)l * DMODEL;
      const ushort_t* Wf1T_l = Wf1T + (size_t)l * DMODEL * DFF_C;
      const ushort_t* Wf2T_l = Wf2T + (size_t)l * DFF_C * DMODEL;
      gemm_mfma_k<<<dim3(16, 128), 256, 0, stream>>>(
          2, Qbf, Wf1T_l, bf1_l, hb, NTOK_C, DFF_C, DMODEL);
      gemm_mfma_k<<<dim3(4, 128), 256, 0, stream>>>(
          0, hb, Wf2T_l, bf2_l, ob, NTOK_C, DMODEL, DFF_C);
      // last layer: write the final layernorm result straight to d_out
      add_ln_k<<<NTOK_C / 4, 256, 0, stream>>>(Q, last ? out : Q, Qbf, ob, g2_l, b2_l);
    }
  };

  // blocks_1: y-stream, router input = x (q_embed copy, unchanged during blocks_1)
  run_layer(0, ybuf, ybf, ybf, 1, true, false);
  run_layer(1, ybuf, ybf, ybf, 1, true, false);
  // blocks_2: (self, no FFN) then (cross to y, strict causal, FFN)
  run_layer(2, xbuf, xbf, xbf, 1, false, false);
  run_layer(3, xbuf, xbf, ybf, 0, true, false);
  run_layer(4, xbuf, xbf, xbf, 1, false, false);
  run_layer(5, xbuf, xbf, ybf, 0, true, true);
}